// Round 5
// baseline (279.378 us; speedup 1.0000x reference)
//
#include <hip/hip_runtime.h>

namespace {

constexpr int B_ = 128;
constexpr int T_ = 4096;
constexpr int BT = B_ * T_;
constexpr int TTILE = 128;
constexpr unsigned INFBITS = 0x7F800000u;

// workspace layout (float offsets); feats array eliminated in round 5 —
// its region now holds the MFMA weight fragments (written by repack_k first).
constexpr size_t OFF_W1F  = 0;                 // 8 frags * 64 * 8 f16 = 2048 floats
constexpr size_t OFF_W2F  = 2048;              // 40 frags * 64 * 8 f16 = 10240 floats
constexpr size_t OFF_HC   = (size_t)B_ * 10 * T_;
constexpr size_t OFF_AN   = OFF_HC + (size_t)BT;
constexpr size_t OFF_SC   = OFF_AN + (size_t)BT;
constexpr size_t OFF_OT   = OFF_SC + (size_t)BT;
constexpr size_t OFF_RULE = OFF_OT + (size_t)BT;
constexpr size_t OFF_LP   = OFF_RULE + (size_t)BT;
constexpr size_t OFF_SCALES = OFF_LP;          // consumed by rule2_k before conv_k writes lp

typedef _Float16 half8 __attribute__((ext_vector_type(8)));
typedef _Float16 half4 __attribute__((ext_vector_type(4)));
typedef _Float16 half2_t __attribute__((ext_vector_type(2)));
typedef float f32x4 __attribute__((ext_vector_type(4)));

__device__ __forceinline__ float clip01(float x) { return fminf(fmaxf(x, 0.f), 1.f); }

// branchless GELU via Abramowitz-Stegun 7.1.26 erf (|err| <= 1.5e-7)
__device__ __forceinline__ float gelu_fast(float x) {
  float s = x * 0.7071067811865475f;
  float a = fabsf(s);
  float t = __builtin_amdgcn_rcpf(__builtin_fmaf(0.3275911f, a, 1.0f));
  float p = __builtin_fmaf(t, 1.061405429f, -1.453152027f);
  p = __builtin_fmaf(t, p, 1.421413741f);
  p = __builtin_fmaf(t, p, -0.284496736f);
  p = __builtin_fmaf(t, p, 0.254829592f);
  p = p * t;
  float e = __builtin_amdgcn_exp2f(a * a * -1.4426950408889634f);
  float erfa = __builtin_fmaf(-p, e, 1.0f);
  float erfs = copysignf(erfa, s);
  return 0.5f * x * (1.0f + erfs);
}

// shared feature math: computes the 10 scorer features for (b,t).
// Identical arithmetic to the round-4 featurize_k (bit-exact outputs).
__device__ __forceinline__ void compute_feats(
    const float* __restrict__ tr, const float* __restrict__ iv,
    const float* __restrict__ mk, const float* __restrict__ om, int t,
    float* __restrict__ f /*10*/, float* anv_out, float* scv_out, float* otv_out) {
  float m  = mk[t];
  float m1 = (t >= 1) ? mk[t - 1] : 0.f;
  float m2 = (t >= 2) ? mk[t - 2] : 0.f;
  float pm01 = (m > 0.5f && m1 > 0.5f) ? 1.f : 0.f;
  float pm12 = (m1 > 0.5f && m2 > 0.5f) ? 1.f : 0.f;
  float x0x = tr[2 * t] * m, x0y = tr[2 * t + 1] * m;
  float x1x = 0.f, x1y = 0.f, x2x = 0.f, x2y = 0.f;
  if (t >= 1) { x1x = tr[2 * (t - 1)] * m1; x1y = tr[2 * (t - 1) + 1] * m1; }
  if (t >= 2) { x2x = tr[2 * (t - 2)] * m2; x2y = tr[2 * (t - 2) + 1] * m2; }
  float dt0 = fmaxf(iv[t], 1e-3f);
  float dt1 = (t >= 1) ? fmaxf(iv[t - 1], 1e-3f) : 1e-3f;
  float vx = 0.f, vy = 0.f, v1x = 0.f, v1y = 0.f;
  if (t >= 1) { vx = (x0x - x1x) * pm01 / dt0 * m; vy = (x0y - x1y) * pm01 / dt0 * m; }
  if (t >= 2) { v1x = (x1x - x2x) * pm12 / dt1 * m1; v1y = (x1y - x2y) * pm12 / dt1 * m1; }
  float ax = 0.f, ay = 0.f;
  if (t >= 1) { ax = (vx - v1x) * pm01 / dt0 * m; ay = (vy - v1y) * pm01 / dt0 * m; }
  float s2 = vx * vx + vy * vy;
  float speed = (s2 > 0.f ? sqrtf(s2) : 0.f) * m;
  float s21 = v1x * v1x + v1y * v1y;
  float speed1 = (s21 > 0.f ? sqrtf(s21) : 0.f) * m1;
  float scv = (t >= 1) ? fabsf((speed - speed1) * pm01) * m : 0.f;
  float a2 = ax * ax + ay * ay;
  float anv = (a2 > 0.f ? sqrtf(a2) : 0.f) * m;
  float hcv = 0.f;
  if (t >= 1) {
    bool z0 = (vx == 0.f && vy == 0.f);
    bool z1 = (v1x == 0.f && v1y == 0.f);
    float yy, xx;
    if (z1)      { yy = vy;  xx = vx; }
    else if (z0) { yy = v1y; xx = v1x; }
    else { yy = vy * v1x - vx * v1y; xx = vx * v1x + vy * v1y; }
    hcv = fabsf(atan2f(yy, xx)) * pm01 * m;
  }
  float obs = om[t] * m;
  float otv = (t >= 1) ? fminf(fabsf(om[t] - om[t - 1]) * pm01 * m, 1.f) : 0.f;
  float itf = iv[t] * m;
  f[0] = x0x; f[1] = x0y; f[2] = vx; f[3] = vy; f[4] = ax; f[5] = ay;
  f[6] = speed; f[7] = hcv; f[8] = itf; f[9] = obs;
  *anv_out = anv; *scv_out = scv; *otv_out = otv;
}

// ---------------- Kernel A: metrics only (feats array eliminated) ----------------
__global__ __launch_bounds__(256)
void metrics_k(const float* __restrict__ traj, const float* __restrict__ intervals,
               const float* __restrict__ amask, const float* __restrict__ omask,
               float* __restrict__ hc, float* __restrict__ an,
               float* __restrict__ sc, float* __restrict__ ot) {
  int idx = blockIdx.x * 256 + threadIdx.x;
  if (idx >= BT) return;
  int b = idx >> 12;
  int t = idx & (T_ - 1);
  float f[10], anv, scv, otv;
  compute_feats(traj + (size_t)b * T_ * 2, intervals + (size_t)b * T_,
                amask + (size_t)b * T_, omask + (size_t)b * T_, t, f, &anv, &scv, &otv);
  hc[idx] = f[7]; an[idx] = anv; sc[idx] = scv; ot[idx] = otv;
}

// ---------------- parallel bucket find ----------------
template <int CHUNK>
__device__ __forceinline__ void find_bucket_par(const unsigned* __restrict__ hist,
                                                unsigned* selb, unsigned* selk,
                                                unsigned* sW4, int tid) {
  unsigned k = *selk;
  unsigned vals[CHUNK];
  unsigned ps = 0;
#pragma unroll
  for (int c = 0; c < CHUNK; ++c) { vals[c] = hist[tid * CHUNK + c]; ps += vals[c]; }
  unsigned incl = ps;
  int lane = tid & 63;
#pragma unroll
  for (int off = 1; off < 64; off <<= 1) {
    unsigned tv = __shfl_up(incl, off, 64);
    if (lane >= off) incl += tv;
  }
  if (lane == 63) sW4[tid >> 6] = incl;
  __syncthreads();
  int wv = tid >> 6;
  unsigned woff = 0;
  if (wv > 0) woff += sW4[0];
  if (wv > 1) woff += sW4[1];
  if (wv > 2) woff += sW4[2];
  incl += woff;
  unsigned excl = incl - ps;
  __syncthreads();
  if (excl <= k && k < incl) {
    unsigned run = excl;
    int c = 0;
#pragma unroll
    for (; c < CHUNK - 1; ++c) {
      if (run + vals[c] > k) break;
      run += vals[c];
    }
    *selb = (unsigned)(tid * CHUNK + c);
    *selk = k - run;
  }
  __syncthreads();
}

__device__ __forceinline__ float radix_select(const unsigned* u, unsigned k, unsigned* hist,
                                              unsigned* selb, unsigned* selk,
                                              unsigned* sW4, int tid) {
  for (int i = tid; i < 4096; i += 256) hist[i] = 0u;
  if (tid == 0) *selk = k;
  __syncthreads();
#pragma unroll
  for (int r = 0; r < 16; ++r) atomicAdd(&hist[u[r] >> 20], 1u);
  __syncthreads();
  find_bucket_par<16>(hist, selb, selk, sW4, tid);
  unsigned p1 = *selb;
  for (int i = tid; i < 4096; i += 256) hist[i] = 0u;
  __syncthreads();
#pragma unroll
  for (int r = 0; r < 16; ++r)
    if ((u[r] >> 20) == p1) atomicAdd(&hist[(u[r] >> 8) & 0xFFFu], 1u);
  __syncthreads();
  find_bucket_par<16>(hist, selb, selk, sW4, tid);
  unsigned p2 = *selb;
  unsigned pref = (p1 << 12) | p2;
  for (int i = tid; i < 256; i += 256) hist[i] = 0u;
  __syncthreads();
#pragma unroll
  for (int r = 0; r < 16; ++r)
    if ((u[r] >> 8) == pref) atomicAdd(&hist[u[r] & 0xFFu], 1u);
  __syncthreads();
  find_bucket_par<1>(hist, selb, selk, sW4, tid);
  unsigned p3 = *selb;
  __syncthreads();
  return __uint_as_float((p1 << 20) | (p2 << 8) | p3);
}

__device__ __forceinline__ float block_max(float v, float* s4, int tid) {
#pragma unroll
  for (int off = 32; off; off >>= 1) v = fmaxf(v, __shfl_xor(v, off));
  if ((tid & 63) == 0) s4[tid >> 6] = v;
  __syncthreads();
  v = fmaxf(fmaxf(s4[0], s4[1]), fmaxf(s4[2], s4[3]));
  __syncthreads();
  return v;
}

__device__ __forceinline__ int count_valid(const float* mrow, float* mreg, int* i4, int tid) {
  int cnt = 0;
#pragma unroll
  for (int r = 0; r < 16; ++r) { mreg[r] = mrow[tid + 256 * r]; cnt += (mreg[r] > 0.5f); }
#pragma unroll
  for (int off = 32; off; off >>= 1) cnt += __shfl_xor(cnt, off);
  if ((tid & 63) == 0) i4[tid >> 6] = cnt;
  __syncthreads();
  int n = i4[0] + i4[1] + i4[2] + i4[3];
  __syncthreads();
  return n;
}

__device__ __forceinline__ int kth_index(int n) {
  int cidx = (int)ceilf((float)n * 0.95f);
  if (cidx < 1) cidx = 1;
  int kidx = cidx - 1;
  if (kidx < 0) kidx = 0;
  if (kidx > T_ - 1) kidx = T_ - 1;
  return kidx;
}

// ---------------- Kernel B1: per-(row,metric) percentile scale ----------------
__global__ __launch_bounds__(256)
void scale_k(const float* __restrict__ hc, const float* __restrict__ an,
             const float* __restrict__ sc, const float* __restrict__ amask,
             float* __restrict__ scales) {
  __shared__ unsigned hist[4096];
  __shared__ unsigned sW4[4];
  __shared__ unsigned selb, selk;
  __shared__ float s4[4];
  __shared__ int i4[4];
  int b = blockIdx.x, metric = blockIdx.y, tid = threadIdx.x;
  const float* mrow = amask + (size_t)b * T_;
  float mreg[16];
  int n = count_valid(mrow, mreg, i4, tid);
  int kidx = kth_index(n);
  const float* arr = (metric == 0 ? hc : metric == 1 ? an : sc) + (size_t)b * T_;
  unsigned u[16];
  float mx = 0.f;
#pragma unroll
  for (int r = 0; r < 16; ++r) {
    float v = arr[tid + 256 * r];
    if (mreg[r] > 0.5f) {
      mx = fmaxf(mx, fabsf(v));
      unsigned ub = __float_as_uint(v);
      if ((int)ub < 0) ub = 0u;
      u[r] = ub;
    } else u[r] = INFBITS;
  }
  mx = block_max(mx, s4, tid);
  float kth = fabsf(radix_select(u, (unsigned)kidx, hist, &selb, &selk, sW4, tid));
  if (tid == 0) {
    float s = (kth < 1e-6f) ? mx : kth;
    scales[metric * B_ + b] = fmaxf(s, 1e-6f);
  }
}

// ---------------- Kernel B2: scores + smooth + 4th select + normalize ----------------
__global__ __launch_bounds__(256)
void rule2_k(const float* __restrict__ hc, const float* __restrict__ an,
             const float* __restrict__ sc, const float* __restrict__ ot,
             const float* __restrict__ amask, const float* __restrict__ scales,
             float* __restrict__ rule) {
  __shared__ unsigned hist[4096];
  __shared__ unsigned sW4[4];
  __shared__ unsigned selb, selk;
  __shared__ float vbuf[4096];
  __shared__ float s4[4];
  __shared__ int i4[4];
  int b = blockIdx.x, tid = threadIdx.x;
  const float* mrow = amask + (size_t)b * T_;
  float mreg[16];
  int n = count_valid(mrow, mreg, i4, tid);
  int kidx = kth_index(n);
  float sc0 = scales[0 * B_ + b], sc1 = scales[1 * B_ + b], sc2 = scales[2 * B_ + b];
  const float* hrow = hc + (size_t)b * T_;
  const float* arow = an + (size_t)b * T_;
  const float* srow = sc + (size_t)b * T_;
  const float* otrow = ot + (size_t)b * T_;
#pragma unroll
  for (int r = 0; r < 16; ++r) {
    int t = tid + 256 * r;
    float v = 0.f;
    if (n > 0) {
      v = 0.35f * (hrow[t] / sc0) + 0.30f * (arow[t] / sc1)
        + 0.25f * (srow[t] / sc2) + 0.10f * otrow[t];
    }
    vbuf[t] = v;
  }
  __syncthreads();
  float sm[16];
#pragma unroll
  for (int r = 0; r < 16; ++r) {
    int t = tid + 256 * r;
    float s = 0.f;
#pragma unroll
    for (int d = -2; d <= 2; ++d) {
      int tt = t + d;
      if (tt >= 0 && tt < T_) s += vbuf[tt];
    }
    sm[r] = s * 0.2f * mreg[r];
  }
  unsigned u2[16];
  float mx2 = 0.f;
#pragma unroll
  for (int r = 0; r < 16; ++r) {
    if (mreg[r] > 0.5f) {
      mx2 = fmaxf(mx2, fabsf(sm[r]));
      unsigned ub = __float_as_uint(sm[r]);
      if ((int)ub < 0) ub = 0u;
      u2[r] = ub;
    } else u2[r] = INFBITS;
  }
  mx2 = block_max(mx2, s4, tid);
  float kth4 = fabsf(radix_select(u2, (unsigned)kidx, hist, &selb, &selk, sW4, tid));
  float scale4 = fmaxf((kth4 < 1e-6f) ? mx2 : kth4, 1e-6f);
  float* rrow = rule + (size_t)b * T_;
#pragma unroll
  for (int r = 0; r < 16; ++r) {
    int t = tid + 256 * r;
    float v = (n > 0) ? sm[r] / scale4 : 0.f;
    rrow[t] = clip01(v) * mreg[r];
  }
}

// ---------------- weight repack (unchanged math; now independent, runs first) ----------------
__global__ __launch_bounds__(256)
void repack_k(const float* __restrict__ w1g, const float* __restrict__ w2g,
              half8* __restrict__ w1f, half8* __restrict__ w2f) {
  int gid = blockIdx.x * 256 + threadIdx.x;
  if (gid >= 48 * 64) return;
  int fid = gid >> 6, lane = gid & 63;
  int qd = lane >> 4, ln = lane & 15;
  half8 v;
  if (fid < 8) {
    int m = fid >> 1, kk = fid & 1;
    int o = m * 16 + ln;
#pragma unroll
    for (int j = 0; j < 8; ++j) {
      int ck = kk * 32 + qd * 8 + j;
      float val = 0.f;
      if (ck < 50) { int k_ = ck / 10, c = ck - 10 * k_; val = w1g[o * 50 + c * 5 + k_]; }
      v[j] = (_Float16)val;
    }
    w1f[fid * 64 + lane] = v;
  } else {
    int f2 = fid - 8;
    int k = f2 >> 3, kk = (f2 >> 2) & 1, m = f2 & 3;
    int o = m * 16 + ln;
#pragma unroll
    for (int j = 0; j < 8; ++j) {
      int ic = kk * 32 + qd * 8 + j;
      v[j] = (_Float16)w2g[o * 320 + ic * 5 + k];
    }
    w2f[f2 * 64 + lane] = v;
  }
}

// ---------------- Kernel C: fused featurize + MFMA conv stack ----------------
__global__ __launch_bounds__(512, 4)
void conv_k(const float* __restrict__ traj, const float* __restrict__ intervals,
            const float* __restrict__ amask, const float* __restrict__ omask,
            const half8* __restrict__ w1f, const float* __restrict__ b1g,
            const half8* __restrict__ w2f, const float* __restrict__ b2g,
            const float* __restrict__ w3g, const float* __restrict__ b3g,
            float* __restrict__ lp) {
  __shared__ _Float16 sIm[144 * 72];
  __shared__ _Float16 sH1[132 * 72];
  __shared__ float sF[10 * 136];     // features * 2^-6, columns t0-4 .. t0+131
  __shared__ float sPart[2][128];
  int tid = threadIdx.x;
  int lane = tid & 63, w = tid >> 6;
  int qd = lane >> 4, ln = lane & 15;
  int tile = blockIdx.x, b = blockIdx.y;
  int t0 = tile * TTILE;

  // fused feature staging: threads 0..135 compute the 10 features for t = t0-4+u
  if (tid < 136) {
    int t = t0 - 4 + tid;
    float f[10];
    if (t >= 0 && t < T_) {
      float anv, scv, otv;
      compute_feats(traj + (size_t)b * T_ * 2, intervals + (size_t)b * T_,
                    amask + (size_t)b * T_, omask + (size_t)b * T_, t, f, &anv, &scv, &otv);
    } else {
#pragma unroll
      for (int c = 0; c < 10; ++c) f[c] = 0.f;
    }
#pragma unroll
    for (int c = 0; c < 10; ++c) sF[c * 136 + tid] = f[c] * 0.015625f;
  }
  // zero K-pad cols [50,64) of im2col for ALL rows
  for (int s = tid; s < 144 * 7; s += 512) {
    int jt = s / 7, d = s - jt * 7;
    *reinterpret_cast<unsigned*>(&sIm[jt * 72 + 50 + 2 * d]) = 0u;
  }
  __syncthreads();
  // im2col: B[ck=k*10+c][jt] = sF[c][jt+k], paired half2 stores (RNE)
  for (int s = tid; s < 660; s += 512) {
    int jt = s / 5, k = s - jt * 5;
#pragma unroll
    for (int cp = 0; cp < 5; ++cp) {
      float lo = sF[(2 * cp) * 136 + jt + k];
      float hi = sF[(2 * cp + 1) * 136 + jt + k];
      half2_t pk;
      pk[0] = (_Float16)lo;
      pk[1] = (_Float16)hi;
      *reinterpret_cast<half2_t*>(&sIm[jt * 72 + k * 10 + 2 * cp]) = pk;
    }
  }

  // hoisted weight/bias fragments
  half8 a1[4][2];
#pragma unroll
  for (int m = 0; m < 4; ++m)
#pragma unroll
    for (int kk = 0; kk < 2; ++kk) a1[m][kk] = w1f[(m * 2 + kk) * 64 + lane];
  f32x4 b1s[4];
#pragma unroll
  for (int m = 0; m < 4; ++m) {
    f32x4 bv = *reinterpret_cast<const f32x4*>(&b1g[m * 16 + qd * 4]);
#pragma unroll
    for (int r = 0; r < 4; ++r) b1s[m][r] = bv[r] * 0.015625f;
  }
  __syncthreads();

  // ---- phase 1: conv1 as 36 (tile,m) units round-robin over 8 waves ----
  for (int q = w; q < 36; q += 8) {
    int tl = q >> 2, m = q & 3;
    int jt = tl * 16 + ln;
    half8 bf0 = *reinterpret_cast<const half8*>(&sIm[jt * 72 + qd * 8]);
    half8 bf1 = *reinterpret_cast<const half8*>(&sIm[jt * 72 + 32 + qd * 8]);
    f32x4 acc = b1s[m];
    acc = __builtin_amdgcn_mfma_f32_16x16x32_f16(a1[m][0], bf0, acc, 0, 0, 0);
    acc = __builtin_amdgcn_mfma_f32_16x16x32_f16(a1[m][1], bf1, acc, 0, 0, 0);
    if (jt < 132) {
      int t = t0 - 2 + jt;
      bool inr = (t >= 0 && t < T_);
      half4 hv;
#pragma unroll
      for (int r = 0; r < 4; ++r) {
        float h = inr ? gelu_fast(acc[r] * 64.f) * 0.0625f : 0.f;
        hv[r] = (_Float16)h;
      }
      *reinterpret_cast<half4*>(&sH1[jt * 72 + m * 16 + qd * 4]) = hv;
    }
  }
  __syncthreads();

  // ---- phase 2: conv2 as 5 shifted GEMMs; wave = (m-pair p, n-pair nq) ----
  int p = w & 1, nq = w >> 1;
  f32x4 acc2[2][2];
#pragma unroll
  for (int dm = 0; dm < 2; ++dm) {
    f32x4 bv = *reinterpret_cast<const f32x4*>(&b2g[(2 * p + dm) * 16 + qd * 4]);
#pragma unroll
    for (int dn = 0; dn < 2; ++dn)
#pragma unroll
      for (int r = 0; r < 4; ++r) acc2[dm][dn][r] = bv[r] * 0.0625f;
  }
#pragma unroll
  for (int k = 0; k < 5; ++k) {
#pragma unroll
    for (int kk = 0; kk < 2; ++kk) {
      half8 A0 = w2f[((k * 2 + kk) * 4 + 2 * p + 0) * 64 + lane];
      half8 A1 = w2f[((k * 2 + kk) * 4 + 2 * p + 1) * 64 + lane];
      half8 B0 = *reinterpret_cast<const half8*>(
          &sH1[((2 * nq + 0) * 16 + ln + k) * 72 + kk * 32 + qd * 8]);
      half8 B1 = *reinterpret_cast<const half8*>(
          &sH1[((2 * nq + 1) * 16 + ln + k) * 72 + kk * 32 + qd * 8]);
      acc2[0][0] = __builtin_amdgcn_mfma_f32_16x16x32_f16(A0, B0, acc2[0][0], 0, 0, 0);
      acc2[0][1] = __builtin_amdgcn_mfma_f32_16x16x32_f16(A0, B1, acc2[0][1], 0, 0, 0);
      acc2[1][0] = __builtin_amdgcn_mfma_f32_16x16x32_f16(A1, B0, acc2[1][0], 0, 0, 0);
      acc2[1][1] = __builtin_amdgcn_mfma_f32_16x16x32_f16(A1, B1, acc2[1][1], 0, 0, 0);
    }
  }
  // ---- conv3 + sigmoid epilogue ----
  f32x4 w3a = *reinterpret_cast<const f32x4*>(&w3g[(2 * p + 0) * 16 + qd * 4]);
  f32x4 w3b = *reinterpret_cast<const f32x4*>(&w3g[(2 * p + 1) * 16 + qd * 4]);
#pragma unroll
  for (int dn = 0; dn < 2; ++dn) {
    float s = 0.f;
#pragma unroll
    for (int r = 0; r < 4; ++r) s += w3a[r] * gelu_fast(acc2[0][dn][r] * 16.f);
#pragma unroll
    for (int r = 0; r < 4; ++r) s += w3b[r] * gelu_fast(acc2[1][dn][r] * 16.f);
    s += __shfl_xor(s, 16);
    s += __shfl_xor(s, 32);
    if (lane < 16) sPart[p][(2 * nq + dn) * 16 + lane] = s;
  }
  __syncthreads();
  if (tid < 128) {
    int t = t0 + tid;
    float logit = sPart[0][tid] + sPart[1][tid] + b3g[0];
    float m = amask[(size_t)b * T_ + t];
    float e = __builtin_amdgcn_exp2f(logit * -1.4426950408889634f);
    lp[(size_t)b * T_ + t] = m * __builtin_amdgcn_rcpf(1.f + e);
  }
}

// ---------------- Kernel D: smooth learned + blend (unchanged) ----------------
__global__ __launch_bounds__(256)
void final_k(const float* __restrict__ rule, const float* __restrict__ lp,
             const float* __restrict__ amask, float* __restrict__ out) {
  int idx = blockIdx.x * 256 + threadIdx.x;
  if (idx >= BT) return;
  int t = idx & (T_ - 1);
  float s = 0.f;
#pragma unroll
  for (int d = -2; d <= 2; ++d) {
    int tt = t + d;
    if (tt >= 0 && tt < T_) s += lp[idx + d];
  }
  float m = amask[idx];
  float learned = clip01(s * 0.2f * m);
  out[idx] = clip01(0.5f * rule[idx] + 0.5f * learned) * m;
}

}  // namespace

extern "C" void kernel_launch(void* const* d_in, const int* in_sizes, int n_in,
                              void* d_out, int out_size, void* d_ws, size_t ws_size,
                              hipStream_t stream) {
  const float* traj      = (const float*)d_in[0];
  const float* intervals = (const float*)d_in[1];
  const float* amask     = (const float*)d_in[2];
  const float* omask     = (const float*)d_in[3];
  const float* w1        = (const float*)d_in[4];
  const float* b1        = (const float*)d_in[5];
  const float* w2        = (const float*)d_in[6];
  const float* b2        = (const float*)d_in[7];
  const float* w3        = (const float*)d_in[8];
  const float* b3        = (const float*)d_in[9];
  float* out = (float*)d_out;
  float* ws = (float*)d_ws;

  float* hc   = ws + OFF_HC;
  float* an   = ws + OFF_AN;
  float* sc   = ws + OFF_SC;
  float* ot   = ws + OFF_OT;
  float* rule = ws + OFF_RULE;
  float* lp   = ws + OFF_LP;
  float* scales = ws + OFF_SCALES;
  half8* w1f = (half8*)(ws + OFF_W1F);
  half8* w2f = (half8*)(ws + OFF_W2F);

  repack_k<<<12, 256, 0, stream>>>(w1, w2, w1f, w2f);
  metrics_k<<<BT / 256, 256, 0, stream>>>(traj, intervals, amask, omask, hc, an, sc, ot);
  scale_k<<<dim3(B_, 3), 256, 0, stream>>>(hc, an, sc, amask, scales);
  rule2_k<<<B_, 256, 0, stream>>>(hc, an, sc, ot, amask, scales, rule);
  conv_k<<<dim3(T_ / TTILE, B_), 512, 0, stream>>>(traj, intervals, amask, omask,
                                                   w1f, b1, w2f, b2, w3, b3, lp);
  final_k<<<BT / 256, 256, 0, stream>>>(rule, lp, amask, out);
}

// Round 6
// 189.011 us; speedup vs baseline: 1.4781x; 1.4781x over previous
//
#include <hip/hip_runtime.h>

namespace {

constexpr int B_ = 128;
constexpr int T_ = 4096;
constexpr int BT = B_ * T_;
constexpr int TTILE = 128;
constexpr unsigned INFBITS = 0x7F800000u;

// workspace layout (float offsets); metric arrays eliminated in round 6
constexpr size_t OFF_W1F   = 0;                 // 8 frags * 64 * 8 f16 = 2048 floats
constexpr size_t OFF_W2F   = 2048;              // 40 frags * 64 * 8 f16 = 10240 floats
constexpr size_t OFF_FEATS = 16384;             // B*10*T floats
constexpr size_t OFF_RULE  = OFF_FEATS + (size_t)B_ * 10 * T_;
constexpr size_t OFF_LP    = OFF_RULE + (size_t)BT;

typedef _Float16 half8 __attribute__((ext_vector_type(8)));
typedef _Float16 half4 __attribute__((ext_vector_type(4)));
typedef _Float16 half2_t __attribute__((ext_vector_type(2)));
typedef float f32x4 __attribute__((ext_vector_type(4)));

__device__ __forceinline__ float clip01(float x) { return fminf(fmaxf(x, 0.f), 1.f); }

// branchless GELU via Abramowitz-Stegun 7.1.26 erf (|err| <= 1.5e-7)
__device__ __forceinline__ float gelu_fast(float x) {
  float s = x * 0.7071067811865475f;
  float a = fabsf(s);
  float t = __builtin_amdgcn_rcpf(__builtin_fmaf(0.3275911f, a, 1.0f));
  float p = __builtin_fmaf(t, 1.061405429f, -1.453152027f);
  p = __builtin_fmaf(t, p, 1.421413741f);
  p = __builtin_fmaf(t, p, -0.284496736f);
  p = __builtin_fmaf(t, p, 0.254829592f);
  p = p * t;
  float e = __builtin_amdgcn_exp2f(a * a * -1.4426950408889634f);
  float erfa = __builtin_fmaf(-p, e, 1.0f);
  float erfs = copysignf(erfa, s);
  return 0.5f * x * (1.0f + erfs);
}

// feature math for (b,t) — bit-identical to round-4 featurize_k
__device__ __forceinline__ void compute_feats(
    const float* __restrict__ tr, const float* __restrict__ iv,
    const float* __restrict__ mk, const float* __restrict__ om, int t,
    float* __restrict__ f /*10*/, float* anv_out, float* scv_out, float* otv_out) {
  float m  = mk[t];
  float m1 = (t >= 1) ? mk[t - 1] : 0.f;
  float m2 = (t >= 2) ? mk[t - 2] : 0.f;
  float pm01 = (m > 0.5f && m1 > 0.5f) ? 1.f : 0.f;
  float pm12 = (m1 > 0.5f && m2 > 0.5f) ? 1.f : 0.f;
  float x0x = tr[2 * t] * m, x0y = tr[2 * t + 1] * m;
  float x1x = 0.f, x1y = 0.f, x2x = 0.f, x2y = 0.f;
  if (t >= 1) { x1x = tr[2 * (t - 1)] * m1; x1y = tr[2 * (t - 1) + 1] * m1; }
  if (t >= 2) { x2x = tr[2 * (t - 2)] * m2; x2y = tr[2 * (t - 2) + 1] * m2; }
  float dt0 = fmaxf(iv[t], 1e-3f);
  float dt1 = (t >= 1) ? fmaxf(iv[t - 1], 1e-3f) : 1e-3f;
  float vx = 0.f, vy = 0.f, v1x = 0.f, v1y = 0.f;
  if (t >= 1) { vx = (x0x - x1x) * pm01 / dt0 * m; vy = (x0y - x1y) * pm01 / dt0 * m; }
  if (t >= 2) { v1x = (x1x - x2x) * pm12 / dt1 * m1; v1y = (x1y - x2y) * pm12 / dt1 * m1; }
  float ax = 0.f, ay = 0.f;
  if (t >= 1) { ax = (vx - v1x) * pm01 / dt0 * m; ay = (vy - v1y) * pm01 / dt0 * m; }
  float s2 = vx * vx + vy * vy;
  float speed = (s2 > 0.f ? sqrtf(s2) : 0.f) * m;
  float s21 = v1x * v1x + v1y * v1y;
  float speed1 = (s21 > 0.f ? sqrtf(s21) : 0.f) * m1;
  float scv = (t >= 1) ? fabsf((speed - speed1) * pm01) * m : 0.f;
  float a2 = ax * ax + ay * ay;
  float anv = (a2 > 0.f ? sqrtf(a2) : 0.f) * m;
  float hcv = 0.f;
  if (t >= 1) {
    bool z0 = (vx == 0.f && vy == 0.f);
    bool z1 = (v1x == 0.f && v1y == 0.f);
    float yy, xx;
    if (z1)      { yy = vy;  xx = vx; }
    else if (z0) { yy = v1y; xx = v1x; }
    else { yy = vy * v1x - vx * v1y; xx = vx * v1x + vy * v1y; }
    hcv = fabsf(atan2f(yy, xx)) * pm01 * m;
  }
  float obs = om[t] * m;
  float otv = (t >= 1) ? fminf(fabsf(om[t] - om[t - 1]) * pm01 * m, 1.f) : 0.f;
  float itf = iv[t] * m;
  f[0] = x0x; f[1] = x0y; f[2] = vx; f[3] = vy; f[4] = ax; f[5] = ay;
  f[6] = speed; f[7] = hcv; f[8] = itf; f[9] = obs;
  *anv_out = anv; *scv_out = scv; *otv_out = otv;
}

// ---------------- 1024-thread parallel bucket find ----------------
// hist has NB bins (NB <= 1024*CHUNK; threads past NB contribute 0).
template <int CHUNK, int NB>
__device__ __forceinline__ void find_bucket_1k(const unsigned* __restrict__ hist,
                                               unsigned* selb, unsigned* selk,
                                               unsigned* sW, int tid) {
  unsigned k = *selk;  // stable: set before the barrier preceding this call
  unsigned vals[CHUNK];
  unsigned ps = 0;
#pragma unroll
  for (int c = 0; c < CHUNK; ++c) {
    int idx = tid * CHUNK + c;
    unsigned v = (idx < NB) ? hist[idx] : 0u;
    vals[c] = v; ps += v;
  }
  unsigned incl = ps;
  int lane = tid & 63;
#pragma unroll
  for (int off = 1; off < 64; off <<= 1) {
    unsigned tv = __shfl_up(incl, off, 64);
    if (lane >= off) incl += tv;
  }
  if (lane == 63) sW[tid >> 6] = incl;
  __syncthreads();
  int wid = tid >> 6;
  unsigned woff = 0;
  for (int i = 0; i < wid; ++i) woff += sW[i];
  incl += woff;
  unsigned excl = incl - ps;
  __syncthreads();  // reads of *selk / sW complete before winner writes
  if (excl <= k && k < incl) {
    unsigned run = excl;
    int c = 0;
#pragma unroll
    for (; c < CHUNK - 1; ++c) {
      if (run + vals[c] > k) break;
      run += vals[c];
    }
    *selb = (unsigned)(tid * CHUNK + c);
    *selk = k - run;
  }
  __syncthreads();
}

// exact k-th smallest over 4096 candidates, 4 per thread (bits; cands >= +0, invalid=+inf)
__device__ __forceinline__ float radix_select_1k(const unsigned* u, unsigned k,
                                                 unsigned* hist, unsigned* selb,
                                                 unsigned* selk, unsigned* sW, int tid) {
  for (int i = tid; i < 4096; i += 1024) hist[i] = 0u;
  if (tid == 0) *selk = k;
  __syncthreads();
#pragma unroll
  for (int r = 0; r < 4; ++r) atomicAdd(&hist[u[r] >> 20], 1u);
  __syncthreads();
  find_bucket_1k<4, 4096>(hist, selb, selk, sW, tid);
  unsigned p1 = *selb;
  for (int i = tid; i < 4096; i += 1024) hist[i] = 0u;
  __syncthreads();
#pragma unroll
  for (int r = 0; r < 4; ++r)
    if ((u[r] >> 20) == p1) atomicAdd(&hist[(u[r] >> 8) & 0xFFFu], 1u);
  __syncthreads();
  find_bucket_1k<4, 4096>(hist, selb, selk, sW, tid);
  unsigned p2 = *selb;
  unsigned pref = (p1 << 12) | p2;
  if (tid < 256) hist[tid] = 0u;
  __syncthreads();
#pragma unroll
  for (int r = 0; r < 4; ++r)
    if ((u[r] >> 8) == pref) atomicAdd(&hist[u[r] & 0xFFu], 1u);
  __syncthreads();
  find_bucket_1k<1, 256>(hist, selb, selk, sW, tid);
  unsigned p3 = *selb;
  __syncthreads();
  return __uint_as_float((p1 << 20) | (p2 << 8) | p3);
}

__device__ __forceinline__ float block_max_1k(float v, float* sM, int tid) {
#pragma unroll
  for (int off = 32; off; off >>= 1) v = fmaxf(v, __shfl_xor(v, off));
  if ((tid & 63) == 0) sM[tid >> 6] = v;
  __syncthreads();
  float m = sM[0];
#pragma unroll
  for (int i = 1; i < 16; ++i) m = fmaxf(m, sM[i]);
  __syncthreads();
  return m;
}

// ---------------- Kernel B: fused featurize + rule scores (one block per row) ----------------
__global__ __launch_bounds__(1024)
void rulefuse_k(const float* __restrict__ traj, const float* __restrict__ intervals,
                const float* __restrict__ amask, const float* __restrict__ omask,
                float* __restrict__ feats, float* __restrict__ rule) {
  __shared__ unsigned hist[4096];
  __shared__ unsigned sW[16];
  __shared__ unsigned selb, selk;
  __shared__ float vbuf[4096];
  __shared__ float sM[16];
  __shared__ int iCnt[16];
  __shared__ int n_sh;
  __shared__ float scale_sh[3];
  int b = blockIdx.x, tid = threadIdx.x;
  const float* tr = traj + (size_t)b * T_ * 2;
  const float* iv = intervals + (size_t)b * T_;
  const float* mk = amask + (size_t)b * T_;
  const float* om = omask + (size_t)b * T_;
  float* frow = feats + (size_t)b * 10 * T_;

  float hcv[4], anv[4], scv[4], otv[4], mreg[4];
  int cnt = 0;
  for (int r = 0; r < 4; ++r) {
    int t = tid + 1024 * r;
    float f[10], a, s, o;
    compute_feats(tr, iv, mk, om, t, f, &a, &s, &o);
#pragma unroll
    for (int c = 0; c < 10; ++c) frow[(size_t)c * T_ + t] = f[c];
    hcv[r] = f[7]; anv[r] = a; scv[r] = s; otv[r] = o;
    mreg[r] = mk[t];
    cnt += (mreg[r] > 0.5f);
  }
#pragma unroll
  for (int off = 32; off; off >>= 1) cnt += __shfl_xor(cnt, off);
  if ((tid & 63) == 0) iCnt[tid >> 6] = cnt;
  __syncthreads();
  if (tid == 0) {
    int n = 0;
#pragma unroll
    for (int i = 0; i < 16; ++i) n += iCnt[i];
    n_sh = n;
  }
  __syncthreads();
  int n = n_sh;
  int cidx = (int)ceilf((float)n * 0.95f);
  if (cidx < 1) cidx = 1;
  int kidx = cidx - 1;
  if (kidx < 0) kidx = 0;
  if (kidx > T_ - 1) kidx = T_ - 1;

  // 3 metric percentile scales (exact)
  for (int m3 = 0; m3 < 3; ++m3) {
    unsigned u[4];
    float mx = 0.f;
#pragma unroll
    for (int r = 0; r < 4; ++r) {
      float v = (m3 == 0 ? hcv[r] : m3 == 1 ? anv[r] : scv[r]);
      if (mreg[r] > 0.5f) {
        mx = fmaxf(mx, fabsf(v));
        unsigned ub = __float_as_uint(v);
        if ((int)ub < 0) ub = 0u;  // -0.0 safety
        u[r] = ub;
      } else u[r] = INFBITS;
    }
    mx = block_max_1k(mx, sM, tid);
    float kth = fabsf(radix_select_1k(u, (unsigned)kidx, hist, &selb, &selk, sW, tid));
    if (tid == 0) {
      float s = (kth < 1e-6f) ? mx : kth;
      scale_sh[m3] = fmaxf(s, 1e-6f);
    }
  }
  __syncthreads();
  float sc0 = scale_sh[0], sc1 = scale_sh[1], sc2 = scale_sh[2];
#pragma unroll
  for (int r = 0; r < 4; ++r) {
    int t = tid + 1024 * r;
    float v = 0.f;
    if (n > 0) {
      v = 0.35f * (hcv[r] / sc0) + 0.30f * (anv[r] / sc1)
        + 0.25f * (scv[r] / sc2) + 0.10f * otv[r];
    }
    vbuf[t] = v;
  }
  __syncthreads();
  float sm[4];
#pragma unroll
  for (int r = 0; r < 4; ++r) {
    int t = tid + 1024 * r;
    float s = 0.f;
#pragma unroll
    for (int d = -2; d <= 2; ++d) {
      int tt = t + d;
      if (tt >= 0 && tt < T_) s += vbuf[tt];
    }
    sm[r] = s * 0.2f * mreg[r];
  }
  unsigned u2[4];
  float mx2 = 0.f;
#pragma unroll
  for (int r = 0; r < 4; ++r) {
    if (mreg[r] > 0.5f) {
      mx2 = fmaxf(mx2, fabsf(sm[r]));
      unsigned ub = __float_as_uint(sm[r]);
      if ((int)ub < 0) ub = 0u;
      u2[r] = ub;
    } else u2[r] = INFBITS;
  }
  mx2 = block_max_1k(mx2, sM, tid);
  float kth4 = fabsf(radix_select_1k(u2, (unsigned)kidx, hist, &selb, &selk, sW, tid));
  float scale4 = fmaxf((kth4 < 1e-6f) ? mx2 : kth4, 1e-6f);
  float* rrow = rule + (size_t)b * T_;
#pragma unroll
  for (int r = 0; r < 4; ++r) {
    int t = tid + 1024 * r;
    float v = (n > 0) ? sm[r] / scale4 : 0.f;
    rrow[t] = clip01(v) * mreg[r];
  }
}

// ---------------- weight repack (unchanged) ----------------
__global__ __launch_bounds__(256)
void repack_k(const float* __restrict__ w1g, const float* __restrict__ w2g,
              half8* __restrict__ w1f, half8* __restrict__ w2f) {
  int gid = blockIdx.x * 256 + threadIdx.x;
  if (gid >= 48 * 64) return;
  int fid = gid >> 6, lane = gid & 63;
  int qd = lane >> 4, ln = lane & 15;
  half8 v;
  if (fid < 8) {
    int m = fid >> 1, kk = fid & 1;
    int o = m * 16 + ln;
#pragma unroll
    for (int j = 0; j < 8; ++j) {
      int ck = kk * 32 + qd * 8 + j;
      float val = 0.f;
      if (ck < 50) { int k_ = ck / 10, c = ck - 10 * k_; val = w1g[o * 50 + c * 5 + k_]; }
      v[j] = (_Float16)val;
    }
    w1f[fid * 64 + lane] = v;
  } else {
    int f2 = fid - 8;
    int k = f2 >> 3, kk = (f2 >> 2) & 1, m = f2 & 3;
    int o = m * 16 + ln;
#pragma unroll
    for (int j = 0; j < 8; ++j) {
      int ic = kk * 32 + qd * 8 + j;
      v[j] = (_Float16)w2g[o * 320 + ic * 5 + k];
    }
    w2f[f2 * 64 + lane] = v;
  }
}

// ---------------- Kernel C: MFMA conv stack (exact round-4 version, 81.5 us) ----------------
__global__ __launch_bounds__(512, 4)
void conv_k(const float* __restrict__ feats, const half8* __restrict__ w1f,
            const float* __restrict__ b1g, const half8* __restrict__ w2f,
            const float* __restrict__ b2g, const float* __restrict__ w3g,
            const float* __restrict__ b3g, const float* __restrict__ amask,
            float* __restrict__ lp) {
  __shared__ _Float16 sIm[144 * 72];
  __shared__ _Float16 sH1[132 * 72];
  __shared__ float sF[10 * 136];
  __shared__ float sPart[2][128];
  int tid = threadIdx.x;
  int lane = tid & 63, w = tid >> 6;
  int qd = lane >> 4, ln = lane & 15;
  int tile = blockIdx.x, b = blockIdx.y;
  int t0 = tile * TTILE;
  const float* frow = feats + (size_t)b * 10 * T_;

  // stage fp32 feats tile, pre-scaled by 2^-6 (only consumer is im2col)
  for (int s = tid; s < 1360; s += 512) {
    int c = s / 136, u = s - c * 136;
    int t = t0 - 4 + u;
    sF[s] = (t >= 0 && t < T_) ? frow[(size_t)c * T_ + t] * 0.015625f : 0.f;
  }
  for (int s = tid; s < 144 * 7; s += 512) {
    int jt = s / 7, d = s - jt * 7;
    *reinterpret_cast<unsigned*>(&sIm[jt * 72 + 50 + 2 * d]) = 0u;
  }
  __syncthreads();
  // im2col: B[ck=k*10+c][jt] = feats[c][t0-4+jt+k] * 2^-6, paired half2 stores (RNE)
  for (int s = tid; s < 660; s += 512) {
    int jt = s / 5, k = s - jt * 5;
#pragma unroll
    for (int cp = 0; cp < 5; ++cp) {
      float lo = sF[(2 * cp) * 136 + jt + k];
      float hi = sF[(2 * cp + 1) * 136 + jt + k];
      half2_t pk;
      pk[0] = (_Float16)lo;
      pk[1] = (_Float16)hi;
      *reinterpret_cast<half2_t*>(&sIm[jt * 72 + k * 10 + 2 * cp]) = pk;
    }
  }
  __syncthreads();

  half8 a1[4][2];
#pragma unroll
  for (int m = 0; m < 4; ++m)
#pragma unroll
    for (int kk = 0; kk < 2; ++kk) a1[m][kk] = w1f[(m * 2 + kk) * 64 + lane];

  for (int n0 = w; n0 < 9; n0 += 8) {
    int jt = n0 * 16 + ln;
    half8 bf0 = *reinterpret_cast<const half8*>(&sIm[jt * 72 + qd * 8]);
    half8 bf1 = *reinterpret_cast<const half8*>(&sIm[jt * 72 + 32 + qd * 8]);
#pragma unroll
    for (int m = 0; m < 4; ++m) {
      f32x4 acc;
      f32x4 bv = *reinterpret_cast<const f32x4*>(&b1g[m * 16 + qd * 4]);
#pragma unroll
      for (int r = 0; r < 4; ++r) acc[r] = bv[r] * 0.015625f;
      acc = __builtin_amdgcn_mfma_f32_16x16x32_f16(a1[m][0], bf0, acc, 0, 0, 0);
      acc = __builtin_amdgcn_mfma_f32_16x16x32_f16(a1[m][1], bf1, acc, 0, 0, 0);
      if (jt < 132) {
        int t = t0 - 2 + jt;
        bool inr = (t >= 0 && t < T_);
        half4 hv;
#pragma unroll
        for (int r = 0; r < 4; ++r) {
          float h = inr ? gelu_fast(acc[r] * 64.f) * 0.0625f : 0.f;
          hv[r] = (_Float16)h;
        }
        *reinterpret_cast<half4*>(&sH1[jt * 72 + m * 16 + qd * 4]) = hv;
      }
    }
  }
  __syncthreads();

  int p = w & 1, nq = w >> 1;
  f32x4 acc2[2][2];
#pragma unroll
  for (int dm = 0; dm < 2; ++dm) {
    f32x4 bv = *reinterpret_cast<const f32x4*>(&b2g[(2 * p + dm) * 16 + qd * 4]);
#pragma unroll
    for (int dn = 0; dn < 2; ++dn)
#pragma unroll
      for (int r = 0; r < 4; ++r) acc2[dm][dn][r] = bv[r] * 0.0625f;
  }
#pragma unroll
  for (int k = 0; k < 5; ++k) {
#pragma unroll
    for (int kk = 0; kk < 2; ++kk) {
      half8 A0 = w2f[((k * 2 + kk) * 4 + 2 * p + 0) * 64 + lane];
      half8 A1 = w2f[((k * 2 + kk) * 4 + 2 * p + 1) * 64 + lane];
      half8 B0 = *reinterpret_cast<const half8*>(
          &sH1[((2 * nq + 0) * 16 + ln + k) * 72 + kk * 32 + qd * 8]);
      half8 B1 = *reinterpret_cast<const half8*>(
          &sH1[((2 * nq + 1) * 16 + ln + k) * 72 + kk * 32 + qd * 8]);
      acc2[0][0] = __builtin_amdgcn_mfma_f32_16x16x32_f16(A0, B0, acc2[0][0], 0, 0, 0);
      acc2[0][1] = __builtin_amdgcn_mfma_f32_16x16x32_f16(A0, B1, acc2[0][1], 0, 0, 0);
      acc2[1][0] = __builtin_amdgcn_mfma_f32_16x16x32_f16(A1, B0, acc2[1][0], 0, 0, 0);
      acc2[1][1] = __builtin_amdgcn_mfma_f32_16x16x32_f16(A1, B1, acc2[1][1], 0, 0, 0);
    }
  }
  f32x4 w3a = *reinterpret_cast<const f32x4*>(&w3g[(2 * p + 0) * 16 + qd * 4]);
  f32x4 w3b = *reinterpret_cast<const f32x4*>(&w3g[(2 * p + 1) * 16 + qd * 4]);
#pragma unroll
  for (int dn = 0; dn < 2; ++dn) {
    float s = 0.f;
#pragma unroll
    for (int r = 0; r < 4; ++r) s += w3a[r] * gelu_fast(acc2[0][dn][r] * 16.f);
#pragma unroll
    for (int r = 0; r < 4; ++r) s += w3b[r] * gelu_fast(acc2[1][dn][r] * 16.f);
    s += __shfl_xor(s, 16);
    s += __shfl_xor(s, 32);
    if (lane < 16) sPart[p][(2 * nq + dn) * 16 + lane] = s;
  }
  __syncthreads();
  if (tid < 128) {
    int t = t0 + tid;
    float logit = sPart[0][tid] + sPart[1][tid] + b3g[0];
    float m = amask[(size_t)b * T_ + t];
    lp[(size_t)b * T_ + t] = (1.f / (1.f + expf(-logit))) * m;
  }
}

// ---------------- Kernel D: smooth learned + blend (unchanged) ----------------
__global__ __launch_bounds__(256)
void final_k(const float* __restrict__ rule, const float* __restrict__ lp,
             const float* __restrict__ amask, float* __restrict__ out) {
  int idx = blockIdx.x * 256 + threadIdx.x;
  if (idx >= BT) return;
  int t = idx & (T_ - 1);
  float s = 0.f;
#pragma unroll
  for (int d = -2; d <= 2; ++d) {
    int tt = t + d;
    if (tt >= 0 && tt < T_) s += lp[idx + d];
  }
  float m = amask[idx];
  float learned = clip01(s * 0.2f * m);
  out[idx] = clip01(0.5f * rule[idx] + 0.5f * learned) * m;
}

}  // namespace

extern "C" void kernel_launch(void* const* d_in, const int* in_sizes, int n_in,
                              void* d_out, int out_size, void* d_ws, size_t ws_size,
                              hipStream_t stream) {
  const float* traj      = (const float*)d_in[0];
  const float* intervals = (const float*)d_in[1];
  const float* amask     = (const float*)d_in[2];
  const float* omask     = (const float*)d_in[3];
  const float* w1        = (const float*)d_in[4];
  const float* b1        = (const float*)d_in[5];
  const float* w2        = (const float*)d_in[6];
  const float* b2        = (const float*)d_in[7];
  const float* w3        = (const float*)d_in[8];
  const float* b3        = (const float*)d_in[9];
  float* out = (float*)d_out;
  float* ws = (float*)d_ws;

  float* feats = ws + OFF_FEATS;
  float* rule  = ws + OFF_RULE;
  float* lp    = ws + OFF_LP;
  half8* w1f = (half8*)(ws + OFF_W1F);
  half8* w2f = (half8*)(ws + OFF_W2F);

  repack_k<<<12, 256, 0, stream>>>(w1, w2, w1f, w2f);
  rulefuse_k<<<B_, 1024, 0, stream>>>(traj, intervals, amask, omask, feats, rule);
  conv_k<<<dim3(T_ / TTILE, B_), 512, 0, stream>>>(feats, w1f, b1, w2f, b2, w3, b3,
                                                   amask, lp);
  final_k<<<BT / 256, 256, 0, stream>>>(rule, lp, amask, out);
}

// Round 7
// 184.218 us; speedup vs baseline: 1.5166x; 1.0260x over previous
//
#include <hip/hip_runtime.h>

namespace {

constexpr int B_ = 128;
constexpr int T_ = 4096;
constexpr int BT = B_ * T_;
constexpr int TTILE = 128;
constexpr unsigned NOINS = 0xFFFFFFFFu;  // "do not insert" sentinel (invalid/masked lane)

// workspace layout (float offsets)
constexpr size_t OFF_W1F   = 0;                 // 8 frags * 64 * 8 f16 = 2048 floats
constexpr size_t OFF_W2F   = 2048;              // 40 frags * 64 * 8 f16 = 10240 floats
constexpr size_t OFF_FEATS = 16384;             // B*10*T floats
constexpr size_t OFF_RULE  = OFF_FEATS + (size_t)B_ * 10 * T_;
constexpr size_t OFF_LP    = OFF_RULE + (size_t)BT;

typedef _Float16 half8 __attribute__((ext_vector_type(8)));
typedef _Float16 half4 __attribute__((ext_vector_type(4)));
typedef _Float16 half2_t __attribute__((ext_vector_type(2)));
typedef float f32x4 __attribute__((ext_vector_type(4)));

__device__ __forceinline__ float clip01(float x) { return fminf(fmaxf(x, 0.f), 1.f); }

// branchless GELU via Abramowitz-Stegun 7.1.26 erf (|err| <= 1.5e-7)
__device__ __forceinline__ float gelu_fast(float x) {
  float s = x * 0.7071067811865475f;
  float a = fabsf(s);
  float t = __builtin_amdgcn_rcpf(__builtin_fmaf(0.3275911f, a, 1.0f));
  float p = __builtin_fmaf(t, 1.061405429f, -1.453152027f);
  p = __builtin_fmaf(t, p, 1.421413741f);
  p = __builtin_fmaf(t, p, -0.284496736f);
  p = __builtin_fmaf(t, p, 0.254829592f);
  p = p * t;
  float e = __builtin_amdgcn_exp2f(a * a * -1.4426950408889634f);
  float erfa = __builtin_fmaf(-p, e, 1.0f);
  float erfs = copysignf(erfa, s);
  return 0.5f * x * (1.0f + erfs);
}

// feature math for (b,t) — bit-identical to round-4 featurize_k
__device__ __forceinline__ void compute_feats(
    const float* __restrict__ tr, const float* __restrict__ iv,
    const float* __restrict__ mk, const float* __restrict__ om, int t,
    float* __restrict__ f /*10*/, float* anv_out, float* scv_out, float* otv_out) {
  float m  = mk[t];
  float m1 = (t >= 1) ? mk[t - 1] : 0.f;
  float m2 = (t >= 2) ? mk[t - 2] : 0.f;
  float pm01 = (m > 0.5f && m1 > 0.5f) ? 1.f : 0.f;
  float pm12 = (m1 > 0.5f && m2 > 0.5f) ? 1.f : 0.f;
  float x0x = tr[2 * t] * m, x0y = tr[2 * t + 1] * m;
  float x1x = 0.f, x1y = 0.f, x2x = 0.f, x2y = 0.f;
  if (t >= 1) { x1x = tr[2 * (t - 1)] * m1; x1y = tr[2 * (t - 1) + 1] * m1; }
  if (t >= 2) { x2x = tr[2 * (t - 2)] * m2; x2y = tr[2 * (t - 2) + 1] * m2; }
  float dt0 = fmaxf(iv[t], 1e-3f);
  float dt1 = (t >= 1) ? fmaxf(iv[t - 1], 1e-3f) : 1e-3f;
  float vx = 0.f, vy = 0.f, v1x = 0.f, v1y = 0.f;
  if (t >= 1) { vx = (x0x - x1x) * pm01 / dt0 * m; vy = (x0y - x1y) * pm01 / dt0 * m; }
  if (t >= 2) { v1x = (x1x - x2x) * pm12 / dt1 * m1; v1y = (x1y - x2y) * pm12 / dt1 * m1; }
  float ax = 0.f, ay = 0.f;
  if (t >= 1) { ax = (vx - v1x) * pm01 / dt0 * m; ay = (vy - v1y) * pm01 / dt0 * m; }
  float s2 = vx * vx + vy * vy;
  float speed = (s2 > 0.f ? sqrtf(s2) : 0.f) * m;
  float s21 = v1x * v1x + v1y * v1y;
  float speed1 = (s21 > 0.f ? sqrtf(s21) : 0.f) * m1;
  float scv = (t >= 1) ? fabsf((speed - speed1) * pm01) * m : 0.f;
  float a2 = ax * ax + ay * ay;
  float anv = (a2 > 0.f ? sqrtf(a2) : 0.f) * m;
  float hcv = 0.f;
  if (t >= 1) {
    bool z0 = (vx == 0.f && vy == 0.f);
    bool z1 = (v1x == 0.f && v1y == 0.f);
    float yy, xx;
    if (z1)      { yy = vy;  xx = vx; }
    else if (z0) { yy = v1y; xx = v1x; }
    else { yy = vy * v1x - vx * v1y; xx = vx * v1x + vy * v1y; }
    hcv = fabsf(atan2f(yy, xx)) * pm01 * m;
  }
  float obs = om[t] * m;
  float otv = (t >= 1) ? fminf(fabsf(om[t] - om[t - 1]) * pm01 * m, 1.f) : 0.f;
  float itf = iv[t] * m;
  f[0] = x0x; f[1] = x0y; f[2] = vx; f[3] = vy; f[4] = ax; f[5] = ay;
  f[6] = speed; f[7] = hcv; f[8] = itf; f[9] = obs;
  *anv_out = anv; *scv_out = scv; *otv_out = otv;
}

// ---------------- 1024-thread parallel bucket find ----------------
template <int CHUNK, int NB>
__device__ __forceinline__ void find_bucket_1k(const unsigned* __restrict__ hist,
                                               unsigned* selb, unsigned* selk,
                                               unsigned* sW, int tid) {
  unsigned k = *selk;  // stable: set before the barrier preceding this call
  unsigned vals[CHUNK];
  unsigned ps = 0;
#pragma unroll
  for (int c = 0; c < CHUNK; ++c) {
    int idx = tid * CHUNK + c;
    unsigned v = (idx < NB) ? hist[idx] : 0u;
    vals[c] = v; ps += v;
  }
  unsigned incl = ps;
  int lane = tid & 63;
#pragma unroll
  for (int off = 1; off < 64; off <<= 1) {
    unsigned tv = __shfl_up(incl, off, 64);
    if (lane >= off) incl += tv;
  }
  if (lane == 63) sW[tid >> 6] = incl;
  __syncthreads();
  int wid = tid >> 6;
  unsigned woff = 0;
  for (int i = 0; i < wid; ++i) woff += sW[i];
  incl += woff;
  unsigned excl = incl - ps;
  __syncthreads();  // reads of *selk / sW complete before winner writes
  if (excl <= k && k < incl) {
    unsigned run = excl;
    int c = 0;
#pragma unroll
    for (; c < CHUNK - 1; ++c) {
      if (run + vals[c] > k) break;
      run += vals[c];
    }
    *selb = (unsigned)(tid * CHUNK + c);
    *selk = k - run;
  }
  __syncthreads();
}

// exact k-th smallest among VALID candidates (u[r]==NOINS lanes never inserted;
// legal because kidx < n so an invalid (+inf) entry can never be the answer).
__device__ __forceinline__ float radix_select_1k(const unsigned* u, unsigned k,
                                                 unsigned* hist, unsigned* selb,
                                                 unsigned* selk, unsigned* sW, int tid) {
  for (int i = tid; i < 4096; i += 1024) hist[i] = 0u;
  if (tid == 0) *selk = k;
  __syncthreads();
#pragma unroll
  for (int r = 0; r < 4; ++r)
    if (u[r] != NOINS) atomicAdd(&hist[u[r] >> 20], 1u);
  __syncthreads();
  find_bucket_1k<4, 4096>(hist, selb, selk, sW, tid);
  unsigned p1 = *selb;
  for (int i = tid; i < 4096; i += 1024) hist[i] = 0u;
  __syncthreads();
#pragma unroll
  for (int r = 0; r < 4; ++r)
    if (u[r] != NOINS && (u[r] >> 20) == p1) atomicAdd(&hist[(u[r] >> 8) & 0xFFFu], 1u);
  __syncthreads();
  find_bucket_1k<4, 4096>(hist, selb, selk, sW, tid);
  unsigned p2 = *selb;
  unsigned pref = (p1 << 12) | p2;
  if (tid < 256) hist[tid] = 0u;
  __syncthreads();
#pragma unroll
  for (int r = 0; r < 4; ++r)
    if (u[r] != NOINS && (u[r] >> 8) == pref) atomicAdd(&hist[u[r] & 0xFFu], 1u);
  __syncthreads();
  find_bucket_1k<1, 256>(hist, selb, selk, sW, tid);
  unsigned p3 = *selb;
  __syncthreads();
  return __uint_as_float((p1 << 20) | (p2 << 8) | p3);
}

__device__ __forceinline__ float block_max_1k(float v, float* sM, int tid) {
#pragma unroll
  for (int off = 32; off; off >>= 1) v = fmaxf(v, __shfl_xor(v, off));
  if ((tid & 63) == 0) sM[tid >> 6] = v;
  __syncthreads();
  float m = sM[0];
#pragma unroll
  for (int i = 1; i < 16; ++i) m = fmaxf(m, sM[i]);
  __syncthreads();
  return m;
}

// ---------------- Kernel B: fused featurize + rule scores (one block per row) ----------------
__global__ __launch_bounds__(1024)
void rulefuse_k(const float* __restrict__ traj, const float* __restrict__ intervals,
                const float* __restrict__ amask, const float* __restrict__ omask,
                float* __restrict__ feats, float* __restrict__ rule) {
  __shared__ unsigned hist[4096];
  __shared__ unsigned sW[16];
  __shared__ unsigned selb, selk;
  __shared__ float vbuf[4096];
  __shared__ float sM[16];
  __shared__ int iCnt[16];
  __shared__ int n_sh;
  __shared__ float scale_sh[3];
  int b = blockIdx.x, tid = threadIdx.x;
  const float* tr = traj + (size_t)b * T_ * 2;
  const float* iv = intervals + (size_t)b * T_;
  const float* mk = amask + (size_t)b * T_;
  const float* om = omask + (size_t)b * T_;
  float* frow = feats + (size_t)b * 10 * T_;

  float hcv[4], anv[4], scv[4], otv[4], mreg[4];
  int cnt = 0;
  for (int r = 0; r < 4; ++r) {
    int t = tid + 1024 * r;
    float f[10], a, s, o;
    compute_feats(tr, iv, mk, om, t, f, &a, &s, &o);
#pragma unroll
    for (int c = 0; c < 10; ++c) frow[(size_t)c * T_ + t] = f[c];
    hcv[r] = f[7]; anv[r] = a; scv[r] = s; otv[r] = o;
    mreg[r] = mk[t];
    cnt += (mreg[r] > 0.5f);
  }
#pragma unroll
  for (int off = 32; off; off >>= 1) cnt += __shfl_xor(cnt, off);
  if ((tid & 63) == 0) iCnt[tid >> 6] = cnt;
  __syncthreads();
  if (tid == 0) {
    int n = 0;
#pragma unroll
    for (int i = 0; i < 16; ++i) n += iCnt[i];
    n_sh = n;
  }
  __syncthreads();
  int n = n_sh;
  int cidx = (int)ceilf((float)n * 0.95f);
  if (cidx < 1) cidx = 1;
  int kidx = cidx - 1;
  if (kidx < 0) kidx = 0;
  if (kidx > T_ - 1) kidx = T_ - 1;

  // 3 metric percentile scales (exact; invalid lanes never inserted)
  for (int m3 = 0; m3 < 3; ++m3) {
    unsigned u[4];
    float mx = 0.f;
#pragma unroll
    for (int r = 0; r < 4; ++r) {
      float v = (m3 == 0 ? hcv[r] : m3 == 1 ? anv[r] : scv[r]);
      if (mreg[r] > 0.5f) {
        mx = fmaxf(mx, fabsf(v));
        unsigned ub = __float_as_uint(v);
        if ((int)ub < 0) ub = 0u;  // -0.0 safety
        u[r] = ub;
      } else u[r] = NOINS;
    }
    mx = block_max_1k(mx, sM, tid);
    float kth = fabsf(radix_select_1k(u, (unsigned)kidx, hist, &selb, &selk, sW, tid));
    if (tid == 0) {
      float s = (kth < 1e-6f) ? mx : kth;
      scale_sh[m3] = fmaxf(s, 1e-6f);
    }
  }
  __syncthreads();
  float sc0 = scale_sh[0], sc1 = scale_sh[1], sc2 = scale_sh[2];
#pragma unroll
  for (int r = 0; r < 4; ++r) {
    int t = tid + 1024 * r;
    float v = 0.f;
    if (n > 0) {
      v = 0.35f * (hcv[r] / sc0) + 0.30f * (anv[r] / sc1)
        + 0.25f * (scv[r] / sc2) + 0.10f * otv[r];
    }
    vbuf[t] = v;
  }
  __syncthreads();
  float sm[4];
#pragma unroll
  for (int r = 0; r < 4; ++r) {
    int t = tid + 1024 * r;
    float s = 0.f;
#pragma unroll
    for (int d = -2; d <= 2; ++d) {
      int tt = t + d;
      if (tt >= 0 && tt < T_) s += vbuf[tt];
    }
    sm[r] = s * 0.2f * mreg[r];
  }
  unsigned u2[4];
  float mx2 = 0.f;
#pragma unroll
  for (int r = 0; r < 4; ++r) {
    if (mreg[r] > 0.5f) {
      mx2 = fmaxf(mx2, fabsf(sm[r]));
      unsigned ub = __float_as_uint(sm[r]);
      if ((int)ub < 0) ub = 0u;
      u2[r] = ub;
    } else u2[r] = NOINS;
  }
  mx2 = block_max_1k(mx2, sM, tid);
  float kth4 = fabsf(radix_select_1k(u2, (unsigned)kidx, hist, &selb, &selk, sW, tid));
  float scale4 = fmaxf((kth4 < 1e-6f) ? mx2 : kth4, 1e-6f);
  float* rrow = rule + (size_t)b * T_;
#pragma unroll
  for (int r = 0; r < 4; ++r) {
    int t = tid + 1024 * r;
    float v = (n > 0) ? sm[r] / scale4 : 0.f;
    rrow[t] = clip01(v) * mreg[r];
  }
}

// ---------------- weight repack (unchanged) ----------------
__global__ __launch_bounds__(256)
void repack_k(const float* __restrict__ w1g, const float* __restrict__ w2g,
              half8* __restrict__ w1f, half8* __restrict__ w2f) {
  int gid = blockIdx.x * 256 + threadIdx.x;
  if (gid >= 48 * 64) return;
  int fid = gid >> 6, lane = gid & 63;
  int qd = lane >> 4, ln = lane & 15;
  half8 v;
  if (fid < 8) {
    int m = fid >> 1, kk = fid & 1;
    int o = m * 16 + ln;
#pragma unroll
    for (int j = 0; j < 8; ++j) {
      int ck = kk * 32 + qd * 8 + j;
      float val = 0.f;
      if (ck < 50) { int k_ = ck / 10, c = ck - 10 * k_; val = w1g[o * 50 + c * 5 + k_]; }
      v[j] = (_Float16)val;
    }
    w1f[fid * 64 + lane] = v;
  } else {
    int f2 = fid - 8;
    int k = f2 >> 3, kk = (f2 >> 2) & 1, m = f2 & 3;
    int o = m * 16 + ln;
#pragma unroll
    for (int j = 0; j < 8; ++j) {
      int ic = kk * 32 + qd * 8 + j;
      v[j] = (_Float16)w2g[o * 320 + ic * 5 + k];
    }
    w2f[f2 * 64 + lane] = v;
  }
}

// ---------------- Kernel C: MFMA conv stack (exact round-4 version, 81 us) ----------------
__global__ __launch_bounds__(512, 4)
void conv_k(const float* __restrict__ feats, const half8* __restrict__ w1f,
            const float* __restrict__ b1g, const half8* __restrict__ w2f,
            const float* __restrict__ b2g, const float* __restrict__ w3g,
            const float* __restrict__ b3g, const float* __restrict__ amask,
            float* __restrict__ lp) {
  __shared__ _Float16 sIm[144 * 72];
  __shared__ _Float16 sH1[132 * 72];
  __shared__ float sF[10 * 136];
  __shared__ float sPart[2][128];
  int tid = threadIdx.x;
  int lane = tid & 63, w = tid >> 6;
  int qd = lane >> 4, ln = lane & 15;
  int tile = blockIdx.x, b = blockIdx.y;
  int t0 = tile * TTILE;
  const float* frow = feats + (size_t)b * 10 * T_;

  for (int s = tid; s < 1360; s += 512) {
    int c = s / 136, u = s - c * 136;
    int t = t0 - 4 + u;
    sF[s] = (t >= 0 && t < T_) ? frow[(size_t)c * T_ + t] * 0.015625f : 0.f;
  }
  for (int s = tid; s < 144 * 7; s += 512) {
    int jt = s / 7, d = s - jt * 7;
    *reinterpret_cast<unsigned*>(&sIm[jt * 72 + 50 + 2 * d]) = 0u;
  }
  __syncthreads();
  for (int s = tid; s < 660; s += 512) {
    int jt = s / 5, k = s - jt * 5;
#pragma unroll
    for (int cp = 0; cp < 5; ++cp) {
      float lo = sF[(2 * cp) * 136 + jt + k];
      float hi = sF[(2 * cp + 1) * 136 + jt + k];
      half2_t pk;
      pk[0] = (_Float16)lo;
      pk[1] = (_Float16)hi;
      *reinterpret_cast<half2_t*>(&sIm[jt * 72 + k * 10 + 2 * cp]) = pk;
    }
  }
  __syncthreads();

  half8 a1[4][2];
#pragma unroll
  for (int m = 0; m < 4; ++m)
#pragma unroll
    for (int kk = 0; kk < 2; ++kk) a1[m][kk] = w1f[(m * 2 + kk) * 64 + lane];

  for (int n0 = w; n0 < 9; n0 += 8) {
    int jt = n0 * 16 + ln;
    half8 bf0 = *reinterpret_cast<const half8*>(&sIm[jt * 72 + qd * 8]);
    half8 bf1 = *reinterpret_cast<const half8*>(&sIm[jt * 72 + 32 + qd * 8]);
#pragma unroll
    for (int m = 0; m < 4; ++m) {
      f32x4 acc;
      f32x4 bv = *reinterpret_cast<const f32x4*>(&b1g[m * 16 + qd * 4]);
#pragma unroll
      for (int r = 0; r < 4; ++r) acc[r] = bv[r] * 0.015625f;
      acc = __builtin_amdgcn_mfma_f32_16x16x32_f16(a1[m][0], bf0, acc, 0, 0, 0);
      acc = __builtin_amdgcn_mfma_f32_16x16x32_f16(a1[m][1], bf1, acc, 0, 0, 0);
      if (jt < 132) {
        int t = t0 - 2 + jt;
        bool inr = (t >= 0 && t < T_);
        half4 hv;
#pragma unroll
        for (int r = 0; r < 4; ++r) {
          float h = inr ? gelu_fast(acc[r] * 64.f) * 0.0625f : 0.f;
          hv[r] = (_Float16)h;
        }
        *reinterpret_cast<half4*>(&sH1[jt * 72 + m * 16 + qd * 4]) = hv;
      }
    }
  }
  __syncthreads();

  int p = w & 1, nq = w >> 1;
  f32x4 acc2[2][2];
#pragma unroll
  for (int dm = 0; dm < 2; ++dm) {
    f32x4 bv = *reinterpret_cast<const f32x4*>(&b2g[(2 * p + dm) * 16 + qd * 4]);
#pragma unroll
    for (int dn = 0; dn < 2; ++dn)
#pragma unroll
      for (int r = 0; r < 4; ++r) acc2[dm][dn][r] = bv[r] * 0.0625f;
  }
#pragma unroll
  for (int k = 0; k < 5; ++k) {
#pragma unroll
    for (int kk = 0; kk < 2; ++kk) {
      half8 A0 = w2f[((k * 2 + kk) * 4 + 2 * p + 0) * 64 + lane];
      half8 A1 = w2f[((k * 2 + kk) * 4 + 2 * p + 1) * 64 + lane];
      half8 B0 = *reinterpret_cast<const half8*>(
          &sH1[((2 * nq + 0) * 16 + ln + k) * 72 + kk * 32 + qd * 8]);
      half8 B1 = *reinterpret_cast<const half8*>(
          &sH1[((2 * nq + 1) * 16 + ln + k) * 72 + kk * 32 + qd * 8]);
      acc2[0][0] = __builtin_amdgcn_mfma_f32_16x16x32_f16(A0, B0, acc2[0][0], 0, 0, 0);
      acc2[0][1] = __builtin_amdgcn_mfma_f32_16x16x32_f16(A0, B1, acc2[0][1], 0, 0, 0);
      acc2[1][0] = __builtin_amdgcn_mfma_f32_16x16x32_f16(A1, B0, acc2[1][0], 0, 0, 0);
      acc2[1][1] = __builtin_amdgcn_mfma_f32_16x16x32_f16(A1, B1, acc2[1][1], 0, 0, 0);
    }
  }
  f32x4 w3a = *reinterpret_cast<const f32x4*>(&w3g[(2 * p + 0) * 16 + qd * 4]);
  f32x4 w3b = *reinterpret_cast<const f32x4*>(&w3g[(2 * p + 1) * 16 + qd * 4]);
#pragma unroll
  for (int dn = 0; dn < 2; ++dn) {
    float s = 0.f;
#pragma unroll
    for (int r = 0; r < 4; ++r) s += w3a[r] * gelu_fast(acc2[0][dn][r] * 16.f);
#pragma unroll
    for (int r = 0; r < 4; ++r) s += w3b[r] * gelu_fast(acc2[1][dn][r] * 16.f);
    s += __shfl_xor(s, 16);
    s += __shfl_xor(s, 32);
    if (lane < 16) sPart[p][(2 * nq + dn) * 16 + lane] = s;
  }
  __syncthreads();
  if (tid < 128) {
    int t = t0 + tid;
    float logit = sPart[0][tid] + sPart[1][tid] + b3g[0];
    float m = amask[(size_t)b * T_ + t];
    lp[(size_t)b * T_ + t] = (1.f / (1.f + expf(-logit))) * m;
  }
}

// ---------------- Kernel D: smooth learned + blend (unchanged) ----------------
__global__ __launch_bounds__(256)
void final_k(const float* __restrict__ rule, const float* __restrict__ lp,
             const float* __restrict__ amask, float* __restrict__ out) {
  int idx = blockIdx.x * 256 + threadIdx.x;
  if (idx >= BT) return;
  int t = idx & (T_ - 1);
  float s = 0.f;
#pragma unroll
  for (int d = -2; d <= 2; ++d) {
    int tt = t + d;
    if (tt >= 0 && tt < T_) s += lp[idx + d];
  }
  float m = amask[idx];
  float learned = clip01(s * 0.2f * m);
  out[idx] = clip01(0.5f * rule[idx] + 0.5f * learned) * m;
}

}  // namespace

extern "C" void kernel_launch(void* const* d_in, const int* in_sizes, int n_in,
                              void* d_out, int out_size, void* d_ws, size_t ws_size,
                              hipStream_t stream) {
  const float* traj      = (const float*)d_in[0];
  const float* intervals = (const float*)d_in[1];
  const float* amask     = (const float*)d_in[2];
  const float* omask     = (const float*)d_in[3];
  const float* w1        = (const float*)d_in[4];
  const float* b1        = (const float*)d_in[5];
  const float* w2        = (const float*)d_in[6];
  const float* b2        = (const float*)d_in[7];
  const float* w3        = (const float*)d_in[8];
  const float* b3        = (const float*)d_in[9];
  float* out = (float*)d_out;
  float* ws = (float*)d_ws;

  float* feats = ws + OFF_FEATS;
  float* rule  = ws + OFF_RULE;
  float* lp    = ws + OFF_LP;
  half8* w1f = (half8*)(ws + OFF_W1F);
  half8* w2f = (half8*)(ws + OFF_W2F);

  repack_k<<<12, 256, 0, stream>>>(w1, w2, w1f, w2f);
  rulefuse_k<<<B_, 1024, 0, stream>>>(traj, intervals, amask, omask, feats, rule);
  conv_k<<<dim3(T_ / TTILE, B_), 512, 0, stream>>>(feats, w1f, b1, w2f, b2, w3, b3,
                                                   amask, lp);
  final_k<<<BT / 256, 256, 0, stream>>>(rule, lp, amask, out);
}

// Round 8
// 181.732 us; speedup vs baseline: 1.5373x; 1.0137x over previous
//
#include <hip/hip_runtime.h>

namespace {

constexpr int B_ = 128;
constexpr int T_ = 4096;
constexpr int BT = B_ * T_;
constexpr int TTILE = 128;
constexpr unsigned NOINS = 0xFFFFFFFFu;  // "do not insert" sentinel (invalid/masked lane)

// workspace layout (float offsets)
constexpr size_t OFF_W1F   = 0;                 // 8 frags * 64 * 8 f16 = 2048 floats
constexpr size_t OFF_W2F   = 2048;              // 40 frags * 64 * 8 f16 = 10240 floats
constexpr size_t OFF_FEATS = 16384;             // B*10*T floats
constexpr size_t OFF_HC    = OFF_FEATS + (size_t)B_ * 10 * T_;
constexpr size_t OFF_AN    = OFF_HC + (size_t)BT;
constexpr size_t OFF_SC    = OFF_AN + (size_t)BT;
constexpr size_t OFF_OT    = OFF_SC + (size_t)BT;
constexpr size_t OFF_RULE  = OFF_OT + (size_t)BT;
constexpr size_t OFF_LP    = OFF_RULE + (size_t)BT;

typedef _Float16 half8 __attribute__((ext_vector_type(8)));
typedef _Float16 half4 __attribute__((ext_vector_type(4)));
typedef _Float16 half2_t __attribute__((ext_vector_type(2)));
typedef float f32x4 __attribute__((ext_vector_type(4)));

__device__ __forceinline__ float clip01(float x) { return fminf(fmaxf(x, 0.f), 1.f); }

// branchless GELU via Abramowitz-Stegun 7.1.26 erf (|err| <= 1.5e-7)
__device__ __forceinline__ float gelu_fast(float x) {
  float s = x * 0.7071067811865475f;
  float a = fabsf(s);
  float t = __builtin_amdgcn_rcpf(__builtin_fmaf(0.3275911f, a, 1.0f));
  float p = __builtin_fmaf(t, 1.061405429f, -1.453152027f);
  p = __builtin_fmaf(t, p, 1.421413741f);
  p = __builtin_fmaf(t, p, -0.284496736f);
  p = __builtin_fmaf(t, p, 0.254829592f);
  p = p * t;
  float e = __builtin_amdgcn_exp2f(a * a * -1.4426950408889634f);
  float erfa = __builtin_fmaf(-p, e, 1.0f);
  float erfs = copysignf(erfa, s);
  return 0.5f * x * (1.0f + erfs);
}

// feature math for (b,t) — bit-identical to round-4 featurize_k
__device__ __forceinline__ void compute_feats(
    const float* __restrict__ tr, const float* __restrict__ iv,
    const float* __restrict__ mk, const float* __restrict__ om, int t,
    float* __restrict__ f /*10*/, float* anv_out, float* scv_out, float* otv_out) {
  float m  = mk[t];
  float m1 = (t >= 1) ? mk[t - 1] : 0.f;
  float m2 = (t >= 2) ? mk[t - 2] : 0.f;
  float pm01 = (m > 0.5f && m1 > 0.5f) ? 1.f : 0.f;
  float pm12 = (m1 > 0.5f && m2 > 0.5f) ? 1.f : 0.f;
  float x0x = tr[2 * t] * m, x0y = tr[2 * t + 1] * m;
  float x1x = 0.f, x1y = 0.f, x2x = 0.f, x2y = 0.f;
  if (t >= 1) { x1x = tr[2 * (t - 1)] * m1; x1y = tr[2 * (t - 1) + 1] * m1; }
  if (t >= 2) { x2x = tr[2 * (t - 2)] * m2; x2y = tr[2 * (t - 2) + 1] * m2; }
  float dt0 = fmaxf(iv[t], 1e-3f);
  float dt1 = (t >= 1) ? fmaxf(iv[t - 1], 1e-3f) : 1e-3f;
  float vx = 0.f, vy = 0.f, v1x = 0.f, v1y = 0.f;
  if (t >= 1) { vx = (x0x - x1x) * pm01 / dt0 * m; vy = (x0y - x1y) * pm01 / dt0 * m; }
  if (t >= 2) { v1x = (x1x - x2x) * pm12 / dt1 * m1; v1y = (x1y - x2y) * pm12 / dt1 * m1; }
  float ax = 0.f, ay = 0.f;
  if (t >= 1) { ax = (vx - v1x) * pm01 / dt0 * m; ay = (vy - v1y) * pm01 / dt0 * m; }
  float s2 = vx * vx + vy * vy;
  float speed = (s2 > 0.f ? sqrtf(s2) : 0.f) * m;
  float s21 = v1x * v1x + v1y * v1y;
  float speed1 = (s21 > 0.f ? sqrtf(s21) : 0.f) * m1;
  float scv = (t >= 1) ? fabsf((speed - speed1) * pm01) * m : 0.f;
  float a2 = ax * ax + ay * ay;
  float anv = (a2 > 0.f ? sqrtf(a2) : 0.f) * m;
  float hcv = 0.f;
  if (t >= 1) {
    bool z0 = (vx == 0.f && vy == 0.f);
    bool z1 = (v1x == 0.f && v1y == 0.f);
    float yy, xx;
    if (z1)      { yy = vy;  xx = vx; }
    else if (z0) { yy = v1y; xx = v1x; }
    else { yy = vy * v1x - vx * v1y; xx = vx * v1x + vy * v1y; }
    hcv = fabsf(atan2f(yy, xx)) * pm01 * m;
  }
  float obs = om[t] * m;
  float otv = (t >= 1) ? fminf(fabsf(om[t] - om[t - 1]) * pm01 * m, 1.f) : 0.f;
  float itf = iv[t] * m;
  f[0] = x0x; f[1] = x0y; f[2] = vx; f[3] = vy; f[4] = ax; f[5] = ay;
  f[6] = speed; f[7] = hcv; f[8] = itf; f[9] = obs;
  *anv_out = anv; *scv_out = scv; *otv_out = otv;
}

// ---------------- Kernel A: featurize (full-chip) + fused weight repack ----------------
__global__ __launch_bounds__(256)
void featurize_k(const float* __restrict__ traj, const float* __restrict__ intervals,
                 const float* __restrict__ amask, const float* __restrict__ omask,
                 const float* __restrict__ w1g, const float* __restrict__ w2g,
                 float* __restrict__ feats, float* __restrict__ hc, float* __restrict__ an,
                 float* __restrict__ sc, float* __restrict__ ot,
                 half8* __restrict__ w1f, half8* __restrict__ w2f) {
  int idx = blockIdx.x * 256 + threadIdx.x;
  int b = idx >> 12;
  int t = idx & (T_ - 1);
  float f[10], anv, scv, otv;
  compute_feats(traj + (size_t)b * T_ * 2, intervals + (size_t)b * T_,
                amask + (size_t)b * T_, omask + (size_t)b * T_, t, f, &anv, &scv, &otv);
  float* frow = feats + (size_t)b * 10 * T_;
#pragma unroll
  for (int c = 0; c < 10; ++c) frow[(size_t)c * T_ + t] = f[c];
  hc[idx] = f[7]; an[idx] = anv; sc[idx] = scv; ot[idx] = otv;

  // fused repack: first 12 blocks also build MFMA weight fragments (48 frags * 64 lanes)
  if (blockIdx.x < 12) {
    int gid = blockIdx.x * 256 + threadIdx.x;
    if (gid < 48 * 64) {
      int fid = gid >> 6, lane = gid & 63;
      int qd = lane >> 4, ln = lane & 15;
      half8 v;
      if (fid < 8) {
        int m = fid >> 1, kk = fid & 1;
        int o = m * 16 + ln;
#pragma unroll
        for (int j = 0; j < 8; ++j) {
          int ck = kk * 32 + qd * 8 + j;
          float val = 0.f;
          if (ck < 50) { int k_ = ck / 10, c = ck - 10 * k_; val = w1g[o * 50 + c * 5 + k_]; }
          v[j] = (_Float16)val;
        }
        w1f[fid * 64 + lane] = v;
      } else {
        int f2 = fid - 8;
        int k = f2 >> 3, kk = (f2 >> 2) & 1, m = f2 & 3;
        int o = m * 16 + ln;
#pragma unroll
        for (int j = 0; j < 8; ++j) {
          int ic = kk * 32 + qd * 8 + j;
          v[j] = (_Float16)w2g[o * 320 + ic * 5 + k];
        }
        w2f[f2 * 64 + lane] = v;
      }
    }
  }
}

// ---------------- 1024-thread parallel bucket find ----------------
template <int CHUNK, int NB>
__device__ __forceinline__ void find_bucket_1k(const unsigned* __restrict__ hist,
                                               unsigned* selb, unsigned* selk,
                                               unsigned* sW, int tid) {
  unsigned k = *selk;  // stable: set before the barrier preceding this call
  unsigned vals[CHUNK];
  unsigned ps = 0;
#pragma unroll
  for (int c = 0; c < CHUNK; ++c) {
    int idx = tid * CHUNK + c;
    unsigned v = (idx < NB) ? hist[idx] : 0u;
    vals[c] = v; ps += v;
  }
  unsigned incl = ps;
  int lane = tid & 63;
#pragma unroll
  for (int off = 1; off < 64; off <<= 1) {
    unsigned tv = __shfl_up(incl, off, 64);
    if (lane >= off) incl += tv;
  }
  if (lane == 63) sW[tid >> 6] = incl;
  __syncthreads();
  int wid = tid >> 6;
  unsigned woff = 0;
  for (int i = 0; i < wid; ++i) woff += sW[i];
  incl += woff;
  unsigned excl = incl - ps;
  __syncthreads();  // reads of *selk / sW complete before winner writes
  if (excl <= k && k < incl) {
    unsigned run = excl;
    int c = 0;
#pragma unroll
    for (; c < CHUNK - 1; ++c) {
      if (run + vals[c] > k) break;
      run += vals[c];
    }
    *selb = (unsigned)(tid * CHUNK + c);
    *selk = k - run;
  }
  __syncthreads();
}

// exact k-th smallest among VALID candidates (u[r]==NOINS never inserted;
// legal because kidx < n so an invalid entry can never be the answer).
__device__ __forceinline__ float radix_select_1k(const unsigned* u, unsigned k,
                                                 unsigned* hist, unsigned* selb,
                                                 unsigned* selk, unsigned* sW, int tid) {
  for (int i = tid; i < 4096; i += 1024) hist[i] = 0u;
  if (tid == 0) *selk = k;
  __syncthreads();
#pragma unroll
  for (int r = 0; r < 4; ++r)
    if (u[r] != NOINS) atomicAdd(&hist[u[r] >> 20], 1u);
  __syncthreads();
  find_bucket_1k<4, 4096>(hist, selb, selk, sW, tid);
  unsigned p1 = *selb;
  for (int i = tid; i < 4096; i += 1024) hist[i] = 0u;
  __syncthreads();
#pragma unroll
  for (int r = 0; r < 4; ++r)
    if (u[r] != NOINS && (u[r] >> 20) == p1) atomicAdd(&hist[(u[r] >> 8) & 0xFFFu], 1u);
  __syncthreads();
  find_bucket_1k<4, 4096>(hist, selb, selk, sW, tid);
  unsigned p2 = *selb;
  unsigned pref = (p1 << 12) | p2;
  if (tid < 256) hist[tid] = 0u;
  __syncthreads();
#pragma unroll
  for (int r = 0; r < 4; ++r)
    if (u[r] != NOINS && (u[r] >> 8) == pref) atomicAdd(&hist[u[r] & 0xFFu], 1u);
  __syncthreads();
  find_bucket_1k<1, 256>(hist, selb, selk, sW, tid);
  unsigned p3 = *selb;
  __syncthreads();
  return __uint_as_float((p1 << 20) | (p2 << 8) | p3);
}

__device__ __forceinline__ float block_max_1k(float v, float* sM, int tid) {
#pragma unroll
  for (int off = 32; off; off >>= 1) v = fmaxf(v, __shfl_xor(v, off));
  if ((tid & 63) == 0) sM[tid >> 6] = v;
  __syncthreads();
  float m = sM[0];
#pragma unroll
  for (int i = 1; i < 16; ++i) m = fmaxf(m, sM[i]);
  __syncthreads();
  return m;
}

// ---------------- Kernel B: selects + smooth + normalize (one block per row) ----------------
__global__ __launch_bounds__(1024)
void ruleselect_k(const float* __restrict__ hc, const float* __restrict__ an,
                  const float* __restrict__ sc, const float* __restrict__ ot,
                  const float* __restrict__ amask, float* __restrict__ rule) {
  __shared__ unsigned hist[4096];
  __shared__ unsigned sW[16];
  __shared__ unsigned selb, selk;
  __shared__ float vbuf[4096];
  __shared__ float sM[16];
  __shared__ int iCnt[16];
  __shared__ int n_sh;
  __shared__ float scale_sh[3];
  int b = blockIdx.x, tid = threadIdx.x;
  const float* mk = amask + (size_t)b * T_;
  const float* hrow = hc + (size_t)b * T_;
  const float* arow = an + (size_t)b * T_;
  const float* srow = sc + (size_t)b * T_;
  const float* orow = ot + (size_t)b * T_;

  float hcv[4], anv[4], scv[4], otv[4], mreg[4];
  int cnt = 0;
#pragma unroll
  for (int r = 0; r < 4; ++r) {
    int t = tid + 1024 * r;
    hcv[r] = hrow[t]; anv[r] = arow[t]; scv[r] = srow[t]; otv[r] = orow[t];
    mreg[r] = mk[t];
    cnt += (mreg[r] > 0.5f);
  }
#pragma unroll
  for (int off = 32; off; off >>= 1) cnt += __shfl_xor(cnt, off);
  if ((tid & 63) == 0) iCnt[tid >> 6] = cnt;
  __syncthreads();
  if (tid == 0) {
    int n = 0;
#pragma unroll
    for (int i = 0; i < 16; ++i) n += iCnt[i];
    n_sh = n;
  }
  __syncthreads();
  int n = n_sh;
  int cidx = (int)ceilf((float)n * 0.95f);
  if (cidx < 1) cidx = 1;
  int kidx = cidx - 1;
  if (kidx < 0) kidx = 0;
  if (kidx > T_ - 1) kidx = T_ - 1;

  // 3 metric percentile scales (exact; invalid lanes never inserted)
  for (int m3 = 0; m3 < 3; ++m3) {
    unsigned u[4];
    float mx = 0.f;
#pragma unroll
    for (int r = 0; r < 4; ++r) {
      float v = (m3 == 0 ? hcv[r] : m3 == 1 ? anv[r] : scv[r]);
      if (mreg[r] > 0.5f) {
        mx = fmaxf(mx, fabsf(v));
        unsigned ub = __float_as_uint(v);
        if ((int)ub < 0) ub = 0u;  // -0.0 safety
        u[r] = ub;
      } else u[r] = NOINS;
    }
    mx = block_max_1k(mx, sM, tid);
    float kth = fabsf(radix_select_1k(u, (unsigned)kidx, hist, &selb, &selk, sW, tid));
    if (tid == 0) {
      float s = (kth < 1e-6f) ? mx : kth;
      scale_sh[m3] = fmaxf(s, 1e-6f);
    }
  }
  __syncthreads();
  float sc0 = scale_sh[0], sc1 = scale_sh[1], sc2 = scale_sh[2];
#pragma unroll
  for (int r = 0; r < 4; ++r) {
    int t = tid + 1024 * r;
    float v = 0.f;
    if (n > 0) {
      v = 0.35f * (hcv[r] / sc0) + 0.30f * (anv[r] / sc1)
        + 0.25f * (scv[r] / sc2) + 0.10f * otv[r];
    }
    vbuf[t] = v;
  }
  __syncthreads();
  float sm[4];
#pragma unroll
  for (int r = 0; r < 4; ++r) {
    int t = tid + 1024 * r;
    float s = 0.f;
#pragma unroll
    for (int d = -2; d <= 2; ++d) {
      int tt = t + d;
      if (tt >= 0 && tt < T_) s += vbuf[tt];
    }
    sm[r] = s * 0.2f * mreg[r];
  }
  unsigned u2[4];
  float mx2 = 0.f;
#pragma unroll
  for (int r = 0; r < 4; ++r) {
    if (mreg[r] > 0.5f) {
      mx2 = fmaxf(mx2, fabsf(sm[r]));
      unsigned ub = __float_as_uint(sm[r]);
      if ((int)ub < 0) ub = 0u;
      u2[r] = ub;
    } else u2[r] = NOINS;
  }
  mx2 = block_max_1k(mx2, sM, tid);
  float kth4 = fabsf(radix_select_1k(u2, (unsigned)kidx, hist, &selb, &selk, sW, tid));
  float scale4 = fmaxf((kth4 < 1e-6f) ? mx2 : kth4, 1e-6f);
  float* rrow = rule + (size_t)b * T_;
#pragma unroll
  for (int r = 0; r < 4; ++r) {
    int t = tid + 1024 * r;
    float v = (n > 0) ? sm[r] / scale4 : 0.f;
    rrow[t] = clip01(v) * mreg[r];
  }
}

// ---------------- Kernel C: MFMA conv stack (exact round-4 version, 81 us) ----------------
__global__ __launch_bounds__(512, 4)
void conv_k(const float* __restrict__ feats, const half8* __restrict__ w1f,
            const float* __restrict__ b1g, const half8* __restrict__ w2f,
            const float* __restrict__ b2g, const float* __restrict__ w3g,
            const float* __restrict__ b3g, const float* __restrict__ amask,
            float* __restrict__ lp) {
  __shared__ _Float16 sIm[144 * 72];
  __shared__ _Float16 sH1[132 * 72];
  __shared__ float sF[10 * 136];
  __shared__ float sPart[2][128];
  int tid = threadIdx.x;
  int lane = tid & 63, w = tid >> 6;
  int qd = lane >> 4, ln = lane & 15;
  int tile = blockIdx.x, b = blockIdx.y;
  int t0 = tile * TTILE;
  const float* frow = feats + (size_t)b * 10 * T_;

  for (int s = tid; s < 1360; s += 512) {
    int c = s / 136, u = s - c * 136;
    int t = t0 - 4 + u;
    sF[s] = (t >= 0 && t < T_) ? frow[(size_t)c * T_ + t] * 0.015625f : 0.f;
  }
  for (int s = tid; s < 144 * 7; s += 512) {
    int jt = s / 7, d = s - jt * 7;
    *reinterpret_cast<unsigned*>(&sIm[jt * 72 + 50 + 2 * d]) = 0u;
  }
  __syncthreads();
  for (int s = tid; s < 660; s += 512) {
    int jt = s / 5, k = s - jt * 5;
#pragma unroll
    for (int cp = 0; cp < 5; ++cp) {
      float lo = sF[(2 * cp) * 136 + jt + k];
      float hi = sF[(2 * cp + 1) * 136 + jt + k];
      half2_t pk;
      pk[0] = (_Float16)lo;
      pk[1] = (_Float16)hi;
      *reinterpret_cast<half2_t*>(&sIm[jt * 72 + k * 10 + 2 * cp]) = pk;
    }
  }
  __syncthreads();

  half8 a1[4][2];
#pragma unroll
  for (int m = 0; m < 4; ++m)
#pragma unroll
    for (int kk = 0; kk < 2; ++kk) a1[m][kk] = w1f[(m * 2 + kk) * 64 + lane];

  for (int n0 = w; n0 < 9; n0 += 8) {
    int jt = n0 * 16 + ln;
    half8 bf0 = *reinterpret_cast<const half8*>(&sIm[jt * 72 + qd * 8]);
    half8 bf1 = *reinterpret_cast<const half8*>(&sIm[jt * 72 + 32 + qd * 8]);
#pragma unroll
    for (int m = 0; m < 4; ++m) {
      f32x4 acc;
      f32x4 bv = *reinterpret_cast<const f32x4*>(&b1g[m * 16 + qd * 4]);
#pragma unroll
      for (int r = 0; r < 4; ++r) acc[r] = bv[r] * 0.015625f;
      acc = __builtin_amdgcn_mfma_f32_16x16x32_f16(a1[m][0], bf0, acc, 0, 0, 0);
      acc = __builtin_amdgcn_mfma_f32_16x16x32_f16(a1[m][1], bf1, acc, 0, 0, 0);
      if (jt < 132) {
        int t = t0 - 2 + jt;
        bool inr = (t >= 0 && t < T_);
        half4 hv;
#pragma unroll
        for (int r = 0; r < 4; ++r) {
          float h = inr ? gelu_fast(acc[r] * 64.f) * 0.0625f : 0.f;
          hv[r] = (_Float16)h;
        }
        *reinterpret_cast<half4*>(&sH1[jt * 72 + m * 16 + qd * 4]) = hv;
      }
    }
  }
  __syncthreads();

  int p = w & 1, nq = w >> 1;
  f32x4 acc2[2][2];
#pragma unroll
  for (int dm = 0; dm < 2; ++dm) {
    f32x4 bv = *reinterpret_cast<const f32x4*>(&b2g[(2 * p + dm) * 16 + qd * 4]);
#pragma unroll
    for (int dn = 0; dn < 2; ++dn)
#pragma unroll
      for (int r = 0; r < 4; ++r) acc2[dm][dn][r] = bv[r] * 0.0625f;
  }
#pragma unroll
  for (int k = 0; k < 5; ++k) {
#pragma unroll
    for (int kk = 0; kk < 2; ++kk) {
      half8 A0 = w2f[((k * 2 + kk) * 4 + 2 * p + 0) * 64 + lane];
      half8 A1 = w2f[((k * 2 + kk) * 4 + 2 * p + 1) * 64 + lane];
      half8 B0 = *reinterpret_cast<const half8*>(
          &sH1[((2 * nq + 0) * 16 + ln + k) * 72 + kk * 32 + qd * 8]);
      half8 B1 = *reinterpret_cast<const half8*>(
          &sH1[((2 * nq + 1) * 16 + ln + k) * 72 + kk * 32 + qd * 8]);
      acc2[0][0] = __builtin_amdgcn_mfma_f32_16x16x32_f16(A0, B0, acc2[0][0], 0, 0, 0);
      acc2[0][1] = __builtin_amdgcn_mfma_f32_16x16x32_f16(A0, B1, acc2[0][1], 0, 0, 0);
      acc2[1][0] = __builtin_amdgcn_mfma_f32_16x16x32_f16(A1, B0, acc2[1][0], 0, 0, 0);
      acc2[1][1] = __builtin_amdgcn_mfma_f32_16x16x32_f16(A1, B1, acc2[1][1], 0, 0, 0);
    }
  }
  f32x4 w3a = *reinterpret_cast<const f32x4*>(&w3g[(2 * p + 0) * 16 + qd * 4]);
  f32x4 w3b = *reinterpret_cast<const f32x4*>(&w3g[(2 * p + 1) * 16 + qd * 4]);
#pragma unroll
  for (int dn = 0; dn < 2; ++dn) {
    float s = 0.f;
#pragma unroll
    for (int r = 0; r < 4; ++r) s += w3a[r] * gelu_fast(acc2[0][dn][r] * 16.f);
#pragma unroll
    for (int r = 0; r < 4; ++r) s += w3b[r] * gelu_fast(acc2[1][dn][r] * 16.f);
    s += __shfl_xor(s, 16);
    s += __shfl_xor(s, 32);
    if (lane < 16) sPart[p][(2 * nq + dn) * 16 + lane] = s;
  }
  __syncthreads();
  if (tid < 128) {
    int t = t0 + tid;
    float logit = sPart[0][tid] + sPart[1][tid] + b3g[0];
    float m = amask[(size_t)b * T_ + t];
    lp[(size_t)b * T_ + t] = (1.f / (1.f + expf(-logit))) * m;
  }
}

// ---------------- Kernel D: smooth learned + blend (unchanged) ----------------
__global__ __launch_bounds__(256)
void final_k(const float* __restrict__ rule, const float* __restrict__ lp,
             const float* __restrict__ amask, float* __restrict__ out) {
  int idx = blockIdx.x * 256 + threadIdx.x;
  if (idx >= BT) return;
  int t = idx & (T_ - 1);
  float s = 0.f;
#pragma unroll
  for (int d = -2; d <= 2; ++d) {
    int tt = t + d;
    if (tt >= 0 && tt < T_) s += lp[idx + d];
  }
  float m = amask[idx];
  float learned = clip01(s * 0.2f * m);
  out[idx] = clip01(0.5f * rule[idx] + 0.5f * learned) * m;
}

}  // namespace

extern "C" void kernel_launch(void* const* d_in, const int* in_sizes, int n_in,
                              void* d_out, int out_size, void* d_ws, size_t ws_size,
                              hipStream_t stream) {
  const float* traj      = (const float*)d_in[0];
  const float* intervals = (const float*)d_in[1];
  const float* amask     = (const float*)d_in[2];
  const float* omask     = (const float*)d_in[3];
  const float* w1        = (const float*)d_in[4];
  const float* b1        = (const float*)d_in[5];
  const float* w2        = (const float*)d_in[6];
  const float* b2        = (const float*)d_in[7];
  const float* w3        = (const float*)d_in[8];
  const float* b3        = (const float*)d_in[9];
  float* out = (float*)d_out;
  float* ws = (float*)d_ws;

  float* feats = ws + OFF_FEATS;
  float* hc    = ws + OFF_HC;
  float* an    = ws + OFF_AN;
  float* sc    = ws + OFF_SC;
  float* ot    = ws + OFF_OT;
  float* rule  = ws + OFF_RULE;
  float* lp    = ws + OFF_LP;
  half8* w1f = (half8*)(ws + OFF_W1F);
  half8* w2f = (half8*)(ws + OFF_W2F);

  featurize_k<<<BT / 256, 256, 0, stream>>>(traj, intervals, amask, omask, w1, w2,
                                            feats, hc, an, sc, ot, w1f, w2f);
  ruleselect_k<<<B_, 1024, 0, stream>>>(hc, an, sc, ot, amask, rule);
  conv_k<<<dim3(T_ / TTILE, B_), 512, 0, stream>>>(feats, w1f, b1, w2f, b2, w3, b3,
                                                   amask, lp);
  final_k<<<BT / 256, 256, 0, stream>>>(rule, lp, amask, out);
}

// Round 9
// 178.847 us; speedup vs baseline: 1.5621x; 1.0161x over previous
//
#include <hip/hip_runtime.h>

namespace {

constexpr int B_ = 128;
constexpr int T_ = 4096;
constexpr int BT = B_ * T_;
constexpr int TTILE = 128;
constexpr unsigned NOINS = 0xFFFFFFFFu;  // "do not insert" sentinel (invalid/masked lane)

// workspace layout (float offsets)
constexpr size_t OFF_W1F   = 0;                 // 8 frags * 64 * 8 f16 = 2048 floats
constexpr size_t OFF_W2F   = 2048;              // 40 frags * 64 * 8 f16 = 10240 floats
constexpr size_t OFF_FEATS = 16384;             // B*10*T floats
constexpr size_t OFF_HC    = OFF_FEATS + (size_t)B_ * 10 * T_;
constexpr size_t OFF_AN    = OFF_HC + (size_t)BT;
constexpr size_t OFF_SC    = OFF_AN + (size_t)BT;
constexpr size_t OFF_OT    = OFF_SC + (size_t)BT;
constexpr size_t OFF_RULE  = OFF_OT + (size_t)BT;
constexpr size_t OFF_LP    = OFF_RULE + (size_t)BT;

typedef _Float16 half8 __attribute__((ext_vector_type(8)));
typedef _Float16 half4 __attribute__((ext_vector_type(4)));
typedef _Float16 half2_t __attribute__((ext_vector_type(2)));
typedef float f32x4 __attribute__((ext_vector_type(4)));

__device__ __forceinline__ float clip01(float x) { return fminf(fmaxf(x, 0.f), 1.f); }

// branchless GELU via Abramowitz-Stegun 7.1.26 erf (|err| <= 1.5e-7)
__device__ __forceinline__ float gelu_fast(float x) {
  float s = x * 0.7071067811865475f;
  float a = fabsf(s);
  float t = __builtin_amdgcn_rcpf(__builtin_fmaf(0.3275911f, a, 1.0f));
  float p = __builtin_fmaf(t, 1.061405429f, -1.453152027f);
  p = __builtin_fmaf(t, p, 1.421413741f);
  p = __builtin_fmaf(t, p, -0.284496736f);
  p = __builtin_fmaf(t, p, 0.254829592f);
  p = p * t;
  float e = __builtin_amdgcn_exp2f(a * a * -1.4426950408889634f);
  float erfa = __builtin_fmaf(-p, e, 1.0f);
  float erfs = copysignf(erfa, s);
  return 0.5f * x * (1.0f + erfs);
}

// feature math for (b,t) — bit-identical to round-4 featurize_k
__device__ __forceinline__ void compute_feats(
    const float* __restrict__ tr, const float* __restrict__ iv,
    const float* __restrict__ mk, const float* __restrict__ om, int t,
    float* __restrict__ f /*10*/, float* anv_out, float* scv_out, float* otv_out) {
  float m  = mk[t];
  float m1 = (t >= 1) ? mk[t - 1] : 0.f;
  float m2 = (t >= 2) ? mk[t - 2] : 0.f;
  float pm01 = (m > 0.5f && m1 > 0.5f) ? 1.f : 0.f;
  float pm12 = (m1 > 0.5f && m2 > 0.5f) ? 1.f : 0.f;
  float x0x = tr[2 * t] * m, x0y = tr[2 * t + 1] * m;
  float x1x = 0.f, x1y = 0.f, x2x = 0.f, x2y = 0.f;
  if (t >= 1) { x1x = tr[2 * (t - 1)] * m1; x1y = tr[2 * (t - 1) + 1] * m1; }
  if (t >= 2) { x2x = tr[2 * (t - 2)] * m2; x2y = tr[2 * (t - 2) + 1] * m2; }
  float dt0 = fmaxf(iv[t], 1e-3f);
  float dt1 = (t >= 1) ? fmaxf(iv[t - 1], 1e-3f) : 1e-3f;
  float vx = 0.f, vy = 0.f, v1x = 0.f, v1y = 0.f;
  if (t >= 1) { vx = (x0x - x1x) * pm01 / dt0 * m; vy = (x0y - x1y) * pm01 / dt0 * m; }
  if (t >= 2) { v1x = (x1x - x2x) * pm12 / dt1 * m1; v1y = (x1y - x2y) * pm12 / dt1 * m1; }
  float ax = 0.f, ay = 0.f;
  if (t >= 1) { ax = (vx - v1x) * pm01 / dt0 * m; ay = (vy - v1y) * pm01 / dt0 * m; }
  float s2 = vx * vx + vy * vy;
  float speed = (s2 > 0.f ? sqrtf(s2) : 0.f) * m;
  float s21 = v1x * v1x + v1y * v1y;
  float speed1 = (s21 > 0.f ? sqrtf(s21) : 0.f) * m1;
  float scv = (t >= 1) ? fabsf((speed - speed1) * pm01) * m : 0.f;
  float a2 = ax * ax + ay * ay;
  float anv = (a2 > 0.f ? sqrtf(a2) : 0.f) * m;
  float hcv = 0.f;
  if (t >= 1) {
    bool z0 = (vx == 0.f && vy == 0.f);
    bool z1 = (v1x == 0.f && v1y == 0.f);
    float yy, xx;
    if (z1)      { yy = vy;  xx = vx; }
    else if (z0) { yy = v1y; xx = v1x; }
    else { yy = vy * v1x - vx * v1y; xx = vx * v1x + vy * v1y; }
    hcv = fabsf(atan2f(yy, xx)) * pm01 * m;
  }
  float obs = om[t] * m;
  float otv = (t >= 1) ? fminf(fabsf(om[t] - om[t - 1]) * pm01 * m, 1.f) : 0.f;
  float itf = iv[t] * m;
  f[0] = x0x; f[1] = x0y; f[2] = vx; f[3] = vy; f[4] = ax; f[5] = ay;
  f[6] = speed; f[7] = hcv; f[8] = itf; f[9] = obs;
  *anv_out = anv; *scv_out = scv; *otv_out = otv;
}

// ---------------- Kernel A: featurize (full-chip) + fused weight repack ----------------
__global__ __launch_bounds__(256)
void featurize_k(const float* __restrict__ traj, const float* __restrict__ intervals,
                 const float* __restrict__ amask, const float* __restrict__ omask,
                 const float* __restrict__ w1g, const float* __restrict__ w2g,
                 float* __restrict__ feats, float* __restrict__ hc, float* __restrict__ an,
                 float* __restrict__ sc, float* __restrict__ ot,
                 half8* __restrict__ w1f, half8* __restrict__ w2f) {
  int idx = blockIdx.x * 256 + threadIdx.x;
  int b = idx >> 12;
  int t = idx & (T_ - 1);
  float f[10], anv, scv, otv;
  compute_feats(traj + (size_t)b * T_ * 2, intervals + (size_t)b * T_,
                amask + (size_t)b * T_, omask + (size_t)b * T_, t, f, &anv, &scv, &otv);
  float* frow = feats + (size_t)b * 10 * T_;
#pragma unroll
  for (int c = 0; c < 10; ++c) frow[(size_t)c * T_ + t] = f[c];
  hc[idx] = f[7]; an[idx] = anv; sc[idx] = scv; ot[idx] = otv;

  // fused repack: first 12 blocks also build MFMA weight fragments (48 frags * 64 lanes)
  if (blockIdx.x < 12) {
    int gid = blockIdx.x * 256 + threadIdx.x;
    if (gid < 48 * 64) {
      int fid = gid >> 6, lane = gid & 63;
      int qd = lane >> 4, ln = lane & 15;
      half8 v;
      if (fid < 8) {
        int m = fid >> 1, kk = fid & 1;
        int o = m * 16 + ln;
#pragma unroll
        for (int j = 0; j < 8; ++j) {
          int ck = kk * 32 + qd * 8 + j;
          float val = 0.f;
          if (ck < 50) { int k_ = ck / 10, c = ck - 10 * k_; val = w1g[o * 50 + c * 5 + k_]; }
          v[j] = (_Float16)val;
        }
        w1f[fid * 64 + lane] = v;
      } else {
        int f2 = fid - 8;
        int k = f2 >> 3, kk = (f2 >> 2) & 1, m = f2 & 3;
        int o = m * 16 + ln;
#pragma unroll
        for (int j = 0; j < 8; ++j) {
          int ic = kk * 32 + qd * 8 + j;
          v[j] = (_Float16)w2g[o * 320 + ic * 5 + k];
        }
        w2f[f2 * 64 + lane] = v;
      }
    }
  }
}

// ---------------- low-barrier radix-select machinery ----------------
// scan phase: read own 4 bins (b128), zero them (self-cleaning), wave-scan, post wave total.
__device__ __forceinline__ void scan4096(unsigned (*hist)[4096], int j, int tid, int lane,
                                         int wv, unsigned (*sW)[16], uint4& v,
                                         unsigned& ps, unsigned& incl) {
  v = *reinterpret_cast<uint4*>(&hist[j][tid * 4]);
  uint4 zz = {0u, 0u, 0u, 0u};
  *reinterpret_cast<uint4*>(&hist[j][tid * 4]) = zz;
  ps = v.x + v.y + v.z + v.w;
  incl = ps;
#pragma unroll
  for (int off = 1; off < 64; off <<= 1) {
    unsigned tv = __shfl_up(incl, off, 64);
    if (lane >= off) incl += tv;
  }
  if (lane == 63) sW[j][wv] = incl;
}
// resolve phase (after barrier): cross-wave offset, winner writes (selb,selk).
__device__ __forceinline__ void resolve4096(const unsigned (*sW)[16], int j, int tid, int wv,
                                            uint4 v, unsigned ps, unsigned incl, unsigned k,
                                            unsigned* selb, unsigned* selk) {
  unsigned woff = 0;
  for (int i = 0; i < wv; ++i) woff += sW[j][i];
  incl += woff;
  unsigned excl = incl - ps;
  if (excl <= k && k < incl) {
    unsigned vv[4] = {v.x, v.y, v.z, v.w};
    unsigned run = excl;
    int c = 0;
#pragma unroll
    for (; c < 3; ++c) {
      if (run + vv[c] > k) break;
      run += vv[c];
    }
    *selb = (unsigned)(tid * 4 + c);
    *selk = k - run;
  }
}
__device__ __forceinline__ void scan256(unsigned (*hist)[4096], int j, int tid, int lane,
                                        int wv, unsigned (*sW)[16], unsigned& v,
                                        unsigned& incl) {
  v = (tid < 256) ? hist[j][tid] : 0u;
  if (tid < 256) hist[j][tid] = 0u;
  incl = v;
#pragma unroll
  for (int off = 1; off < 64; off <<= 1) {
    unsigned tv = __shfl_up(incl, off, 64);
    if (lane >= off) incl += tv;
  }
  if (lane == 63) sW[j][wv] = incl;
}
__device__ __forceinline__ void resolve256(const unsigned (*sW)[16], int j, int tid, int wv,
                                           unsigned v, unsigned incl, unsigned k,
                                           unsigned* selb) {
  unsigned woff = 0;
  for (int i = 0; i < wv; ++i) woff += sW[j][i];
  incl += woff;
  unsigned excl = incl - v;
  if (excl <= k && k < incl) *selb = (unsigned)tid;
}

// ---------------- Kernel B: selects + smooth + normalize (one block per row) ----------------
// Tri-select: 3 independent metric percentiles share one barrier sequence via 3 histograms.
__global__ __launch_bounds__(1024)
void ruleselect_k(const float* __restrict__ hc, const float* __restrict__ an,
                  const float* __restrict__ sc, const float* __restrict__ ot,
                  const float* __restrict__ amask, float* __restrict__ rule) {
  __shared__ unsigned hist3[3][4096];   // 48 KB
  __shared__ float vbuf[4096];          // 16 KB
  __shared__ unsigned selB[2][4];
  __shared__ unsigned selK[2][4];
  __shared__ unsigned sW3[3][16];
  __shared__ float sM3[3][16];
  __shared__ int iCnt[16];
  int b = blockIdx.x, tid = threadIdx.x;
  int lane = tid & 63, wv = tid >> 6;
  const float* mk = amask + (size_t)b * T_;
  const float* h0 = hc + (size_t)b * T_;
  const float* a0 = an + (size_t)b * T_;
  const float* s0 = sc + (size_t)b * T_;
  const float* o0 = ot + (size_t)b * T_;

  float mv0[4], mv1[4], mv2[4], otv[4], mreg[4];
  int cnt = 0;
#pragma unroll
  for (int r = 0; r < 4; ++r) {
    int t = tid + 1024 * r;
    mv0[r] = h0[t]; mv1[r] = a0[t]; mv2[r] = s0[t]; otv[r] = o0[t];
    mreg[r] = mk[t];
    cnt += (mreg[r] > 0.5f);
  }
#pragma unroll
  for (int off = 32; off; off >>= 1) cnt += __shfl_xor(cnt, off);
  if (lane == 0) iCnt[wv] = cnt;
  // zero all 3 histograms in the same phase
  {
    unsigned* hflat = &hist3[0][0];
    for (int i = tid; i < 3 * 4096; i += 1024) hflat[i] = 0u;
  }
  // candidate bits + fused 3-metric maxima
  unsigned u0[4], u1[4], u2[4];
  float mxa = 0.f, mxb = 0.f, mxc = 0.f;
#pragma unroll
  for (int r = 0; r < 4; ++r) {
    bool valid = mreg[r] > 0.5f;
    unsigned b0 = __float_as_uint(mv0[r]); if ((int)b0 < 0) b0 = 0u;  // -0.0 safety
    unsigned b1 = __float_as_uint(mv1[r]); if ((int)b1 < 0) b1 = 0u;
    unsigned b2 = __float_as_uint(mv2[r]); if ((int)b2 < 0) b2 = 0u;
    u0[r] = valid ? b0 : NOINS;
    u1[r] = valid ? b1 : NOINS;
    u2[r] = valid ? b2 : NOINS;
    if (valid) {
      mxa = fmaxf(mxa, fabsf(mv0[r]));
      mxb = fmaxf(mxb, fabsf(mv1[r]));
      mxc = fmaxf(mxc, fabsf(mv2[r]));
    }
  }
#pragma unroll
  for (int off = 32; off; off >>= 1) {
    mxa = fmaxf(mxa, __shfl_xor(mxa, off));
    mxb = fmaxf(mxb, __shfl_xor(mxb, off));
    mxc = fmaxf(mxc, __shfl_xor(mxc, off));
  }
  if (lane == 0) { sM3[0][wv] = mxa; sM3[1][wv] = mxb; sM3[2][wv] = mxc; }
  __syncthreads();  // B1: iCnt + zeros + maxima visible
  int n = 0;
#pragma unroll
  for (int i = 0; i < 16; ++i) n += iCnt[i];
  int cidx = (int)ceilf((float)n * 0.95f);
  if (cidx < 1) cidx = 1;
  unsigned kidx = (unsigned)(cidx - 1);
  if (kidx > (unsigned)(T_ - 1)) kidx = T_ - 1;
  float mx3a = sM3[0][0], mx3b = sM3[1][0], mx3c = sM3[2][0];
#pragma unroll
  for (int i = 1; i < 16; ++i) {
    mx3a = fmaxf(mx3a, sM3[0][i]);
    mx3b = fmaxf(mx3b, sM3[1][i]);
    mx3c = fmaxf(mx3c, sM3[2][i]);
  }

  // ---- tri-select round 1 (bits >> 20) ----
#pragma unroll
  for (int r = 0; r < 4; ++r) {
    if (u0[r] != NOINS) atomicAdd(&hist3[0][u0[r] >> 20], 1u);
    if (u1[r] != NOINS) atomicAdd(&hist3[1][u1[r] >> 20], 1u);
    if (u2[r] != NOINS) atomicAdd(&hist3[2][u2[r] >> 20], 1u);
  }
  __syncthreads();  // B2
  uint4 v40, v41, v42; unsigned ps0, ps1, ps2, in0, in1, in2;
  scan4096(hist3, 0, tid, lane, wv, sW3, v40, ps0, in0);
  scan4096(hist3, 1, tid, lane, wv, sW3, v41, ps1, in1);
  scan4096(hist3, 2, tid, lane, wv, sW3, v42, ps2, in2);
  __syncthreads();  // B3
  resolve4096(sW3, 0, tid, wv, v40, ps0, in0, kidx, &selB[1][0], &selK[1][0]);
  resolve4096(sW3, 1, tid, wv, v41, ps1, in1, kidx, &selB[1][1], &selK[1][1]);
  resolve4096(sW3, 2, tid, wv, v42, ps2, in2, kidx, &selB[1][2], &selK[1][2]);
  __syncthreads();  // B4
  unsigned p1_0 = selB[1][0], p1_1 = selB[1][1], p1_2 = selB[1][2];
  unsigned k2_0 = selK[1][0], k2_1 = selK[1][1], k2_2 = selK[1][2];
  // ---- round 2 (bits 8..19 within p1) ----
#pragma unroll
  for (int r = 0; r < 4; ++r) {
    if (u0[r] != NOINS && (u0[r] >> 20) == p1_0) atomicAdd(&hist3[0][(u0[r] >> 8) & 0xFFFu], 1u);
    if (u1[r] != NOINS && (u1[r] >> 20) == p1_1) atomicAdd(&hist3[1][(u1[r] >> 8) & 0xFFFu], 1u);
    if (u2[r] != NOINS && (u2[r] >> 20) == p1_2) atomicAdd(&hist3[2][(u2[r] >> 8) & 0xFFFu], 1u);
  }
  __syncthreads();  // B5
  scan4096(hist3, 0, tid, lane, wv, sW3, v40, ps0, in0);
  scan4096(hist3, 1, tid, lane, wv, sW3, v41, ps1, in1);
  scan4096(hist3, 2, tid, lane, wv, sW3, v42, ps2, in2);
  __syncthreads();  // B6
  resolve4096(sW3, 0, tid, wv, v40, ps0, in0, k2_0, &selB[0][0], &selK[0][0]);
  resolve4096(sW3, 1, tid, wv, v41, ps1, in1, k2_1, &selB[0][1], &selK[0][1]);
  resolve4096(sW3, 2, tid, wv, v42, ps2, in2, k2_2, &selB[0][2], &selK[0][2]);
  __syncthreads();  // B7
  unsigned p2_0 = selB[0][0], p2_1 = selB[0][1], p2_2 = selB[0][2];
  unsigned k3_0 = selK[0][0], k3_1 = selK[0][1], k3_2 = selK[0][2];
  unsigned pf0 = (p1_0 << 12) | p2_0, pf1 = (p1_1 << 12) | p2_1, pf2 = (p1_2 << 12) | p2_2;
  // ---- round 3 (low 8 bits within prefix) ----
#pragma unroll
  for (int r = 0; r < 4; ++r) {
    if (u0[r] != NOINS && (u0[r] >> 8) == pf0) atomicAdd(&hist3[0][u0[r] & 0xFFu], 1u);
    if (u1[r] != NOINS && (u1[r] >> 8) == pf1) atomicAdd(&hist3[1][u1[r] & 0xFFu], 1u);
    if (u2[r] != NOINS && (u2[r] >> 8) == pf2) atomicAdd(&hist3[2][u2[r] & 0xFFu], 1u);
  }
  __syncthreads();  // B8
  unsigned s80, s81, s82;
  scan256(hist3, 0, tid, lane, wv, sW3, s80, in0);
  scan256(hist3, 1, tid, lane, wv, sW3, s81, in1);
  scan256(hist3, 2, tid, lane, wv, sW3, s82, in2);
  __syncthreads();  // B9
  resolve256(sW3, 0, tid, wv, s80, in0, k3_0, &selB[1][0]);
  resolve256(sW3, 1, tid, wv, s81, in1, k3_1, &selB[1][1]);
  resolve256(sW3, 2, tid, wv, s82, in2, k3_2, &selB[1][2]);
  __syncthreads();  // B10
  float kth0 = fabsf(__uint_as_float((p1_0 << 20) | (p2_0 << 8) | selB[1][0]));
  float kth1 = fabsf(__uint_as_float((p1_1 << 20) | (p2_1 << 8) | selB[1][1]));
  float kth2 = fabsf(__uint_as_float((p1_2 << 20) | (p2_2 << 8) | selB[1][2]));
  float sc0 = fmaxf((kth0 < 1e-6f) ? mx3a : kth0, 1e-6f);
  float sc1 = fmaxf((kth1 < 1e-6f) ? mx3b : kth1, 1e-6f);
  float sc2 = fmaxf((kth2 < 1e-6f) ? mx3c : kth2, 1e-6f);

  // ---- combine + smooth ----
#pragma unroll
  for (int r = 0; r < 4; ++r) {
    int t = tid + 1024 * r;
    float v = 0.f;
    if (n > 0) {
      v = 0.35f * (mv0[r] / sc0) + 0.30f * (mv1[r] / sc1)
        + 0.25f * (mv2[r] / sc2) + 0.10f * otv[r];
    }
    vbuf[t] = v;
  }
  __syncthreads();  // B11
  float sm[4];
#pragma unroll
  for (int r = 0; r < 4; ++r) {
    int t = tid + 1024 * r;
    float s = 0.f;
#pragma unroll
    for (int d = -2; d <= 2; ++d) {
      int tt = t + d;
      if (tt >= 0 && tt < T_) s += vbuf[tt];
    }
    sm[r] = s * 0.2f * mreg[r];
  }
  // ---- 4th select (single metric, hist3[0], slot index 3) ----
  unsigned uu[4];
  float mxs = 0.f;
#pragma unroll
  for (int r = 0; r < 4; ++r) {
    bool valid = mreg[r] > 0.5f;
    unsigned ub = __float_as_uint(sm[r]); if ((int)ub < 0) ub = 0u;
    uu[r] = valid ? ub : NOINS;
    if (valid) mxs = fmaxf(mxs, fabsf(sm[r]));
  }
#pragma unroll
  for (int off = 32; off; off >>= 1) mxs = fmaxf(mxs, __shfl_xor(mxs, off));
  if (lane == 0) sM3[0][wv] = mxs;
#pragma unroll
  for (int r = 0; r < 4; ++r)
    if (uu[r] != NOINS) atomicAdd(&hist3[0][uu[r] >> 20], 1u);
  __syncthreads();  // B12
  float mx4 = sM3[0][0];
#pragma unroll
  for (int i = 1; i < 16; ++i) mx4 = fmaxf(mx4, sM3[0][i]);
  scan4096(hist3, 0, tid, lane, wv, sW3, v40, ps0, in0);
  __syncthreads();  // B13
  resolve4096(sW3, 0, tid, wv, v40, ps0, in0, kidx, &selB[1][3], &selK[1][3]);
  __syncthreads();  // B14
  unsigned q1 = selB[1][3], kq2 = selK[1][3];
#pragma unroll
  for (int r = 0; r < 4; ++r)
    if (uu[r] != NOINS && (uu[r] >> 20) == q1) atomicAdd(&hist3[0][(uu[r] >> 8) & 0xFFFu], 1u);
  __syncthreads();  // B15
  scan4096(hist3, 0, tid, lane, wv, sW3, v40, ps0, in0);
  __syncthreads();  // B16
  resolve4096(sW3, 0, tid, wv, v40, ps0, in0, kq2, &selB[0][3], &selK[0][3]);
  __syncthreads();  // B17
  unsigned q2 = selB[0][3], kq3 = selK[0][3];
  unsigned qf = (q1 << 12) | q2;
#pragma unroll
  for (int r = 0; r < 4; ++r)
    if (uu[r] != NOINS && (uu[r] >> 8) == qf) atomicAdd(&hist3[0][uu[r] & 0xFFu], 1u);
  __syncthreads();  // B18
  scan256(hist3, 0, tid, lane, wv, sW3, s80, in0);
  __syncthreads();  // B19
  resolve256(sW3, 0, tid, wv, s80, in0, kq3, &selB[1][3]);
  __syncthreads();  // B20
  float kth4 = fabsf(__uint_as_float((q1 << 20) | (q2 << 8) | selB[1][3]));
  float scale4 = fmaxf((kth4 < 1e-6f) ? mx4 : kth4, 1e-6f);
  float* rrow = rule + (size_t)b * T_;
#pragma unroll
  for (int r = 0; r < 4; ++r) {
    int t = tid + 1024 * r;
    float v = (n > 0) ? sm[r] / scale4 : 0.f;
    rrow[t] = clip01(v) * mreg[r];
  }
}

// ---------------- Kernel C: MFMA conv stack (exact round-4 version, 80 us) ----------------
__global__ __launch_bounds__(512, 4)
void conv_k(const float* __restrict__ feats, const half8* __restrict__ w1f,
            const float* __restrict__ b1g, const half8* __restrict__ w2f,
            const float* __restrict__ b2g, const float* __restrict__ w3g,
            const float* __restrict__ b3g, const float* __restrict__ amask,
            float* __restrict__ lp) {
  __shared__ _Float16 sIm[144 * 72];
  __shared__ _Float16 sH1[132 * 72];
  __shared__ float sF[10 * 136];
  __shared__ float sPart[2][128];
  int tid = threadIdx.x;
  int lane = tid & 63, w = tid >> 6;
  int qd = lane >> 4, ln = lane & 15;
  int tile = blockIdx.x, b = blockIdx.y;
  int t0 = tile * TTILE;
  const float* frow = feats + (size_t)b * 10 * T_;

  for (int s = tid; s < 1360; s += 512) {
    int c = s / 136, u = s - c * 136;
    int t = t0 - 4 + u;
    sF[s] = (t >= 0 && t < T_) ? frow[(size_t)c * T_ + t] * 0.015625f : 0.f;
  }
  for (int s = tid; s < 144 * 7; s += 512) {
    int jt = s / 7, d = s - jt * 7;
    *reinterpret_cast<unsigned*>(&sIm[jt * 72 + 50 + 2 * d]) = 0u;
  }
  __syncthreads();
  for (int s = tid; s < 660; s += 512) {
    int jt = s / 5, k = s - jt * 5;
#pragma unroll
    for (int cp = 0; cp < 5; ++cp) {
      float lo = sF[(2 * cp) * 136 + jt + k];
      float hi = sF[(2 * cp + 1) * 136 + jt + k];
      half2_t pk;
      pk[0] = (_Float16)lo;
      pk[1] = (_Float16)hi;
      *reinterpret_cast<half2_t*>(&sIm[jt * 72 + k * 10 + 2 * cp]) = pk;
    }
  }
  __syncthreads();

  half8 a1[4][2];
#pragma unroll
  for (int m = 0; m < 4; ++m)
#pragma unroll
    for (int kk = 0; kk < 2; ++kk) a1[m][kk] = w1f[(m * 2 + kk) * 64 + lane];

  for (int n0 = w; n0 < 9; n0 += 8) {
    int jt = n0 * 16 + ln;
    half8 bf0 = *reinterpret_cast<const half8*>(&sIm[jt * 72 + qd * 8]);
    half8 bf1 = *reinterpret_cast<const half8*>(&sIm[jt * 72 + 32 + qd * 8]);
#pragma unroll
    for (int m = 0; m < 4; ++m) {
      f32x4 acc;
      f32x4 bv = *reinterpret_cast<const f32x4*>(&b1g[m * 16 + qd * 4]);
#pragma unroll
      for (int r = 0; r < 4; ++r) acc[r] = bv[r] * 0.015625f;
      acc = __builtin_amdgcn_mfma_f32_16x16x32_f16(a1[m][0], bf0, acc, 0, 0, 0);
      acc = __builtin_amdgcn_mfma_f32_16x16x32_f16(a1[m][1], bf1, acc, 0, 0, 0);
      if (jt < 132) {
        int t = t0 - 2 + jt;
        bool inr = (t >= 0 && t < T_);
        half4 hv;
#pragma unroll
        for (int r = 0; r < 4; ++r) {
          float h = inr ? gelu_fast(acc[r] * 64.f) * 0.0625f : 0.f;
          hv[r] = (_Float16)h;
        }
        *reinterpret_cast<half4*>(&sH1[jt * 72 + m * 16 + qd * 4]) = hv;
      }
    }
  }
  __syncthreads();

  int p = w & 1, nq = w >> 1;
  f32x4 acc2[2][2];
#pragma unroll
  for (int dm = 0; dm < 2; ++dm) {
    f32x4 bv = *reinterpret_cast<const f32x4*>(&b2g[(2 * p + dm) * 16 + qd * 4]);
#pragma unroll
    for (int dn = 0; dn < 2; ++dn)
#pragma unroll
      for (int r = 0; r < 4; ++r) acc2[dm][dn][r] = bv[r] * 0.0625f;
  }
#pragma unroll
  for (int k = 0; k < 5; ++k) {
#pragma unroll
    for (int kk = 0; kk < 2; ++kk) {
      half8 A0 = w2f[((k * 2 + kk) * 4 + 2 * p + 0) * 64 + lane];
      half8 A1 = w2f[((k * 2 + kk) * 4 + 2 * p + 1) * 64 + lane];
      half8 B0 = *reinterpret_cast<const half8*>(
          &sH1[((2 * nq + 0) * 16 + ln + k) * 72 + kk * 32 + qd * 8]);
      half8 B1 = *reinterpret_cast<const half8*>(
          &sH1[((2 * nq + 1) * 16 + ln + k) * 72 + kk * 32 + qd * 8]);
      acc2[0][0] = __builtin_amdgcn_mfma_f32_16x16x32_f16(A0, B0, acc2[0][0], 0, 0, 0);
      acc2[0][1] = __builtin_amdgcn_mfma_f32_16x16x32_f16(A0, B1, acc2[0][1], 0, 0, 0);
      acc2[1][0] = __builtin_amdgcn_mfma_f32_16x16x32_f16(A1, B0, acc2[1][0], 0, 0, 0);
      acc2[1][1] = __builtin_amdgcn_mfma_f32_16x16x32_f16(A1, B1, acc2[1][1], 0, 0, 0);
    }
  }
  f32x4 w3a = *reinterpret_cast<const f32x4*>(&w3g[(2 * p + 0) * 16 + qd * 4]);
  f32x4 w3b = *reinterpret_cast<const f32x4*>(&w3g[(2 * p + 1) * 16 + qd * 4]);
#pragma unroll
  for (int dn = 0; dn < 2; ++dn) {
    float s = 0.f;
#pragma unroll
    for (int r = 0; r < 4; ++r) s += w3a[r] * gelu_fast(acc2[0][dn][r] * 16.f);
#pragma unroll
    for (int r = 0; r < 4; ++r) s += w3b[r] * gelu_fast(acc2[1][dn][r] * 16.f);
    s += __shfl_xor(s, 16);
    s += __shfl_xor(s, 32);
    if (lane < 16) sPart[p][(2 * nq + dn) * 16 + lane] = s;
  }
  __syncthreads();
  if (tid < 128) {
    int t = t0 + tid;
    float logit = sPart[0][tid] + sPart[1][tid] + b3g[0];
    float m = amask[(size_t)b * T_ + t];
    lp[(size_t)b * T_ + t] = (1.f / (1.f + expf(-logit))) * m;
  }
}

// ---------------- Kernel D: smooth learned + blend (unchanged) ----------------
__global__ __launch_bounds__(256)
void final_k(const float* __restrict__ rule, const float* __restrict__ lp,
             const float* __restrict__ amask, float* __restrict__ out) {
  int idx = blockIdx.x * 256 + threadIdx.x;
  if (idx >= BT) return;
  int t = idx & (T_ - 1);
  float s = 0.f;
#pragma unroll
  for (int d = -2; d <= 2; ++d) {
    int tt = t + d;
    if (tt >= 0 && tt < T_) s += lp[idx + d];
  }
  float m = amask[idx];
  float learned = clip01(s * 0.2f * m);
  out[idx] = clip01(0.5f * rule[idx] + 0.5f * learned) * m;
}

}  // namespace

extern "C" void kernel_launch(void* const* d_in, const int* in_sizes, int n_in,
                              void* d_out, int out_size, void* d_ws, size_t ws_size,
                              hipStream_t stream) {
  const float* traj      = (const float*)d_in[0];
  const float* intervals = (const float*)d_in[1];
  const float* amask     = (const float*)d_in[2];
  const float* omask     = (const float*)d_in[3];
  const float* w1        = (const float*)d_in[4];
  const float* b1        = (const float*)d_in[5];
  const float* w2        = (const float*)d_in[6];
  const float* b2        = (const float*)d_in[7];
  const float* w3        = (const float*)d_in[8];
  const float* b3        = (const float*)d_in[9];
  float* out = (float*)d_out;
  float* ws = (float*)d_ws;

  float* feats = ws + OFF_FEATS;
  float* hc    = ws + OFF_HC;
  float* an    = ws + OFF_AN;
  float* sc    = ws + OFF_SC;
  float* ot    = ws + OFF_OT;
  float* rule  = ws + OFF_RULE;
  float* lp    = ws + OFF_LP;
  half8* w1f = (half8*)(ws + OFF_W1F);
  half8* w2f = (half8*)(ws + OFF_W2F);

  featurize_k<<<BT / 256, 256, 0, stream>>>(traj, intervals, amask, omask, w1, w2,
                                            feats, hc, an, sc, ot, w1f, w2f);
  ruleselect_k<<<B_, 1024, 0, stream>>>(hc, an, sc, ot, amask, rule);
  conv_k<<<dim3(T_ / TTILE, B_), 512, 0, stream>>>(feats, w1f, b1, w2f, b2, w3, b3,
                                                   amask, lp);
  final_k<<<BT / 256, 256, 0, stream>>>(rule, lp, amask, out);
}

// Round 10
// 159.141 us; speedup vs baseline: 1.7555x; 1.1238x over previous
//
#include <hip/hip_runtime.h>

namespace {

constexpr int B_ = 128;
constexpr int T_ = 4096;
constexpr int BT = B_ * T_;
constexpr int TTILE = 128;
constexpr unsigned NOINS = 0xFFFFFFFFu;  // "do not insert" sentinel (invalid/masked lane)

// workspace layout (float offsets)
constexpr size_t OFF_W1F = 0;                     // 8 frags * 64 * 8 f16
constexpr size_t OFF_W2F = 2048;                  // 40 frags * 64 * 8 f16
constexpr size_t OFF_F16 = 16384;                 // feats16: B*T*10 halfs = B*T*5 dwords
constexpr size_t OFF_HC  = OFF_F16 + (size_t)BT * 5 / 2 * 2;  // = OFF_F16 + BT*5 (dword=float count)
constexpr size_t OFF_AN  = OFF_HC + (size_t)BT;
constexpr size_t OFF_SC  = OFF_AN + (size_t)BT;
constexpr size_t OFF_OT  = OFF_SC + (size_t)BT;
constexpr size_t OFF_LP  = OFF_OT + (size_t)BT;

typedef _Float16 half8 __attribute__((ext_vector_type(8)));
typedef _Float16 half4 __attribute__((ext_vector_type(4)));
typedef _Float16 half2_t __attribute__((ext_vector_type(2)));
typedef float f32x4 __attribute__((ext_vector_type(4)));

__device__ __forceinline__ float clip01(float x) { return fminf(fmaxf(x, 0.f), 1.f); }

// tanh-GELU as sigmoid: x*sigmoid(1.5957691*(x+0.044715x^3)), 7 VALU ops.
// |err vs exact| <= ~3e-3 per eval; washes to <1e-3 at final output (see analysis).
__device__ __forceinline__ float gelu_tanh(float x) {
  float x2 = x * x;
  float q = x * __builtin_fmaf(-0.10294444f, x2, -2.3022077f);
  float e = __builtin_amdgcn_exp2f(q);
  return x * __builtin_amdgcn_rcpf(1.0f + e);
}

// feature math for (b,t) — bit-identical to round-4 featurize_k
__device__ __forceinline__ void compute_feats(
    const float* __restrict__ tr, const float* __restrict__ iv,
    const float* __restrict__ mk, const float* __restrict__ om, int t,
    float* __restrict__ f /*10*/, float* anv_out, float* scv_out, float* otv_out) {
  float m  = mk[t];
  float m1 = (t >= 1) ? mk[t - 1] : 0.f;
  float m2 = (t >= 2) ? mk[t - 2] : 0.f;
  float pm01 = (m > 0.5f && m1 > 0.5f) ? 1.f : 0.f;
  float pm12 = (m1 > 0.5f && m2 > 0.5f) ? 1.f : 0.f;
  float x0x = tr[2 * t] * m, x0y = tr[2 * t + 1] * m;
  float x1x = 0.f, x1y = 0.f, x2x = 0.f, x2y = 0.f;
  if (t >= 1) { x1x = tr[2 * (t - 1)] * m1; x1y = tr[2 * (t - 1) + 1] * m1; }
  if (t >= 2) { x2x = tr[2 * (t - 2)] * m2; x2y = tr[2 * (t - 2) + 1] * m2; }
  float dt0 = fmaxf(iv[t], 1e-3f);
  float dt1 = (t >= 1) ? fmaxf(iv[t - 1], 1e-3f) : 1e-3f;
  float vx = 0.f, vy = 0.f, v1x = 0.f, v1y = 0.f;
  if (t >= 1) { vx = (x0x - x1x) * pm01 / dt0 * m; vy = (x0y - x1y) * pm01 / dt0 * m; }
  if (t >= 2) { v1x = (x1x - x2x) * pm12 / dt1 * m1; v1y = (x1y - x2y) * pm12 / dt1 * m1; }
  float ax = 0.f, ay = 0.f;
  if (t >= 1) { ax = (vx - v1x) * pm01 / dt0 * m; ay = (vy - v1y) * pm01 / dt0 * m; }
  float s2 = vx * vx + vy * vy;
  float speed = (s2 > 0.f ? sqrtf(s2) : 0.f) * m;
  float s21 = v1x * v1x + v1y * v1y;
  float speed1 = (s21 > 0.f ? sqrtf(s21) : 0.f) * m1;
  float scv = (t >= 1) ? fabsf((speed - speed1) * pm01) * m : 0.f;
  float a2 = ax * ax + ay * ay;
  float anv = (a2 > 0.f ? sqrtf(a2) : 0.f) * m;
  float hcv = 0.f;
  if (t >= 1) {
    bool z0 = (vx == 0.f && vy == 0.f);
    bool z1 = (v1x == 0.f && v1y == 0.f);
    float yy, xx;
    if (z1)      { yy = vy;  xx = vx; }
    else if (z0) { yy = v1y; xx = v1x; }
    else { yy = vy * v1x - vx * v1y; xx = vx * v1x + vy * v1y; }
    hcv = fabsf(atan2f(yy, xx)) * pm01 * m;
  }
  float obs = om[t] * m;
  float otv = (t >= 1) ? fminf(fabsf(om[t] - om[t - 1]) * pm01 * m, 1.f) : 0.f;
  float itf = iv[t] * m;
  f[0] = x0x; f[1] = x0y; f[2] = vx; f[3] = vy; f[4] = ax; f[5] = ay;
  f[6] = speed; f[7] = hcv; f[8] = itf; f[9] = obs;
  *anv_out = anv; *scv_out = scv; *otv_out = otv;
}

// ---------------- Kernel A: featurize -> f16 interleaved feats + metrics + repack ----------------
__global__ __launch_bounds__(256)
void featurize_k(const float* __restrict__ traj, const float* __restrict__ intervals,
                 const float* __restrict__ amask, const float* __restrict__ omask,
                 const float* __restrict__ w1g, const float* __restrict__ w2g,
                 _Float16* __restrict__ feats16, float* __restrict__ hc,
                 float* __restrict__ an, float* __restrict__ sc, float* __restrict__ ot,
                 half8* __restrict__ w1f, half8* __restrict__ w2f) {
  int idx = blockIdx.x * 256 + threadIdx.x;
  int b = idx >> 12;
  int t = idx & (T_ - 1);
  float f[10], anv, scv, otv;
  compute_feats(traj + (size_t)b * T_ * 2, intervals + (size_t)b * T_,
                amask + (size_t)b * T_, omask + (size_t)b * T_, t, f, &anv, &scv, &otv);
  // interleaved [t][c] layout, pre-scaled 2^-6 (RNE — bit-identical to old stage+cvt path)
  half2_t* fd = reinterpret_cast<half2_t*>(feats16) + (size_t)idx * 5;
#pragma unroll
  for (int q = 0; q < 5; ++q) {
    half2_t pk;
    pk[0] = (_Float16)(f[2 * q] * 0.015625f);
    pk[1] = (_Float16)(f[2 * q + 1] * 0.015625f);
    fd[q] = pk;
  }
  hc[idx] = f[7]; an[idx] = anv; sc[idx] = scv; ot[idx] = otv;

  // fused repack: first 12 blocks also build MFMA weight fragments
  if (blockIdx.x < 12) {
    int gid = blockIdx.x * 256 + threadIdx.x;
    if (gid < 48 * 64) {
      int fid = gid >> 6, lane = gid & 63;
      int qd = lane >> 4, ln = lane & 15;
      half8 v;
      if (fid < 8) {
        int m = fid >> 1, kk = fid & 1;
        int o = m * 16 + ln;
#pragma unroll
        for (int j = 0; j < 8; ++j) {
          int ck = kk * 32 + qd * 8 + j;
          float val = 0.f;
          if (ck < 50) { int k_ = ck / 10, c = ck - 10 * k_; val = w1g[o * 50 + c * 5 + k_]; }
          v[j] = (_Float16)val;
        }
        w1f[fid * 64 + lane] = v;
      } else {
        int f2 = fid - 8;
        int k = f2 >> 3, kk = (f2 >> 2) & 1, m = f2 & 3;
        int o = m * 16 + ln;
#pragma unroll
        for (int j = 0; j < 8; ++j) {
          int ic = kk * 32 + qd * 8 + j;
          v[j] = (_Float16)w2g[o * 320 + ic * 5 + k];
        }
        w2f[f2 * 64 + lane] = v;
      }
    }
  }
}

// ---------------- Kernel B: MFMA conv stack (f16 feats in, lean staging, tanh-GELU) ----------------
__global__ __launch_bounds__(512, 4)
void conv_k(const _Float16* __restrict__ feats16, const half8* __restrict__ w1f,
            const float* __restrict__ b1g, const half8* __restrict__ w2f,
            const float* __restrict__ b2g, const float* __restrict__ w3g,
            const float* __restrict__ b3g, const float* __restrict__ amask,
            float* __restrict__ lp) {
  __shared__ _Float16 sIm[144 * 72];
  __shared__ _Float16 sH1[132 * 72];
  __shared__ _Float16 sF16[136 * 10];   // interleaved [u][c], u = t-(t0-4)
  __shared__ float sPart[2][128];
  int tid = threadIdx.x;
  int lane = tid & 63, w = tid >> 6;
  int qd = lane >> 4, ln = lane & 15;
  int tile = blockIdx.x, b = blockIdx.y;
  int t0 = tile * TTILE;

  // stage f16 feats (680 dwords), already scaled; OOB t -> 0
  const unsigned* gfd = reinterpret_cast<const unsigned*>(feats16 + (size_t)b * T_ * 10);
  unsigned* sFd = reinterpret_cast<unsigned*>(sF16);
  int dbase = (t0 - 4) * 5;
  for (int s = tid; s < 680; s += 512) {
    int gi = dbase + s;
    sFd[s] = (gi >= 0 && gi < T_ * 5) ? gfd[gi] : 0u;
  }
  // zero K-pad cols [50,64) of im2col for ALL rows
  for (int s = tid; s < 144 * 7; s += 512) {
    int jt = s / 7, d = s - jt * 7;
    *reinterpret_cast<unsigned*>(&sIm[jt * 72 + 50 + 2 * d]) = 0u;
  }
  __syncthreads();
  // im2col: pure dword LDS->LDS copies (no converts)
  unsigned* sId = reinterpret_cast<unsigned*>(sIm);
  for (int s = tid; s < 660; s += 512) {
    int jt = s / 5, k = s - jt * 5;
    const unsigned* src = sFd + (jt + k) * 5;
    unsigned* dst = sId + jt * 36 + k * 5;
#pragma unroll
    for (int q = 0; q < 5; ++q) dst[q] = src[q];
  }
  __syncthreads();

  half8 a1[4][2];
#pragma unroll
  for (int m = 0; m < 4; ++m)
#pragma unroll
    for (int kk = 0; kk < 2; ++kk) a1[m][kk] = w1f[(m * 2 + kk) * 64 + lane];

  for (int n0 = w; n0 < 9; n0 += 8) {
    int jt = n0 * 16 + ln;
    half8 bf0 = *reinterpret_cast<const half8*>(&sIm[jt * 72 + qd * 8]);
    half8 bf1 = *reinterpret_cast<const half8*>(&sIm[jt * 72 + 32 + qd * 8]);
#pragma unroll
    for (int m = 0; m < 4; ++m) {
      f32x4 acc;
      f32x4 bv = *reinterpret_cast<const f32x4*>(&b1g[m * 16 + qd * 4]);
#pragma unroll
      for (int r = 0; r < 4; ++r) acc[r] = bv[r] * 0.015625f;
      acc = __builtin_amdgcn_mfma_f32_16x16x32_f16(a1[m][0], bf0, acc, 0, 0, 0);
      acc = __builtin_amdgcn_mfma_f32_16x16x32_f16(a1[m][1], bf1, acc, 0, 0, 0);
      if (jt < 132) {
        int t = t0 - 2 + jt;
        bool inr = (t >= 0 && t < T_);
        half4 hv;
#pragma unroll
        for (int r = 0; r < 4; ++r) {
          float h = inr ? gelu_tanh(acc[r] * 64.f) * 0.0625f : 0.f;
          hv[r] = (_Float16)h;
        }
        *reinterpret_cast<half4*>(&sH1[jt * 72 + m * 16 + qd * 4]) = hv;
      }
    }
  }
  __syncthreads();

  int p = w & 1, nq = w >> 1;
  f32x4 acc2[2][2];
#pragma unroll
  for (int dm = 0; dm < 2; ++dm) {
    f32x4 bv = *reinterpret_cast<const f32x4*>(&b2g[(2 * p + dm) * 16 + qd * 4]);
#pragma unroll
    for (int dn = 0; dn < 2; ++dn)
#pragma unroll
      for (int r = 0; r < 4; ++r) acc2[dm][dn][r] = bv[r] * 0.0625f;
  }
#pragma unroll
  for (int k = 0; k < 5; ++k) {
#pragma unroll
    for (int kk = 0; kk < 2; ++kk) {
      half8 A0 = w2f[((k * 2 + kk) * 4 + 2 * p + 0) * 64 + lane];
      half8 A1 = w2f[((k * 2 + kk) * 4 + 2 * p + 1) * 64 + lane];
      half8 B0 = *reinterpret_cast<const half8*>(
          &sH1[((2 * nq + 0) * 16 + ln + k) * 72 + kk * 32 + qd * 8]);
      half8 B1 = *reinterpret_cast<const half8*>(
          &sH1[((2 * nq + 1) * 16 + ln + k) * 72 + kk * 32 + qd * 8]);
      acc2[0][0] = __builtin_amdgcn_mfma_f32_16x16x32_f16(A0, B0, acc2[0][0], 0, 0, 0);
      acc2[0][1] = __builtin_amdgcn_mfma_f32_16x16x32_f16(A0, B1, acc2[0][1], 0, 0, 0);
      acc2[1][0] = __builtin_amdgcn_mfma_f32_16x16x32_f16(A1, B0, acc2[1][0], 0, 0, 0);
      acc2[1][1] = __builtin_amdgcn_mfma_f32_16x16x32_f16(A1, B1, acc2[1][1], 0, 0, 0);
    }
  }
  f32x4 w3a = *reinterpret_cast<const f32x4*>(&w3g[(2 * p + 0) * 16 + qd * 4]);
  f32x4 w3b = *reinterpret_cast<const f32x4*>(&w3g[(2 * p + 1) * 16 + qd * 4]);
#pragma unroll
  for (int dn = 0; dn < 2; ++dn) {
    float s = 0.f;
#pragma unroll
    for (int r = 0; r < 4; ++r) s += w3a[r] * gelu_tanh(acc2[0][dn][r] * 16.f);
#pragma unroll
    for (int r = 0; r < 4; ++r) s += w3b[r] * gelu_tanh(acc2[1][dn][r] * 16.f);
    s += __shfl_xor(s, 16);
    s += __shfl_xor(s, 32);
    if (lane < 16) sPart[p][(2 * nq + dn) * 16 + lane] = s;
  }
  __syncthreads();
  if (tid < 128) {
    int t = t0 + tid;
    float logit = sPart[0][tid] + sPart[1][tid] + b3g[0];
    float m = amask[(size_t)b * T_ + t];
    float e = __builtin_amdgcn_exp2f(logit * -1.4426950408889634f);
    lp[(size_t)b * T_ + t] = m * __builtin_amdgcn_rcpf(1.f + e);
  }
}

// ---------------- low-barrier radix-select machinery ----------------
__device__ __forceinline__ void scan4096(unsigned (*hist)[4096], int j, int tid, int lane,
                                         int wv, unsigned (*sW)[16], uint4& v,
                                         unsigned& ps, unsigned& incl) {
  v = *reinterpret_cast<uint4*>(&hist[j][tid * 4]);
  uint4 zz = {0u, 0u, 0u, 0u};
  *reinterpret_cast<uint4*>(&hist[j][tid * 4]) = zz;
  ps = v.x + v.y + v.z + v.w;
  incl = ps;
#pragma unroll
  for (int off = 1; off < 64; off <<= 1) {
    unsigned tv = __shfl_up(incl, off, 64);
    if (lane >= off) incl += tv;
  }
  if (lane == 63) sW[j][wv] = incl;
}
__device__ __forceinline__ void resolve4096(const unsigned (*sW)[16], int j, int tid, int wv,
                                            uint4 v, unsigned ps, unsigned incl, unsigned k,
                                            unsigned* selb, unsigned* selk) {
  unsigned woff = 0;
  for (int i = 0; i < wv; ++i) woff += sW[j][i];
  incl += woff;
  unsigned excl = incl - ps;
  if (excl <= k && k < incl) {
    unsigned vv[4] = {v.x, v.y, v.z, v.w};
    unsigned run = excl;
    int c = 0;
#pragma unroll
    for (; c < 3; ++c) {
      if (run + vv[c] > k) break;
      run += vv[c];
    }
    *selb = (unsigned)(tid * 4 + c);
    *selk = k - run;
  }
}
__device__ __forceinline__ void scan256(unsigned (*hist)[4096], int j, int tid, int lane,
                                        int wv, unsigned (*sW)[16], unsigned& v,
                                        unsigned& incl) {
  v = (tid < 256) ? hist[j][tid] : 0u;
  if (tid < 256) hist[j][tid] = 0u;
  incl = v;
#pragma unroll
  for (int off = 1; off < 64; off <<= 1) {
    unsigned tv = __shfl_up(incl, off, 64);
    if (lane >= off) incl += tv;
  }
  if (lane == 63) sW[j][wv] = incl;
}
__device__ __forceinline__ void resolve256(const unsigned (*sW)[16], int j, int tid, int wv,
                                           unsigned v, unsigned incl, unsigned k,
                                           unsigned* selb) {
  unsigned woff = 0;
  for (int i = 0; i < wv; ++i) woff += sW[j][i];
  incl += woff;
  unsigned excl = incl - v;
  if (excl <= k && k < incl) *selb = (unsigned)tid;
}

// ---------------- Kernel C: selects + smooth + normalize + FINAL BLEND (per row) ----------------
__global__ __launch_bounds__(1024)
void ruleselect_k(const float* __restrict__ hc, const float* __restrict__ an,
                  const float* __restrict__ sc, const float* __restrict__ ot,
                  const float* __restrict__ amask, const float* __restrict__ lp,
                  float* __restrict__ out) {
  __shared__ unsigned hist3[3][4096];
  __shared__ float vbuf[4096];
  __shared__ unsigned selB[2][4];
  __shared__ unsigned selK[2][4];
  __shared__ unsigned sW3[3][16];
  __shared__ float sM3[3][16];
  __shared__ int iCnt[16];
  int b = blockIdx.x, tid = threadIdx.x;
  int lane = tid & 63, wv = tid >> 6;
  const float* mk = amask + (size_t)b * T_;
  const float* h0 = hc + (size_t)b * T_;
  const float* a0 = an + (size_t)b * T_;
  const float* s0 = sc + (size_t)b * T_;
  const float* o0 = ot + (size_t)b * T_;

  float mv0[4], mv1[4], mv2[4], otv[4], mreg[4];
  int cnt = 0;
#pragma unroll
  for (int r = 0; r < 4; ++r) {
    int t = tid + 1024 * r;
    mv0[r] = h0[t]; mv1[r] = a0[t]; mv2[r] = s0[t]; otv[r] = o0[t];
    mreg[r] = mk[t];
    cnt += (mreg[r] > 0.5f);
  }
#pragma unroll
  for (int off = 32; off; off >>= 1) cnt += __shfl_xor(cnt, off);
  if (lane == 0) iCnt[wv] = cnt;
  {
    unsigned* hflat = &hist3[0][0];
    for (int i = tid; i < 3 * 4096; i += 1024) hflat[i] = 0u;
  }
  unsigned u0[4], u1[4], u2[4];
  float mxa = 0.f, mxb = 0.f, mxc = 0.f;
#pragma unroll
  for (int r = 0; r < 4; ++r) {
    bool valid = mreg[r] > 0.5f;
    unsigned b0 = __float_as_uint(mv0[r]); if ((int)b0 < 0) b0 = 0u;
    unsigned b1 = __float_as_uint(mv1[r]); if ((int)b1 < 0) b1 = 0u;
    unsigned b2 = __float_as_uint(mv2[r]); if ((int)b2 < 0) b2 = 0u;
    u0[r] = valid ? b0 : NOINS;
    u1[r] = valid ? b1 : NOINS;
    u2[r] = valid ? b2 : NOINS;
    if (valid) {
      mxa = fmaxf(mxa, fabsf(mv0[r]));
      mxb = fmaxf(mxb, fabsf(mv1[r]));
      mxc = fmaxf(mxc, fabsf(mv2[r]));
    }
  }
#pragma unroll
  for (int off = 32; off; off >>= 1) {
    mxa = fmaxf(mxa, __shfl_xor(mxa, off));
    mxb = fmaxf(mxb, __shfl_xor(mxb, off));
    mxc = fmaxf(mxc, __shfl_xor(mxc, off));
  }
  if (lane == 0) { sM3[0][wv] = mxa; sM3[1][wv] = mxb; sM3[2][wv] = mxc; }
  __syncthreads();  // B1
  int n = 0;
#pragma unroll
  for (int i = 0; i < 16; ++i) n += iCnt[i];
  int cidx = (int)ceilf((float)n * 0.95f);
  if (cidx < 1) cidx = 1;
  unsigned kidx = (unsigned)(cidx - 1);
  if (kidx > (unsigned)(T_ - 1)) kidx = T_ - 1;
  float mx3a = sM3[0][0], mx3b = sM3[1][0], mx3c = sM3[2][0];
#pragma unroll
  for (int i = 1; i < 16; ++i) {
    mx3a = fmaxf(mx3a, sM3[0][i]);
    mx3b = fmaxf(mx3b, sM3[1][i]);
    mx3c = fmaxf(mx3c, sM3[2][i]);
  }

#pragma unroll
  for (int r = 0; r < 4; ++r) {
    if (u0[r] != NOINS) atomicAdd(&hist3[0][u0[r] >> 20], 1u);
    if (u1[r] != NOINS) atomicAdd(&hist3[1][u1[r] >> 20], 1u);
    if (u2[r] != NOINS) atomicAdd(&hist3[2][u2[r] >> 20], 1u);
  }
  __syncthreads();  // B2
  uint4 v40, v41, v42; unsigned ps0, ps1, ps2, in0, in1, in2;
  scan4096(hist3, 0, tid, lane, wv, sW3, v40, ps0, in0);
  scan4096(hist3, 1, tid, lane, wv, sW3, v41, ps1, in1);
  scan4096(hist3, 2, tid, lane, wv, sW3, v42, ps2, in2);
  __syncthreads();  // B3
  resolve4096(sW3, 0, tid, wv, v40, ps0, in0, kidx, &selB[1][0], &selK[1][0]);
  resolve4096(sW3, 1, tid, wv, v41, ps1, in1, kidx, &selB[1][1], &selK[1][1]);
  resolve4096(sW3, 2, tid, wv, v42, ps2, in2, kidx, &selB[1][2], &selK[1][2]);
  __syncthreads();  // B4
  unsigned p1_0 = selB[1][0], p1_1 = selB[1][1], p1_2 = selB[1][2];
  unsigned k2_0 = selK[1][0], k2_1 = selK[1][1], k2_2 = selK[1][2];
#pragma unroll
  for (int r = 0; r < 4; ++r) {
    if (u0[r] != NOINS && (u0[r] >> 20) == p1_0) atomicAdd(&hist3[0][(u0[r] >> 8) & 0xFFFu], 1u);
    if (u1[r] != NOINS && (u1[r] >> 20) == p1_1) atomicAdd(&hist3[1][(u1[r] >> 8) & 0xFFFu], 1u);
    if (u2[r] != NOINS && (u2[r] >> 20) == p1_2) atomicAdd(&hist3[2][(u2[r] >> 8) & 0xFFFu], 1u);
  }
  __syncthreads();  // B5
  scan4096(hist3, 0, tid, lane, wv, sW3, v40, ps0, in0);
  scan4096(hist3, 1, tid, lane, wv, sW3, v41, ps1, in1);
  scan4096(hist3, 2, tid, lane, wv, sW3, v42, ps2, in2);
  __syncthreads();  // B6
  resolve4096(sW3, 0, tid, wv, v40, ps0, in0, k2_0, &selB[0][0], &selK[0][0]);
  resolve4096(sW3, 1, tid, wv, v41, ps1, in1, k2_1, &selB[0][1], &selK[0][1]);
  resolve4096(sW3, 2, tid, wv, v42, ps2, in2, k2_2, &selB[0][2], &selK[0][2]);
  __syncthreads();  // B7
  unsigned p2_0 = selB[0][0], p2_1 = selB[0][1], p2_2 = selB[0][2];
  unsigned k3_0 = selK[0][0], k3_1 = selK[0][1], k3_2 = selK[0][2];
  unsigned pf0 = (p1_0 << 12) | p2_0, pf1 = (p1_1 << 12) | p2_1, pf2 = (p1_2 << 12) | p2_2;
#pragma unroll
  for (int r = 0; r < 4; ++r) {
    if (u0[r] != NOINS && (u0[r] >> 8) == pf0) atomicAdd(&hist3[0][u0[r] & 0xFFu], 1u);
    if (u1[r] != NOINS && (u1[r] >> 8) == pf1) atomicAdd(&hist3[1][u1[r] & 0xFFu], 1u);
    if (u2[r] != NOINS && (u2[r] >> 8) == pf2) atomicAdd(&hist3[2][u2[r] & 0xFFu], 1u);
  }
  __syncthreads();  // B8
  unsigned s80, s81, s82;
  scan256(hist3, 0, tid, lane, wv, sW3, s80, in0);
  scan256(hist3, 1, tid, lane, wv, sW3, s81, in1);
  scan256(hist3, 2, tid, lane, wv, sW3, s82, in2);
  __syncthreads();  // B9
  resolve256(sW3, 0, tid, wv, s80, in0, k3_0, &selB[1][0]);
  resolve256(sW3, 1, tid, wv, s81, in1, k3_1, &selB[1][1]);
  resolve256(sW3, 2, tid, wv, s82, in2, k3_2, &selB[1][2]);
  __syncthreads();  // B10
  float kth0 = fabsf(__uint_as_float((p1_0 << 20) | (p2_0 << 8) | selB[1][0]));
  float kth1 = fabsf(__uint_as_float((p1_1 << 20) | (p2_1 << 8) | selB[1][1]));
  float kth2 = fabsf(__uint_as_float((p1_2 << 20) | (p2_2 << 8) | selB[1][2]));
  float sc0 = fmaxf((kth0 < 1e-6f) ? mx3a : kth0, 1e-6f);
  float sc1 = fmaxf((kth1 < 1e-6f) ? mx3b : kth1, 1e-6f);
  float sc2 = fmaxf((kth2 < 1e-6f) ? mx3c : kth2, 1e-6f);

#pragma unroll
  for (int r = 0; r < 4; ++r) {
    int t = tid + 1024 * r;
    float v = 0.f;
    if (n > 0) {
      v = 0.35f * (mv0[r] / sc0) + 0.30f * (mv1[r] / sc1)
        + 0.25f * (mv2[r] / sc2) + 0.10f * otv[r];
    }
    vbuf[t] = v;
  }
  __syncthreads();  // B11
  float sm[4];
#pragma unroll
  for (int r = 0; r < 4; ++r) {
    int t = tid + 1024 * r;
    float s = 0.f;
#pragma unroll
    for (int d = -2; d <= 2; ++d) {
      int tt = t + d;
      if (tt >= 0 && tt < T_) s += vbuf[tt];
    }
    sm[r] = s * 0.2f * mreg[r];
  }
  // ---- 4th select (hist3[0], slot 3) ----
  unsigned uu[4];
  float mxs = 0.f;
#pragma unroll
  for (int r = 0; r < 4; ++r) {
    bool valid = mreg[r] > 0.5f;
    unsigned ub = __float_as_uint(sm[r]); if ((int)ub < 0) ub = 0u;
    uu[r] = valid ? ub : NOINS;
    if (valid) mxs = fmaxf(mxs, fabsf(sm[r]));
  }
#pragma unroll
  for (int off = 32; off; off >>= 1) mxs = fmaxf(mxs, __shfl_xor(mxs, off));
  if (lane == 0) sM3[0][wv] = mxs;
#pragma unroll
  for (int r = 0; r < 4; ++r)
    if (uu[r] != NOINS) atomicAdd(&hist3[0][uu[r] >> 20], 1u);
  __syncthreads();  // B12 — all smooth reads of vbuf done; safe to repurpose vbuf for lp
  // stage lp row into vbuf (reads happen after B13+)
  const float* lprow = lp + (size_t)b * T_;
#pragma unroll
  for (int r = 0; r < 4; ++r) {
    int t = tid + 1024 * r;
    vbuf[t] = lprow[t];
  }
  float mx4 = sM3[0][0];
#pragma unroll
  for (int i = 1; i < 16; ++i) mx4 = fmaxf(mx4, sM3[0][i]);
  scan4096(hist3, 0, tid, lane, wv, sW3, v40, ps0, in0);
  __syncthreads();  // B13
  resolve4096(sW3, 0, tid, wv, v40, ps0, in0, kidx, &selB[1][3], &selK[1][3]);
  __syncthreads();  // B14
  unsigned q1 = selB[1][3], kq2 = selK[1][3];
#pragma unroll
  for (int r = 0; r < 4; ++r)
    if (uu[r] != NOINS && (uu[r] >> 20) == q1) atomicAdd(&hist3[0][(uu[r] >> 8) & 0xFFFu], 1u);
  __syncthreads();  // B15
  scan4096(hist3, 0, tid, lane, wv, sW3, v40, ps0, in0);
  __syncthreads();  // B16
  resolve4096(sW3, 0, tid, wv, v40, ps0, in0, kq2, &selB[0][3], &selK[0][3]);
  __syncthreads();  // B17
  unsigned q2 = selB[0][3], kq3 = selK[0][3];
  unsigned qf = (q1 << 12) | q2;
#pragma unroll
  for (int r = 0; r < 4; ++r)
    if (uu[r] != NOINS && (uu[r] >> 8) == qf) atomicAdd(&hist3[0][uu[r] & 0xFFu], 1u);
  __syncthreads();  // B18
  scan256(hist3, 0, tid, lane, wv, sW3, s80, in0);
  __syncthreads();  // B19
  resolve256(sW3, 0, tid, wv, s80, in0, kq3, &selB[1][3]);
  __syncthreads();  // B20
  float kth4 = fabsf(__uint_as_float((q1 << 20) | (q2 << 8) | selB[1][3]));
  float scale4 = fmaxf((kth4 < 1e-6f) ? mx4 : kth4, 1e-6f);
  // ---- final blend (ex final_k): rule + smoothed learned -> out ----
  float* orow = out + (size_t)b * T_;
#pragma unroll
  for (int r = 0; r < 4; ++r) {
    int t = tid + 1024 * r;
    float rv = (n > 0) ? sm[r] / scale4 : 0.f;
    rv = clip01(rv) * mreg[r];
    float ssum = 0.f;
#pragma unroll
    for (int d = -2; d <= 2; ++d) {
      int tt = t + d;
      if (tt >= 0 && tt < T_) ssum += vbuf[tt];
    }
    float learned = clip01(ssum * 0.2f * mreg[r]);
    orow[t] = clip01(0.5f * rv + 0.5f * learned) * mreg[r];
  }
}

}  // namespace

extern "C" void kernel_launch(void* const* d_in, const int* in_sizes, int n_in,
                              void* d_out, int out_size, void* d_ws, size_t ws_size,
                              hipStream_t stream) {
  const float* traj      = (const float*)d_in[0];
  const float* intervals = (const float*)d_in[1];
  const float* amask     = (const float*)d_in[2];
  const float* omask     = (const float*)d_in[3];
  const float* w1        = (const float*)d_in[4];
  const float* b1        = (const float*)d_in[5];
  const float* w2        = (const float*)d_in[6];
  const float* b2        = (const float*)d_in[7];
  const float* w3        = (const float*)d_in[8];
  const float* b3        = (const float*)d_in[9];
  float* out = (float*)d_out;
  float* ws = (float*)d_ws;

  _Float16* feats16 = (_Float16*)(ws + OFF_F16);
  float* hc = ws + OFF_HC;
  float* an = ws + OFF_AN;
  float* sc = ws + OFF_SC;
  float* ot = ws + OFF_OT;
  float* lp = ws + OFF_LP;
  half8* w1f = (half8*)(ws + OFF_W1F);
  half8* w2f = (half8*)(ws + OFF_W2F);

  featurize_k<<<BT / 256, 256, 0, stream>>>(traj, intervals, amask, omask, w1, w2,
                                            feats16, hc, an, sc, ot, w1f, w2f);
  conv_k<<<dim3(T_ / TTILE, B_), 512, 0, stream>>>(feats16, w1f, b1, w2f, b2, w3, b3,
                                                   amask, lp);
  ruleselect_k<<<B_, 1024, 0, stream>>>(hc, an, sc, ot, amask, lp, out);
}

// Round 11
// 157.687 us; speedup vs baseline: 1.7717x; 1.0092x over previous
//
#include <hip/hip_runtime.h>

namespace {

constexpr int B_ = 128;
constexpr int T_ = 4096;
constexpr int BT = B_ * T_;
constexpr int TTILE = 128;
constexpr unsigned NOINS = 0xFFFFFFFFu;  // "do not insert" sentinel (invalid/masked lane)

// workspace layout (float offsets)
constexpr size_t OFF_W1F = 0;                     // 8 frags * 64 * 8 f16
constexpr size_t OFF_W2F = 2048;                  // 40 frags * 64 * 8 f16
constexpr size_t OFF_F16 = 16384;                 // feats16: B*T*10 halfs = B*T*5 dwords
constexpr size_t OFF_HC  = OFF_F16 + (size_t)BT * 5;
constexpr size_t OFF_AN  = OFF_HC + (size_t)BT;
constexpr size_t OFF_SC  = OFF_AN + (size_t)BT;
constexpr size_t OFF_OT  = OFF_SC + (size_t)BT;
constexpr size_t OFF_LP  = OFF_OT + (size_t)BT;

typedef _Float16 half8 __attribute__((ext_vector_type(8)));
typedef _Float16 half4 __attribute__((ext_vector_type(4)));
typedef _Float16 half2_t __attribute__((ext_vector_type(2)));
typedef float f32x4 __attribute__((ext_vector_type(4)));

__device__ __forceinline__ float clip01(float x) { return fminf(fmaxf(x, 0.f), 1.f); }

// tanh-GELU as sigmoid: x*sigmoid(1.5957691*(x+0.044715x^3)), 7 VALU ops.
__device__ __forceinline__ float gelu_tanh(float x) {
  float x2 = x * x;
  float q = x * __builtin_fmaf(-0.10294444f, x2, -2.3022077f);
  float e = __builtin_amdgcn_exp2f(q);
  return x * __builtin_amdgcn_rcpf(1.0f + e);
}

// feature math for (b,t) — bit-identical to round-4 featurize_k
__device__ __forceinline__ void compute_feats(
    const float* __restrict__ tr, const float* __restrict__ iv,
    const float* __restrict__ mk, const float* __restrict__ om, int t,
    float* __restrict__ f /*10*/, float* anv_out, float* scv_out, float* otv_out) {
  float m  = mk[t];
  float m1 = (t >= 1) ? mk[t - 1] : 0.f;
  float m2 = (t >= 2) ? mk[t - 2] : 0.f;
  float pm01 = (m > 0.5f && m1 > 0.5f) ? 1.f : 0.f;
  float pm12 = (m1 > 0.5f && m2 > 0.5f) ? 1.f : 0.f;
  float x0x = tr[2 * t] * m, x0y = tr[2 * t + 1] * m;
  float x1x = 0.f, x1y = 0.f, x2x = 0.f, x2y = 0.f;
  if (t >= 1) { x1x = tr[2 * (t - 1)] * m1; x1y = tr[2 * (t - 1) + 1] * m1; }
  if (t >= 2) { x2x = tr[2 * (t - 2)] * m2; x2y = tr[2 * (t - 2) + 1] * m2; }
  float dt0 = fmaxf(iv[t], 1e-3f);
  float dt1 = (t >= 1) ? fmaxf(iv[t - 1], 1e-3f) : 1e-3f;
  float vx = 0.f, vy = 0.f, v1x = 0.f, v1y = 0.f;
  if (t >= 1) { vx = (x0x - x1x) * pm01 / dt0 * m; vy = (x0y - x1y) * pm01 / dt0 * m; }
  if (t >= 2) { v1x = (x1x - x2x) * pm12 / dt1 * m1; v1y = (x1y - x2y) * pm12 / dt1 * m1; }
  float ax = 0.f, ay = 0.f;
  if (t >= 1) { ax = (vx - v1x) * pm01 / dt0 * m; ay = (vy - v1y) * pm01 / dt0 * m; }
  float s2 = vx * vx + vy * vy;
  float speed = (s2 > 0.f ? sqrtf(s2) : 0.f) * m;
  float s21 = v1x * v1x + v1y * v1y;
  float speed1 = (s21 > 0.f ? sqrtf(s21) : 0.f) * m1;
  float scv = (t >= 1) ? fabsf((speed - speed1) * pm01) * m : 0.f;
  float a2 = ax * ax + ay * ay;
  float anv = (a2 > 0.f ? sqrtf(a2) : 0.f) * m;
  float hcv = 0.f;
  if (t >= 1) {
    bool z0 = (vx == 0.f && vy == 0.f);
    bool z1 = (v1x == 0.f && v1y == 0.f);
    float yy, xx;
    if (z1)      { yy = vy;  xx = vx; }
    else if (z0) { yy = v1y; xx = v1x; }
    else { yy = vy * v1x - vx * v1y; xx = vx * v1x + vy * v1y; }
    hcv = fabsf(atan2f(yy, xx)) * pm01 * m;
  }
  float obs = om[t] * m;
  float otv = (t >= 1) ? fminf(fabsf(om[t] - om[t - 1]) * pm01 * m, 1.f) : 0.f;
  float itf = iv[t] * m;
  f[0] = x0x; f[1] = x0y; f[2] = vx; f[3] = vy; f[4] = ax; f[5] = ay;
  f[6] = speed; f[7] = hcv; f[8] = itf; f[9] = obs;
  *anv_out = anv; *scv_out = scv; *otv_out = otv;
}

// ---------------- Kernel A: featurize -> f16 interleaved feats + metrics + repack ----------------
__global__ __launch_bounds__(256)
void featurize_k(const float* __restrict__ traj, const float* __restrict__ intervals,
                 const float* __restrict__ amask, const float* __restrict__ omask,
                 const float* __restrict__ w1g, const float* __restrict__ w2g,
                 _Float16* __restrict__ feats16, float* __restrict__ hc,
                 float* __restrict__ an, float* __restrict__ sc, float* __restrict__ ot,
                 half8* __restrict__ w1f, half8* __restrict__ w2f) {
  int idx = blockIdx.x * 256 + threadIdx.x;
  int b = idx >> 12;
  int t = idx & (T_ - 1);
  float f[10], anv, scv, otv;
  compute_feats(traj + (size_t)b * T_ * 2, intervals + (size_t)b * T_,
                amask + (size_t)b * T_, omask + (size_t)b * T_, t, f, &anv, &scv, &otv);
  // interleaved [t][c] layout, pre-scaled 2^-6 (RNE)
  half2_t* fd = reinterpret_cast<half2_t*>(feats16) + (size_t)idx * 5;
#pragma unroll
  for (int q = 0; q < 5; ++q) {
    half2_t pk;
    pk[0] = (_Float16)(f[2 * q] * 0.015625f);
    pk[1] = (_Float16)(f[2 * q + 1] * 0.015625f);
    fd[q] = pk;
  }
  hc[idx] = f[7]; an[idx] = anv; sc[idx] = scv; ot[idx] = otv;

  // fused repack: first 12 blocks also build MFMA weight fragments
  if (blockIdx.x < 12) {
    int gid = blockIdx.x * 256 + threadIdx.x;
    if (gid < 48 * 64) {
      int fid = gid >> 6, lane = gid & 63;
      int qd = lane >> 4, ln = lane & 15;
      half8 v;
      if (fid < 8) {
        int m = fid >> 1, kk = fid & 1;
        int o = m * 16 + ln;
#pragma unroll
        for (int j = 0; j < 8; ++j) {
          int ck = kk * 32 + qd * 8 + j;
          float val = 0.f;
          if (ck < 50) { int k_ = ck / 10, c = ck - 10 * k_; val = w1g[o * 50 + c * 5 + k_]; }
          v[j] = (_Float16)val;
        }
        w1f[fid * 64 + lane] = v;
      } else {
        int f2 = fid - 8;
        int k = f2 >> 3, kk = (f2 >> 2) & 1, m = f2 & 3;
        int o = m * 16 + ln;
#pragma unroll
        for (int j = 0; j < 8; ++j) {
          int ic = kk * 32 + qd * 8 + j;
          v[j] = (_Float16)w2g[o * 320 + ic * 5 + k];
        }
        w2f[f2 * 64 + lane] = v;
      }
    }
  }
}

// ---------------- Kernel B: MFMA conv stack ----------------
// LDS: sF16 staging buffer ALIASES the head of sH1 — sF16's last read (im2col)
// and sH1's first write (phase 1) are separated by the same __syncthreads, so the
// overlap is race-free and output is bit-identical to the non-aliased version.
// This drops LDS 43520 -> 40960 B: exactly 4 blocks/CU (4 x 40960 = 160 KiB).
__global__ __launch_bounds__(512, 4)
void conv_k(const _Float16* __restrict__ feats16, const half8* __restrict__ w1f,
            const float* __restrict__ b1g, const half8* __restrict__ w2f,
            const float* __restrict__ b2g, const float* __restrict__ w3g,
            const float* __restrict__ b3g, const float* __restrict__ amask,
            float* __restrict__ lp) {
  __shared__ _Float16 sIm[144 * 72];
  __shared__ _Float16 sH1[132 * 72];
  __shared__ float sPart[2][128];
  _Float16* sF16 = sH1;  // alias: staging tile [136][10] lives in sH1[0..1360) until im2col barrier
  int tid = threadIdx.x;
  int lane = tid & 63, w = tid >> 6;
  int qd = lane >> 4, ln = lane & 15;
  int tile = blockIdx.x, b = blockIdx.y;
  int t0 = tile * TTILE;

  // stage f16 feats (680 dwords), already scaled; OOB t -> 0
  const unsigned* gfd = reinterpret_cast<const unsigned*>(feats16 + (size_t)b * T_ * 10);
  unsigned* sFd = reinterpret_cast<unsigned*>(sF16);
  int dbase = (t0 - 4) * 5;
  for (int s = tid; s < 680; s += 512) {
    int gi = dbase + s;
    sFd[s] = (gi >= 0 && gi < T_ * 5) ? gfd[gi] : 0u;
  }
  // zero K-pad cols [50,64) of im2col for ALL rows
  for (int s = tid; s < 144 * 7; s += 512) {
    int jt = s / 7, d = s - jt * 7;
    *reinterpret_cast<unsigned*>(&sIm[jt * 72 + 50 + 2 * d]) = 0u;
  }
  __syncthreads();
  // im2col: pure dword LDS->LDS copies (no converts)
  unsigned* sId = reinterpret_cast<unsigned*>(sIm);
  for (int s = tid; s < 660; s += 512) {
    int jt = s / 5, k = s - jt * 5;
    const unsigned* src = sFd + (jt + k) * 5;
    unsigned* dst = sId + jt * 36 + k * 5;
#pragma unroll
    for (int q = 0; q < 5; ++q) dst[q] = src[q];
  }
  __syncthreads();  // after this barrier sF16 is dead; sH1 writes may begin

  half8 a1[4][2];
#pragma unroll
  for (int m = 0; m < 4; ++m)
#pragma unroll
    for (int kk = 0; kk < 2; ++kk) a1[m][kk] = w1f[(m * 2 + kk) * 64 + lane];

  for (int n0 = w; n0 < 9; n0 += 8) {
    int jt = n0 * 16 + ln;
    half8 bf0 = *reinterpret_cast<const half8*>(&sIm[jt * 72 + qd * 8]);
    half8 bf1 = *reinterpret_cast<const half8*>(&sIm[jt * 72 + 32 + qd * 8]);
#pragma unroll
    for (int m = 0; m < 4; ++m) {
      f32x4 acc;
      f32x4 bv = *reinterpret_cast<const f32x4*>(&b1g[m * 16 + qd * 4]);
#pragma unroll
      for (int r = 0; r < 4; ++r) acc[r] = bv[r] * 0.015625f;
      acc = __builtin_amdgcn_mfma_f32_16x16x32_f16(a1[m][0], bf0, acc, 0, 0, 0);
      acc = __builtin_amdgcn_mfma_f32_16x16x32_f16(a1[m][1], bf1, acc, 0, 0, 0);
      if (jt < 132) {
        int t = t0 - 2 + jt;
        bool inr = (t >= 0 && t < T_);
        half4 hv;
#pragma unroll
        for (int r = 0; r < 4; ++r) {
          float h = inr ? gelu_tanh(acc[r] * 64.f) * 0.0625f : 0.f;
          hv[r] = (_Float16)h;
        }
        *reinterpret_cast<half4*>(&sH1[jt * 72 + m * 16 + qd * 4]) = hv;
      }
    }
  }
  __syncthreads();

  int p = w & 1, nq = w >> 1;
  f32x4 acc2[2][2];
#pragma unroll
  for (int dm = 0; dm < 2; ++dm) {
    f32x4 bv = *reinterpret_cast<const f32x4*>(&b2g[(2 * p + dm) * 16 + qd * 4]);
#pragma unroll
    for (int dn = 0; dn < 2; ++dn)
#pragma unroll
      for (int r = 0; r < 4; ++r) acc2[dm][dn][r] = bv[r] * 0.0625f;
  }
#pragma unroll
  for (int k = 0; k < 5; ++k) {
#pragma unroll
    for (int kk = 0; kk < 2; ++kk) {
      half8 A0 = w2f[((k * 2 + kk) * 4 + 2 * p + 0) * 64 + lane];
      half8 A1 = w2f[((k * 2 + kk) * 4 + 2 * p + 1) * 64 + lane];
      half8 B0 = *reinterpret_cast<const half8*>(
          &sH1[((2 * nq + 0) * 16 + ln + k) * 72 + kk * 32 + qd * 8]);
      half8 B1 = *reinterpret_cast<const half8*>(
          &sH1[((2 * nq + 1) * 16 + ln + k) * 72 + kk * 32 + qd * 8]);
      acc2[0][0] = __builtin_amdgcn_mfma_f32_16x16x32_f16(A0, B0, acc2[0][0], 0, 0, 0);
      acc2[0][1] = __builtin_amdgcn_mfma_f32_16x16x32_f16(A0, B1, acc2[0][1], 0, 0, 0);
      acc2[1][0] = __builtin_amdgcn_mfma_f32_16x16x32_f16(A1, B0, acc2[1][0], 0, 0, 0);
      acc2[1][1] = __builtin_amdgcn_mfma_f32_16x16x32_f16(A1, B1, acc2[1][1], 0, 0, 0);
    }
  }
  f32x4 w3a = *reinterpret_cast<const f32x4*>(&w3g[(2 * p + 0) * 16 + qd * 4]);
  f32x4 w3b = *reinterpret_cast<const f32x4*>(&w3g[(2 * p + 1) * 16 + qd * 4]);
#pragma unroll
  for (int dn = 0; dn < 2; ++dn) {
    float s = 0.f;
#pragma unroll
    for (int r = 0; r < 4; ++r) s += w3a[r] * gelu_tanh(acc2[0][dn][r] * 16.f);
#pragma unroll
    for (int r = 0; r < 4; ++r) s += w3b[r] * gelu_tanh(acc2[1][dn][r] * 16.f);
    s += __shfl_xor(s, 16);
    s += __shfl_xor(s, 32);
    if (lane < 16) sPart[p][(2 * nq + dn) * 16 + lane] = s;
  }
  __syncthreads();
  if (tid < 128) {
    int t = t0 + tid;
    float logit = sPart[0][tid] + sPart[1][tid] + b3g[0];
    float m = amask[(size_t)b * T_ + t];
    float e = __builtin_amdgcn_exp2f(logit * -1.4426950408889634f);
    lp[(size_t)b * T_ + t] = m * __builtin_amdgcn_rcpf(1.f + e);
  }
}

// ---------------- low-barrier radix-select machinery ----------------
__device__ __forceinline__ void scan4096(unsigned (*hist)[4096], int j, int tid, int lane,
                                         int wv, unsigned (*sW)[16], uint4& v,
                                         unsigned& ps, unsigned& incl) {
  v = *reinterpret_cast<uint4*>(&hist[j][tid * 4]);
  uint4 zz = {0u, 0u, 0u, 0u};
  *reinterpret_cast<uint4*>(&hist[j][tid * 4]) = zz;
  ps = v.x + v.y + v.z + v.w;
  incl = ps;
#pragma unroll
  for (int off = 1; off < 64; off <<= 1) {
    unsigned tv = __shfl_up(incl, off, 64);
    if (lane >= off) incl += tv;
  }
  if (lane == 63) sW[j][wv] = incl;
}
__device__ __forceinline__ void resolve4096(const unsigned (*sW)[16], int j, int tid, int wv,
                                            uint4 v, unsigned ps, unsigned incl, unsigned k,
                                            unsigned* selb, unsigned* selk) {
  unsigned woff = 0;
  for (int i = 0; i < wv; ++i) woff += sW[j][i];
  incl += woff;
  unsigned excl = incl - ps;
  if (excl <= k && k < incl) {
    unsigned vv[4] = {v.x, v.y, v.z, v.w};
    unsigned run = excl;
    int c = 0;
#pragma unroll
    for (; c < 3; ++c) {
      if (run + vv[c] > k) break;
      run += vv[c];
    }
    *selb = (unsigned)(tid * 4 + c);
    *selk = k - run;
  }
}
__device__ __forceinline__ void scan256(unsigned (*hist)[4096], int j, int tid, int lane,
                                        int wv, unsigned (*sW)[16], unsigned& v,
                                        unsigned& incl) {
  v = (tid < 256) ? hist[j][tid] : 0u;
  if (tid < 256) hist[j][tid] = 0u;
  incl = v;
#pragma unroll
  for (int off = 1; off < 64; off <<= 1) {
    unsigned tv = __shfl_up(incl, off, 64);
    if (lane >= off) incl += tv;
  }
  if (lane == 63) sW[j][wv] = incl;
}
__device__ __forceinline__ void resolve256(const unsigned (*sW)[16], int j, int tid, int wv,
                                           unsigned v, unsigned incl, unsigned k,
                                           unsigned* selb) {
  unsigned woff = 0;
  for (int i = 0; i < wv; ++i) woff += sW[j][i];
  incl += woff;
  unsigned excl = incl - v;
  if (excl <= k && k < incl) *selb = (unsigned)tid;
}

// ---------------- Kernel C: selects + smooth + normalize + FINAL BLEND (per row) ----------------
__global__ __launch_bounds__(1024)
void ruleselect_k(const float* __restrict__ hc, const float* __restrict__ an,
                  const float* __restrict__ sc, const float* __restrict__ ot,
                  const float* __restrict__ amask, const float* __restrict__ lp,
                  float* __restrict__ out) {
  __shared__ unsigned hist3[3][4096];
  __shared__ float vbuf[4096];
  __shared__ unsigned selB[2][4];
  __shared__ unsigned selK[2][4];
  __shared__ unsigned sW3[3][16];
  __shared__ float sM3[3][16];
  __shared__ int iCnt[16];
  int b = blockIdx.x, tid = threadIdx.x;
  int lane = tid & 63, wv = tid >> 6;
  const float* mk = amask + (size_t)b * T_;
  const float* h0 = hc + (size_t)b * T_;
  const float* a0 = an + (size_t)b * T_;
  const float* s0 = sc + (size_t)b * T_;
  const float* o0 = ot + (size_t)b * T_;

  float mv0[4], mv1[4], mv2[4], otv[4], mreg[4];
  int cnt = 0;
#pragma unroll
  for (int r = 0; r < 4; ++r) {
    int t = tid + 1024 * r;
    mv0[r] = h0[t]; mv1[r] = a0[t]; mv2[r] = s0[t]; otv[r] = o0[t];
    mreg[r] = mk[t];
    cnt += (mreg[r] > 0.5f);
  }
#pragma unroll
  for (int off = 32; off; off >>= 1) cnt += __shfl_xor(cnt, off);
  if (lane == 0) iCnt[wv] = cnt;
  {
    unsigned* hflat = &hist3[0][0];
    for (int i = tid; i < 3 * 4096; i += 1024) hflat[i] = 0u;
  }
  unsigned u0[4], u1[4], u2[4];
  float mxa = 0.f, mxb = 0.f, mxc = 0.f;
#pragma unroll
  for (int r = 0; r < 4; ++r) {
    bool valid = mreg[r] > 0.5f;
    unsigned b0 = __float_as_uint(mv0[r]); if ((int)b0 < 0) b0 = 0u;
    unsigned b1 = __float_as_uint(mv1[r]); if ((int)b1 < 0) b1 = 0u;
    unsigned b2 = __float_as_uint(mv2[r]); if ((int)b2 < 0) b2 = 0u;
    u0[r] = valid ? b0 : NOINS;
    u1[r] = valid ? b1 : NOINS;
    u2[r] = valid ? b2 : NOINS;
    if (valid) {
      mxa = fmaxf(mxa, fabsf(mv0[r]));
      mxb = fmaxf(mxb, fabsf(mv1[r]));
      mxc = fmaxf(mxc, fabsf(mv2[r]));
    }
  }
#pragma unroll
  for (int off = 32; off; off >>= 1) {
    mxa = fmaxf(mxa, __shfl_xor(mxa, off));
    mxb = fmaxf(mxb, __shfl_xor(mxb, off));
    mxc = fmaxf(mxc, __shfl_xor(mxc, off));
  }
  if (lane == 0) { sM3[0][wv] = mxa; sM3[1][wv] = mxb; sM3[2][wv] = mxc; }
  __syncthreads();  // B1
  int n = 0;
#pragma unroll
  for (int i = 0; i < 16; ++i) n += iCnt[i];
  int cidx = (int)ceilf((float)n * 0.95f);
  if (cidx < 1) cidx = 1;
  unsigned kidx = (unsigned)(cidx - 1);
  if (kidx > (unsigned)(T_ - 1)) kidx = T_ - 1;
  float mx3a = sM3[0][0], mx3b = sM3[1][0], mx3c = sM3[2][0];
#pragma unroll
  for (int i = 1; i < 16; ++i) {
    mx3a = fmaxf(mx3a, sM3[0][i]);
    mx3b = fmaxf(mx3b, sM3[1][i]);
    mx3c = fmaxf(mx3c, sM3[2][i]);
  }

#pragma unroll
  for (int r = 0; r < 4; ++r) {
    if (u0[r] != NOINS) atomicAdd(&hist3[0][u0[r] >> 20], 1u);
    if (u1[r] != NOINS) atomicAdd(&hist3[1][u1[r] >> 20], 1u);
    if (u2[r] != NOINS) atomicAdd(&hist3[2][u2[r] >> 20], 1u);
  }
  __syncthreads();  // B2
  uint4 v40, v41, v42; unsigned ps0, ps1, ps2, in0, in1, in2;
  scan4096(hist3, 0, tid, lane, wv, sW3, v40, ps0, in0);
  scan4096(hist3, 1, tid, lane, wv, sW3, v41, ps1, in1);
  scan4096(hist3, 2, tid, lane, wv, sW3, v42, ps2, in2);
  __syncthreads();  // B3
  resolve4096(sW3, 0, tid, wv, v40, ps0, in0, kidx, &selB[1][0], &selK[1][0]);
  resolve4096(sW3, 1, tid, wv, v41, ps1, in1, kidx, &selB[1][1], &selK[1][1]);
  resolve4096(sW3, 2, tid, wv, v42, ps2, in2, kidx, &selB[1][2], &selK[1][2]);
  __syncthreads();  // B4
  unsigned p1_0 = selB[1][0], p1_1 = selB[1][1], p1_2 = selB[1][2];
  unsigned k2_0 = selK[1][0], k2_1 = selK[1][1], k2_2 = selK[1][2];
#pragma unroll
  for (int r = 0; r < 4; ++r) {
    if (u0[r] != NOINS && (u0[r] >> 20) == p1_0) atomicAdd(&hist3[0][(u0[r] >> 8) & 0xFFFu], 1u);
    if (u1[r] != NOINS && (u1[r] >> 20) == p1_1) atomicAdd(&hist3[1][(u1[r] >> 8) & 0xFFFu], 1u);
    if (u2[r] != NOINS && (u2[r] >> 20) == p1_2) atomicAdd(&hist3[2][(u2[r] >> 8) & 0xFFFu], 1u);
  }
  __syncthreads();  // B5
  scan4096(hist3, 0, tid, lane, wv, sW3, v40, ps0, in0);
  scan4096(hist3, 1, tid, lane, wv, sW3, v41, ps1, in1);
  scan4096(hist3, 2, tid, lane, wv, sW3, v42, ps2, in2);
  __syncthreads();  // B6
  resolve4096(sW3, 0, tid, wv, v40, ps0, in0, k2_0, &selB[0][0], &selK[0][0]);
  resolve4096(sW3, 1, tid, wv, v41, ps1, in1, k2_1, &selB[0][1], &selK[0][1]);
  resolve4096(sW3, 2, tid, wv, v42, ps2, in2, k2_2, &selB[0][2], &selK[0][2]);
  __syncthreads();  // B7
  unsigned p2_0 = selB[0][0], p2_1 = selB[0][1], p2_2 = selB[0][2];
  unsigned k3_0 = selK[0][0], k3_1 = selK[0][1], k3_2 = selK[0][2];
  unsigned pf0 = (p1_0 << 12) | p2_0, pf1 = (p1_1 << 12) | p2_1, pf2 = (p1_2 << 12) | p2_2;
#pragma unroll
  for (int r = 0; r < 4; ++r) {
    if (u0[r] != NOINS && (u0[r] >> 8) == pf0) atomicAdd(&hist3[0][u0[r] & 0xFFu], 1u);
    if (u1[r] != NOINS && (u1[r] >> 8) == pf1) atomicAdd(&hist3[1][u1[r] & 0xFFu], 1u);
    if (u2[r] != NOINS && (u2[r] >> 8) == pf2) atomicAdd(&hist3[2][u2[r] & 0xFFu], 1u);
  }
  __syncthreads();  // B8
  unsigned s80, s81, s82;
  scan256(hist3, 0, tid, lane, wv, sW3, s80, in0);
  scan256(hist3, 1, tid, lane, wv, sW3, s81, in1);
  scan256(hist3, 2, tid, lane, wv, sW3, s82, in2);
  __syncthreads();  // B9
  resolve256(sW3, 0, tid, wv, s80, in0, k3_0, &selB[1][0]);
  resolve256(sW3, 1, tid, wv, s81, in1, k3_1, &selB[1][1]);
  resolve256(sW3, 2, tid, wv, s82, in2, k3_2, &selB[1][2]);
  __syncthreads();  // B10
  float kth0 = fabsf(__uint_as_float((p1_0 << 20) | (p2_0 << 8) | selB[1][0]));
  float kth1 = fabsf(__uint_as_float((p1_1 << 20) | (p2_1 << 8) | selB[1][1]));
  float kth2 = fabsf(__uint_as_float((p1_2 << 20) | (p2_2 << 8) | selB[1][2]));
  float sc0 = fmaxf((kth0 < 1e-6f) ? mx3a : kth0, 1e-6f);
  float sc1 = fmaxf((kth1 < 1e-6f) ? mx3b : kth1, 1e-6f);
  float sc2 = fmaxf((kth2 < 1e-6f) ? mx3c : kth2, 1e-6f);

#pragma unroll
  for (int r = 0; r < 4; ++r) {
    int t = tid + 1024 * r;
    float v = 0.f;
    if (n > 0) {
      v = 0.35f * (mv0[r] / sc0) + 0.30f * (mv1[r] / sc1)
        + 0.25f * (mv2[r] / sc2) + 0.10f * otv[r];
    }
    vbuf[t] = v;
  }
  __syncthreads();  // B11
  float sm[4];
#pragma unroll
  for (int r = 0; r < 4; ++r) {
    int t = tid + 1024 * r;
    float s = 0.f;
#pragma unroll
    for (int d = -2; d <= 2; ++d) {
      int tt = t + d;
      if (tt >= 0 && tt < T_) s += vbuf[tt];
    }
    sm[r] = s * 0.2f * mreg[r];
  }
  // ---- 4th select (hist3[0], slot 3) ----
  unsigned uu[4];
  float mxs = 0.f;
#pragma unroll
  for (int r = 0; r < 4; ++r) {
    bool valid = mreg[r] > 0.5f;
    unsigned ub = __float_as_uint(sm[r]); if ((int)ub < 0) ub = 0u;
    uu[r] = valid ? ub : NOINS;
    if (valid) mxs = fmaxf(mxs, fabsf(sm[r]));
  }
#pragma unroll
  for (int off = 32; off; off >>= 1) mxs = fmaxf(mxs, __shfl_xor(mxs, off));
  if (lane == 0) sM3[0][wv] = mxs;
#pragma unroll
  for (int r = 0; r < 4; ++r)
    if (uu[r] != NOINS) atomicAdd(&hist3[0][uu[r] >> 20], 1u);
  __syncthreads();  // B12 — smooth reads of vbuf done; repurpose vbuf for lp
  const float* lprow = lp + (size_t)b * T_;
#pragma unroll
  for (int r = 0; r < 4; ++r) {
    int t = tid + 1024 * r;
    vbuf[t] = lprow[t];
  }
  float mx4 = sM3[0][0];
#pragma unroll
  for (int i = 1; i < 16; ++i) mx4 = fmaxf(mx4, sM3[0][i]);
  scan4096(hist3, 0, tid, lane, wv, sW3, v40, ps0, in0);
  __syncthreads();  // B13
  resolve4096(sW3, 0, tid, wv, v40, ps0, in0, kidx, &selB[1][3], &selK[1][3]);
  __syncthreads();  // B14
  unsigned q1 = selB[1][3], kq2 = selK[1][3];
#pragma unroll
  for (int r = 0; r < 4; ++r)
    if (uu[r] != NOINS && (uu[r] >> 20) == q1) atomicAdd(&hist3[0][(uu[r] >> 8) & 0xFFFu], 1u);
  __syncthreads();  // B15
  scan4096(hist3, 0, tid, lane, wv, sW3, v40, ps0, in0);
  __syncthreads();  // B16
  resolve4096(sW3, 0, tid, wv, v40, ps0, in0, kq2, &selB[0][3], &selK[0][3]);
  __syncthreads();  // B17
  unsigned q2 = selB[0][3], kq3 = selK[0][3];
  unsigned qf = (q1 << 12) | q2;
#pragma unroll
  for (int r = 0; r < 4; ++r)
    if (uu[r] != NOINS && (uu[r] >> 8) == qf) atomicAdd(&hist3[0][uu[r] & 0xFFu], 1u);
  __syncthreads();  // B18
  scan256(hist3, 0, tid, lane, wv, sW3, s80, in0);
  __syncthreads();  // B19
  resolve256(sW3, 0, tid, wv, s80, in0, kq3, &selB[1][3]);
  __syncthreads();  // B20
  float kth4 = fabsf(__uint_as_float((q1 << 20) | (q2 << 8) | selB[1][3]));
  float scale4 = fmaxf((kth4 < 1e-6f) ? mx4 : kth4, 1e-6f);
  // ---- final blend: rule + smoothed learned -> out ----
  float* orow = out + (size_t)b * T_;
#pragma unroll
  for (int r = 0; r < 4; ++r) {
    int t = tid + 1024 * r;
    float rv = (n > 0) ? sm[r] / scale4 : 0.f;
    rv = clip01(rv) * mreg[r];
    float ssum = 0.f;
#pragma unroll
    for (int d = -2; d <= 2; ++d) {
      int tt = t + d;
      if (tt >= 0 && tt < T_) ssum += vbuf[tt];
    }
    float learned = clip01(ssum * 0.2f * mreg[r]);
    orow[t] = clip01(0.5f * rv + 0.5f * learned) * mreg[r];
  }
}

}  // namespace

extern "C" void kernel_launch(void* const* d_in, const int* in_sizes, int n_in,
                              void* d_out, int out_size, void* d_ws, size_t ws_size,
                              hipStream_t stream) {
  const float* traj      = (const float*)d_in[0];
  const float* intervals = (const float*)d_in[1];
  const float* amask     = (const float*)d_in[2];
  const float* omask     = (const float*)d_in[3];
  const float* w1        = (const float*)d_in[4];
  const float* b1        = (const float*)d_in[5];
  const float* w2        = (const float*)d_in[6];
  const float* b2        = (const float*)d_in[7];
  const float* w3        = (const float*)d_in[8];
  const float* b3        = (const float*)d_in[9];
  float* out = (float*)d_out;
  float* ws = (float*)d_ws;

  _Float16* feats16 = (_Float16*)(ws + OFF_F16);
  float* hc = ws + OFF_HC;
  float* an = ws + OFF_AN;
  float* sc = ws + OFF_SC;
  float* ot = ws + OFF_OT;
  float* lp = ws + OFF_LP;
  half8* w1f = (half8*)(ws + OFF_W1F);
  half8* w2f = (half8*)(ws + OFF_W2F);

  featurize_k<<<BT / 256, 256, 0, stream>>>(traj, intervals, amask, omask, w1, w2,
                                            feats16, hc, an, sc, ot, w1f, w2f);
  conv_k<<<dim3(T_ / TTILE, B_), 512, 0, stream>>>(feats16, w1f, b1, w2f, b2, w3, b3,
                                                   amask, lp);
  ruleselect_k<<<B_, 1024, 0, stream>>>(hc, an, sc, ot, amask, lp, out);
}

// Round 12
// 150.637 us; speedup vs baseline: 1.8546x; 1.0468x over previous
//
#include <hip/hip_runtime.h>

namespace {

constexpr int B_ = 128;
constexpr int T_ = 4096;
constexpr int BT = B_ * T_;
constexpr int CT = 64;  // conv t-tile (4-wave blocks, 7 blocks/CU)
constexpr unsigned NOINS = 0xFFFFFFFFu;  // "do not insert" sentinel (invalid/masked lane)

// workspace layout (float offsets)
constexpr size_t OFF_W1F = 0;                     // 8 frags * 64 * 8 f16
constexpr size_t OFF_W2F = 2048;                  // 40 frags * 64 * 8 f16
constexpr size_t OFF_F16 = 16384;                 // feats16: B*T*10 halfs = B*T*5 dwords
constexpr size_t OFF_HC  = OFF_F16 + (size_t)BT * 5;
constexpr size_t OFF_AN  = OFF_HC + (size_t)BT;
constexpr size_t OFF_SC  = OFF_AN + (size_t)BT;
constexpr size_t OFF_OT  = OFF_SC + (size_t)BT;
constexpr size_t OFF_LP  = OFF_OT + (size_t)BT;

typedef _Float16 half8 __attribute__((ext_vector_type(8)));
typedef _Float16 half4 __attribute__((ext_vector_type(4)));
typedef _Float16 half2_t __attribute__((ext_vector_type(2)));
typedef float f32x4 __attribute__((ext_vector_type(4)));

__device__ __forceinline__ float clip01(float x) { return fminf(fmaxf(x, 0.f), 1.f); }

// tanh-GELU as sigmoid: x*sigmoid(1.5957691*(x+0.044715x^3)), 7 VALU ops.
__device__ __forceinline__ float gelu_tanh(float x) {
  float x2 = x * x;
  float q = x * __builtin_fmaf(-0.10294444f, x2, -2.3022077f);
  float e = __builtin_amdgcn_exp2f(q);
  return x * __builtin_amdgcn_rcpf(1.0f + e);
}

// feature math for (b,t) — bit-identical to round-4 featurize_k
__device__ __forceinline__ void compute_feats(
    const float* __restrict__ tr, const float* __restrict__ iv,
    const float* __restrict__ mk, const float* __restrict__ om, int t,
    float* __restrict__ f /*10*/, float* anv_out, float* scv_out, float* otv_out) {
  float m  = mk[t];
  float m1 = (t >= 1) ? mk[t - 1] : 0.f;
  float m2 = (t >= 2) ? mk[t - 2] : 0.f;
  float pm01 = (m > 0.5f && m1 > 0.5f) ? 1.f : 0.f;
  float pm12 = (m1 > 0.5f && m2 > 0.5f) ? 1.f : 0.f;
  float x0x = tr[2 * t] * m, x0y = tr[2 * t + 1] * m;
  float x1x = 0.f, x1y = 0.f, x2x = 0.f, x2y = 0.f;
  if (t >= 1) { x1x = tr[2 * (t - 1)] * m1; x1y = tr[2 * (t - 1) + 1] * m1; }
  if (t >= 2) { x2x = tr[2 * (t - 2)] * m2; x2y = tr[2 * (t - 2) + 1] * m2; }
  float dt0 = fmaxf(iv[t], 1e-3f);
  float dt1 = (t >= 1) ? fmaxf(iv[t - 1], 1e-3f) : 1e-3f;
  float vx = 0.f, vy = 0.f, v1x = 0.f, v1y = 0.f;
  if (t >= 1) { vx = (x0x - x1x) * pm01 / dt0 * m; vy = (x0y - x1y) * pm01 / dt0 * m; }
  if (t >= 2) { v1x = (x1x - x2x) * pm12 / dt1 * m1; v1y = (x1y - x2y) * pm12 / dt1 * m1; }
  float ax = 0.f, ay = 0.f;
  if (t >= 1) { ax = (vx - v1x) * pm01 / dt0 * m; ay = (vy - v1y) * pm01 / dt0 * m; }
  float s2 = vx * vx + vy * vy;
  float speed = (s2 > 0.f ? sqrtf(s2) : 0.f) * m;
  float s21 = v1x * v1x + v1y * v1y;
  float speed1 = (s21 > 0.f ? sqrtf(s21) : 0.f) * m1;
  float scv = (t >= 1) ? fabsf((speed - speed1) * pm01) * m : 0.f;
  float a2 = ax * ax + ay * ay;
  float anv = (a2 > 0.f ? sqrtf(a2) : 0.f) * m;
  float hcv = 0.f;
  if (t >= 1) {
    bool z0 = (vx == 0.f && vy == 0.f);
    bool z1 = (v1x == 0.f && v1y == 0.f);
    float yy, xx;
    if (z1)      { yy = vy;  xx = vx; }
    else if (z0) { yy = v1y; xx = v1x; }
    else { yy = vy * v1x - vx * v1y; xx = vx * v1x + vy * v1y; }
    hcv = fabsf(atan2f(yy, xx)) * pm01 * m;
  }
  float obs = om[t] * m;
  float otv = (t >= 1) ? fminf(fabsf(om[t] - om[t - 1]) * pm01 * m, 1.f) : 0.f;
  float itf = iv[t] * m;
  f[0] = x0x; f[1] = x0y; f[2] = vx; f[3] = vy; f[4] = ax; f[5] = ay;
  f[6] = speed; f[7] = hcv; f[8] = itf; f[9] = obs;
  *anv_out = anv; *scv_out = scv; *otv_out = otv;
}

// ---------------- Kernel A: featurize -> f16 interleaved feats + metrics + repack ----------------
__global__ __launch_bounds__(256)
void featurize_k(const float* __restrict__ traj, const float* __restrict__ intervals,
                 const float* __restrict__ amask, const float* __restrict__ omask,
                 const float* __restrict__ w1g, const float* __restrict__ w2g,
                 _Float16* __restrict__ feats16, float* __restrict__ hc,
                 float* __restrict__ an, float* __restrict__ sc, float* __restrict__ ot,
                 half8* __restrict__ w1f, half8* __restrict__ w2f) {
  int idx = blockIdx.x * 256 + threadIdx.x;
  int b = idx >> 12;
  int t = idx & (T_ - 1);
  float f[10], anv, scv, otv;
  compute_feats(traj + (size_t)b * T_ * 2, intervals + (size_t)b * T_,
                amask + (size_t)b * T_, omask + (size_t)b * T_, t, f, &anv, &scv, &otv);
  // interleaved [t][c] layout, pre-scaled 2^-6 (RNE)
  half2_t* fd = reinterpret_cast<half2_t*>(feats16) + (size_t)idx * 5;
#pragma unroll
  for (int q = 0; q < 5; ++q) {
    half2_t pk;
    pk[0] = (_Float16)(f[2 * q] * 0.015625f);
    pk[1] = (_Float16)(f[2 * q + 1] * 0.015625f);
    fd[q] = pk;
  }
  hc[idx] = f[7]; an[idx] = anv; sc[idx] = scv; ot[idx] = otv;

  // fused repack: first 12 blocks also build MFMA weight fragments
  if (blockIdx.x < 12) {
    int gid = blockIdx.x * 256 + threadIdx.x;
    if (gid < 48 * 64) {
      int fid = gid >> 6, lane = gid & 63;
      int qd = lane >> 4, ln = lane & 15;
      half8 v;
      if (fid < 8) {
        int m = fid >> 1, kk = fid & 1;
        int o = m * 16 + ln;
#pragma unroll
        for (int j = 0; j < 8; ++j) {
          int ck = kk * 32 + qd * 8 + j;
          float val = 0.f;
          if (ck < 50) { int k_ = ck / 10, c = ck - 10 * k_; val = w1g[o * 50 + c * 5 + k_]; }
          v[j] = (_Float16)val;
        }
        w1f[fid * 64 + lane] = v;
      } else {
        int f2 = fid - 8;
        int k = f2 >> 3, kk = (f2 >> 2) & 1, m = f2 & 3;
        int o = m * 16 + ln;
#pragma unroll
        for (int j = 0; j < 8; ++j) {
          int ic = kk * 32 + qd * 8 + j;
          v[j] = (_Float16)w2g[o * 320 + ic * 5 + k];
        }
        w2f[f2 * 64 + lane] = v;
      }
    }
  }
}

// ---------------- Kernel B: MFMA conv stack, CT=64 / 4-wave blocks ----------------
// LDS = 21.8 KB -> 7 blocks/CU (28 waves). Barriers sync only 4 waves; 7 resident
// blocks interleave phases. Math identical to the CT=128 version (bit-exact).
__global__ __launch_bounds__(256)
void conv_k(const _Float16* __restrict__ feats16, const half8* __restrict__ w1f,
            const float* __restrict__ b1g, const half8* __restrict__ w2f,
            const float* __restrict__ b2g, const float* __restrict__ w3g,
            const float* __restrict__ b3g, const float* __restrict__ amask,
            float* __restrict__ lp) {
  __shared__ _Float16 sIm[80 * 72];    // 11520 B; rows jt in [0,80), cols ck + pad
  __shared__ _Float16 sH1[68 * 72];    // 9792 B;  h1^T rows jh in [0,68)
  __shared__ float sPart[2][64];
  _Float16* sF16 = sH1;  // staging tile (360 dwords) aliases sH1 until im2col barrier
  int tid = threadIdx.x;
  int lane = tid & 63, w = tid >> 6;   // w in [0,4)
  int qd = lane >> 4, ln = lane & 15;
  int tile = blockIdx.x, b = blockIdx.y;
  int t0 = tile * CT;

  // stage f16 feats (t0-4 .. t0+67 => 72 t's = 360 dwords), already scaled; OOB -> 0
  const unsigned* gfd = reinterpret_cast<const unsigned*>(feats16 + (size_t)b * T_ * 10);
  unsigned* sFd = reinterpret_cast<unsigned*>(sF16);
  int dbase = (t0 - 4) * 5;
  for (int s = tid; s < 360; s += 256) {
    int gi = dbase + s;
    sFd[s] = (gi >= 0 && gi < T_ * 5) ? gfd[gi] : 0u;
  }
  // zero K-pad cols [50,64) of im2col for ALL 80 rows
  for (int s = tid; s < 560; s += 256) {
    int jt = s / 7, d = s - jt * 7;
    *reinterpret_cast<unsigned*>(&sIm[jt * 72 + 50 + 2 * d]) = 0u;
  }
  __syncthreads();
  // im2col: pure dword LDS->LDS copies; rows jt in [0,68)
  unsigned* sId = reinterpret_cast<unsigned*>(sIm);
  for (int s = tid; s < 340; s += 256) {
    int jt = s / 5, k = s - jt * 5;
    const unsigned* src = sFd + (jt + k) * 5;
    unsigned* dst = sId + jt * 36 + k * 5;
#pragma unroll
    for (int q = 0; q < 5; ++q) dst[q] = src[q];
  }
  __syncthreads();  // sF16 dead; sH1 writes may begin

  // ---- phase 1: conv1; wave w owns output-channel group m = w for all 5 jt-tiles ----
  {
    int m = w;
    half8 a1k0 = w1f[(m * 2 + 0) * 64 + lane];
    half8 a1k1 = w1f[(m * 2 + 1) * 64 + lane];
    f32x4 bv = *reinterpret_cast<const f32x4*>(&b1g[m * 16 + qd * 4]);
    f32x4 b1s;
#pragma unroll
    for (int r = 0; r < 4; ++r) b1s[r] = bv[r] * 0.015625f;
#pragma unroll
    for (int tl = 0; tl < 5; ++tl) {
      int jt = tl * 16 + ln;  // up to 79; rows >= 68 discarded below
      half8 bf0 = *reinterpret_cast<const half8*>(&sIm[jt * 72 + qd * 8]);
      half8 bf1 = *reinterpret_cast<const half8*>(&sIm[jt * 72 + 32 + qd * 8]);
      f32x4 acc = b1s;
      acc = __builtin_amdgcn_mfma_f32_16x16x32_f16(a1k0, bf0, acc, 0, 0, 0);
      acc = __builtin_amdgcn_mfma_f32_16x16x32_f16(a1k1, bf1, acc, 0, 0, 0);
      if (jt < 68) {
        int t = t0 - 2 + jt;
        bool inr = (t >= 0 && t < T_);
        half4 hv;
#pragma unroll
        for (int r = 0; r < 4; ++r) {
          float h = inr ? gelu_tanh(acc[r] * 64.f) * 0.0625f : 0.f;
          hv[r] = (_Float16)h;
        }
        *reinterpret_cast<half4*>(&sH1[jt * 72 + m * 16 + qd * 4]) = hv;
      }
    }
  }
  __syncthreads();

  // ---- phase 2: conv2 as 5 shifted GEMMs; wave = (m-pair p, n-pair nq), nq in {0,1} ----
  int p = w & 1, nq = w >> 1;
  f32x4 acc2[2][2];
#pragma unroll
  for (int dm = 0; dm < 2; ++dm) {
    f32x4 bv = *reinterpret_cast<const f32x4*>(&b2g[(2 * p + dm) * 16 + qd * 4]);
#pragma unroll
    for (int dn = 0; dn < 2; ++dn)
#pragma unroll
      for (int r = 0; r < 4; ++r) acc2[dm][dn][r] = bv[r] * 0.0625f;
  }
#pragma unroll
  for (int k = 0; k < 5; ++k) {
#pragma unroll
    for (int kk = 0; kk < 2; ++kk) {
      half8 A0 = w2f[((k * 2 + kk) * 4 + 2 * p + 0) * 64 + lane];
      half8 A1 = w2f[((k * 2 + kk) * 4 + 2 * p + 1) * 64 + lane];
      half8 B0 = *reinterpret_cast<const half8*>(
          &sH1[((2 * nq + 0) * 16 + ln + k) * 72 + kk * 32 + qd * 8]);
      half8 B1 = *reinterpret_cast<const half8*>(
          &sH1[((2 * nq + 1) * 16 + ln + k) * 72 + kk * 32 + qd * 8]);
      acc2[0][0] = __builtin_amdgcn_mfma_f32_16x16x32_f16(A0, B0, acc2[0][0], 0, 0, 0);
      acc2[0][1] = __builtin_amdgcn_mfma_f32_16x16x32_f16(A0, B1, acc2[0][1], 0, 0, 0);
      acc2[1][0] = __builtin_amdgcn_mfma_f32_16x16x32_f16(A1, B0, acc2[1][0], 0, 0, 0);
      acc2[1][1] = __builtin_amdgcn_mfma_f32_16x16x32_f16(A1, B1, acc2[1][1], 0, 0, 0);
    }
  }
  f32x4 w3a = *reinterpret_cast<const f32x4*>(&w3g[(2 * p + 0) * 16 + qd * 4]);
  f32x4 w3b = *reinterpret_cast<const f32x4*>(&w3g[(2 * p + 1) * 16 + qd * 4]);
#pragma unroll
  for (int dn = 0; dn < 2; ++dn) {
    float s = 0.f;
#pragma unroll
    for (int r = 0; r < 4; ++r) s += w3a[r] * gelu_tanh(acc2[0][dn][r] * 16.f);
#pragma unroll
    for (int r = 0; r < 4; ++r) s += w3b[r] * gelu_tanh(acc2[1][dn][r] * 16.f);
    s += __shfl_xor(s, 16);
    s += __shfl_xor(s, 32);
    if (lane < 16) sPart[p][(2 * nq + dn) * 16 + lane] = s;
  }
  __syncthreads();
  if (tid < 64) {
    int t = t0 + tid;
    float logit = sPart[0][tid] + sPart[1][tid] + b3g[0];
    float m = amask[(size_t)b * T_ + t];
    float e = __builtin_amdgcn_exp2f(logit * -1.4426950408889634f);
    lp[(size_t)b * T_ + t] = m * __builtin_amdgcn_rcpf(1.f + e);
  }
}

// ---------------- low-barrier radix-select machinery ----------------
__device__ __forceinline__ void scan4096(unsigned (*hist)[4096], int j, int tid, int lane,
                                         int wv, unsigned (*sW)[16], uint4& v,
                                         unsigned& ps, unsigned& incl) {
  v = *reinterpret_cast<uint4*>(&hist[j][tid * 4]);
  uint4 zz = {0u, 0u, 0u, 0u};
  *reinterpret_cast<uint4*>(&hist[j][tid * 4]) = zz;
  ps = v.x + v.y + v.z + v.w;
  incl = ps;
#pragma unroll
  for (int off = 1; off < 64; off <<= 1) {
    unsigned tv = __shfl_up(incl, off, 64);
    if (lane >= off) incl += tv;
  }
  if (lane == 63) sW[j][wv] = incl;
}
__device__ __forceinline__ void resolve4096(const unsigned (*sW)[16], int j, int tid, int wv,
                                            uint4 v, unsigned ps, unsigned incl, unsigned k,
                                            unsigned* selb, unsigned* selk) {
  unsigned woff = 0;
  for (int i = 0; i < wv; ++i) woff += sW[j][i];
  incl += woff;
  unsigned excl = incl - ps;
  if (excl <= k && k < incl) {
    unsigned vv[4] = {v.x, v.y, v.z, v.w};
    unsigned run = excl;
    int c = 0;
#pragma unroll
    for (; c < 3; ++c) {
      if (run + vv[c] > k) break;
      run += vv[c];
    }
    *selb = (unsigned)(tid * 4 + c);
    *selk = k - run;
  }
}
__device__ __forceinline__ void scan256(unsigned (*hist)[4096], int j, int tid, int lane,
                                        int wv, unsigned (*sW)[16], unsigned& v,
                                        unsigned& incl) {
  v = (tid < 256) ? hist[j][tid] : 0u;
  if (tid < 256) hist[j][tid] = 0u;
  incl = v;
#pragma unroll
  for (int off = 1; off < 64; off <<= 1) {
    unsigned tv = __shfl_up(incl, off, 64);
    if (lane >= off) incl += tv;
  }
  if (lane == 63) sW[j][wv] = incl;
}
__device__ __forceinline__ void resolve256(const unsigned (*sW)[16], int j, int tid, int wv,
                                           unsigned v, unsigned incl, unsigned k,
                                           unsigned* selb) {
  unsigned woff = 0;
  for (int i = 0; i < wv; ++i) woff += sW[j][i];
  incl += woff;
  unsigned excl = incl - v;
  if (excl <= k && k < incl) *selb = (unsigned)tid;
}

// ---------------- Kernel C: selects + smooth + normalize + FINAL BLEND (per row) ----------------
__global__ __launch_bounds__(1024)
void ruleselect_k(const float* __restrict__ hc, const float* __restrict__ an,
                  const float* __restrict__ sc, const float* __restrict__ ot,
                  const float* __restrict__ amask, const float* __restrict__ lp,
                  float* __restrict__ out) {
  __shared__ unsigned hist3[3][4096];
  __shared__ float vbuf[4096];
  __shared__ unsigned selB[2][4];
  __shared__ unsigned selK[2][4];
  __shared__ unsigned sW3[3][16];
  __shared__ float sM3[3][16];
  __shared__ int iCnt[16];
  int b = blockIdx.x, tid = threadIdx.x;
  int lane = tid & 63, wv = tid >> 6;
  const float* mk = amask + (size_t)b * T_;
  const float* h0 = hc + (size_t)b * T_;
  const float* a0 = an + (size_t)b * T_;
  const float* s0 = sc + (size_t)b * T_;
  const float* o0 = ot + (size_t)b * T_;

  float mv0[4], mv1[4], mv2[4], otv[4], mreg[4];
  int cnt = 0;
#pragma unroll
  for (int r = 0; r < 4; ++r) {
    int t = tid + 1024 * r;
    mv0[r] = h0[t]; mv1[r] = a0[t]; mv2[r] = s0[t]; otv[r] = o0[t];
    mreg[r] = mk[t];
    cnt += (mreg[r] > 0.5f);
  }
#pragma unroll
  for (int off = 32; off; off >>= 1) cnt += __shfl_xor(cnt, off);
  if (lane == 0) iCnt[wv] = cnt;
  {
    unsigned* hflat = &hist3[0][0];
    for (int i = tid; i < 3 * 4096; i += 1024) hflat[i] = 0u;
  }
  unsigned u0[4], u1[4], u2[4];
  float mxa = 0.f, mxb = 0.f, mxc = 0.f;
#pragma unroll
  for (int r = 0; r < 4; ++r) {
    bool valid = mreg[r] > 0.5f;
    unsigned b0 = __float_as_uint(mv0[r]); if ((int)b0 < 0) b0 = 0u;
    unsigned b1 = __float_as_uint(mv1[r]); if ((int)b1 < 0) b1 = 0u;
    unsigned b2 = __float_as_uint(mv2[r]); if ((int)b2 < 0) b2 = 0u;
    u0[r] = valid ? b0 : NOINS;
    u1[r] = valid ? b1 : NOINS;
    u2[r] = valid ? b2 : NOINS;
    if (valid) {
      mxa = fmaxf(mxa, fabsf(mv0[r]));
      mxb = fmaxf(mxb, fabsf(mv1[r]));
      mxc = fmaxf(mxc, fabsf(mv2[r]));
    }
  }
#pragma unroll
  for (int off = 32; off; off >>= 1) {
    mxa = fmaxf(mxa, __shfl_xor(mxa, off));
    mxb = fmaxf(mxb, __shfl_xor(mxb, off));
    mxc = fmaxf(mxc, __shfl_xor(mxc, off));
  }
  if (lane == 0) { sM3[0][wv] = mxa; sM3[1][wv] = mxb; sM3[2][wv] = mxc; }
  __syncthreads();  // B1
  int n = 0;
#pragma unroll
  for (int i = 0; i < 16; ++i) n += iCnt[i];
  int cidx = (int)ceilf((float)n * 0.95f);
  if (cidx < 1) cidx = 1;
  unsigned kidx = (unsigned)(cidx - 1);
  if (kidx > (unsigned)(T_ - 1)) kidx = T_ - 1;
  float mx3a = sM3[0][0], mx3b = sM3[1][0], mx3c = sM3[2][0];
#pragma unroll
  for (int i = 1; i < 16; ++i) {
    mx3a = fmaxf(mx3a, sM3[0][i]);
    mx3b = fmaxf(mx3b, sM3[1][i]);
    mx3c = fmaxf(mx3c, sM3[2][i]);
  }

#pragma unroll
  for (int r = 0; r < 4; ++r) {
    if (u0[r] != NOINS) atomicAdd(&hist3[0][u0[r] >> 20], 1u);
    if (u1[r] != NOINS) atomicAdd(&hist3[1][u1[r] >> 20], 1u);
    if (u2[r] != NOINS) atomicAdd(&hist3[2][u2[r] >> 20], 1u);
  }
  __syncthreads();  // B2
  uint4 v40, v41, v42; unsigned ps0, ps1, ps2, in0, in1, in2;
  scan4096(hist3, 0, tid, lane, wv, sW3, v40, ps0, in0);
  scan4096(hist3, 1, tid, lane, wv, sW3, v41, ps1, in1);
  scan4096(hist3, 2, tid, lane, wv, sW3, v42, ps2, in2);
  __syncthreads();  // B3
  resolve4096(sW3, 0, tid, wv, v40, ps0, in0, kidx, &selB[1][0], &selK[1][0]);
  resolve4096(sW3, 1, tid, wv, v41, ps1, in1, kidx, &selB[1][1], &selK[1][1]);
  resolve4096(sW3, 2, tid, wv, v42, ps2, in2, kidx, &selB[1][2], &selK[1][2]);
  __syncthreads();  // B4
  unsigned p1_0 = selB[1][0], p1_1 = selB[1][1], p1_2 = selB[1][2];
  unsigned k2_0 = selK[1][0], k2_1 = selK[1][1], k2_2 = selK[1][2];
#pragma unroll
  for (int r = 0; r < 4; ++r) {
    if (u0[r] != NOINS && (u0[r] >> 20) == p1_0) atomicAdd(&hist3[0][(u0[r] >> 8) & 0xFFFu], 1u);
    if (u1[r] != NOINS && (u1[r] >> 20) == p1_1) atomicAdd(&hist3[1][(u1[r] >> 8) & 0xFFFu], 1u);
    if (u2[r] != NOINS && (u2[r] >> 20) == p1_2) atomicAdd(&hist3[2][(u2[r] >> 8) & 0xFFFu], 1u);
  }
  __syncthreads();  // B5
  scan4096(hist3, 0, tid, lane, wv, sW3, v40, ps0, in0);
  scan4096(hist3, 1, tid, lane, wv, sW3, v41, ps1, in1);
  scan4096(hist3, 2, tid, lane, wv, sW3, v42, ps2, in2);
  __syncthreads();  // B6
  resolve4096(sW3, 0, tid, wv, v40, ps0, in0, k2_0, &selB[0][0], &selK[0][0]);
  resolve4096(sW3, 1, tid, wv, v41, ps1, in1, k2_1, &selB[0][1], &selK[0][1]);
  resolve4096(sW3, 2, tid, wv, v42, ps2, in2, k2_2, &selB[0][2], &selK[0][2]);
  __syncthreads();  // B7
  unsigned p2_0 = selB[0][0], p2_1 = selB[0][1], p2_2 = selB[0][2];
  unsigned k3_0 = selK[0][0], k3_1 = selK[0][1], k3_2 = selK[0][2];
  unsigned pf0 = (p1_0 << 12) | p2_0, pf1 = (p1_1 << 12) | p2_1, pf2 = (p1_2 << 12) | p2_2;
#pragma unroll
  for (int r = 0; r < 4; ++r) {
    if (u0[r] != NOINS && (u0[r] >> 8) == pf0) atomicAdd(&hist3[0][u0[r] & 0xFFu], 1u);
    if (u1[r] != NOINS && (u1[r] >> 8) == pf1) atomicAdd(&hist3[1][u1[r] & 0xFFu], 1u);
    if (u2[r] != NOINS && (u2[r] >> 8) == pf2) atomicAdd(&hist3[2][u2[r] & 0xFFu], 1u);
  }
  __syncthreads();  // B8
  unsigned s80, s81, s82;
  scan256(hist3, 0, tid, lane, wv, sW3, s80, in0);
  scan256(hist3, 1, tid, lane, wv, sW3, s81, in1);
  scan256(hist3, 2, tid, lane, wv, sW3, s82, in2);
  __syncthreads();  // B9
  resolve256(sW3, 0, tid, wv, s80, in0, k3_0, &selB[1][0]);
  resolve256(sW3, 1, tid, wv, s81, in1, k3_1, &selB[1][1]);
  resolve256(sW3, 2, tid, wv, s82, in2, k3_2, &selB[1][2]);
  __syncthreads();  // B10
  float kth0 = fabsf(__uint_as_float((p1_0 << 20) | (p2_0 << 8) | selB[1][0]));
  float kth1 = fabsf(__uint_as_float((p1_1 << 20) | (p2_1 << 8) | selB[1][1]));
  float kth2 = fabsf(__uint_as_float((p1_2 << 20) | (p2_2 << 8) | selB[1][2]));
  float sc0 = fmaxf((kth0 < 1e-6f) ? mx3a : kth0, 1e-6f);
  float sc1 = fmaxf((kth1 < 1e-6f) ? mx3b : kth1, 1e-6f);
  float sc2 = fmaxf((kth2 < 1e-6f) ? mx3c : kth2, 1e-6f);

#pragma unroll
  for (int r = 0; r < 4; ++r) {
    int t = tid + 1024 * r;
    float v = 0.f;
    if (n > 0) {
      v = 0.35f * (mv0[r] / sc0) + 0.30f * (mv1[r] / sc1)
        + 0.25f * (mv2[r] / sc2) + 0.10f * otv[r];
    }
    vbuf[t] = v;
  }
  __syncthreads();  // B11
  float sm[4];
#pragma unroll
  for (int r = 0; r < 4; ++r) {
    int t = tid + 1024 * r;
    float s = 0.f;
#pragma unroll
    for (int d = -2; d <= 2; ++d) {
      int tt = t + d;
      if (tt >= 0 && tt < T_) s += vbuf[tt];
    }
    sm[r] = s * 0.2f * mreg[r];
  }
  // ---- 4th select (hist3[0], slot 3) ----
  unsigned uu[4];
  float mxs = 0.f;
#pragma unroll
  for (int r = 0; r < 4; ++r) {
    bool valid = mreg[r] > 0.5f;
    unsigned ub = __float_as_uint(sm[r]); if ((int)ub < 0) ub = 0u;
    uu[r] = valid ? ub : NOINS;
    if (valid) mxs = fmaxf(mxs, fabsf(sm[r]));
  }
#pragma unroll
  for (int off = 32; off; off >>= 1) mxs = fmaxf(mxs, __shfl_xor(mxs, off));
  if (lane == 0) sM3[0][wv] = mxs;
#pragma unroll
  for (int r = 0; r < 4; ++r)
    if (uu[r] != NOINS) atomicAdd(&hist3[0][uu[r] >> 20], 1u);
  __syncthreads();  // B12 — smooth reads of vbuf done; repurpose vbuf for lp
  const float* lprow = lp + (size_t)b * T_;
#pragma unroll
  for (int r = 0; r < 4; ++r) {
    int t = tid + 1024 * r;
    vbuf[t] = lprow[t];
  }
  float mx4 = sM3[0][0];
#pragma unroll
  for (int i = 1; i < 16; ++i) mx4 = fmaxf(mx4, sM3[0][i]);
  scan4096(hist3, 0, tid, lane, wv, sW3, v40, ps0, in0);
  __syncthreads();  // B13
  resolve4096(sW3, 0, tid, wv, v40, ps0, in0, kidx, &selB[1][3], &selK[1][3]);
  __syncthreads();  // B14
  unsigned q1 = selB[1][3], kq2 = selK[1][3];
#pragma unroll
  for (int r = 0; r < 4; ++r)
    if (uu[r] != NOINS && (uu[r] >> 20) == q1) atomicAdd(&hist3[0][(uu[r] >> 8) & 0xFFFu], 1u);
  __syncthreads();  // B15
  scan4096(hist3, 0, tid, lane, wv, sW3, v40, ps0, in0);
  __syncthreads();  // B16
  resolve4096(sW3, 0, tid, wv, v40, ps0, in0, kq2, &selB[0][3], &selK[0][3]);
  __syncthreads();  // B17
  unsigned q2 = selB[0][3], kq3 = selK[0][3];
  unsigned qf = (q1 << 12) | q2;
#pragma unroll
  for (int r = 0; r < 4; ++r)
    if (uu[r] != NOINS && (uu[r] >> 8) == qf) atomicAdd(&hist3[0][uu[r] & 0xFFu], 1u);
  __syncthreads();  // B18
  scan256(hist3, 0, tid, lane, wv, sW3, s80, in0);
  __syncthreads();  // B19
  resolve256(sW3, 0, tid, wv, s80, in0, kq3, &selB[1][3]);
  __syncthreads();  // B20
  float kth4 = fabsf(__uint_as_float((q1 << 20) | (q2 << 8) | selB[1][3]));
  float scale4 = fmaxf((kth4 < 1e-6f) ? mx4 : kth4, 1e-6f);
  // ---- final blend: rule + smoothed learned -> out ----
  float* orow = out + (size_t)b * T_;
#pragma unroll
  for (int r = 0; r < 4; ++r) {
    int t = tid + 1024 * r;
    float rv = (n > 0) ? sm[r] / scale4 : 0.f;
    rv = clip01(rv) * mreg[r];
    float ssum = 0.f;
#pragma unroll
    for (int d = -2; d <= 2; ++d) {
      int tt = t + d;
      if (tt >= 0 && tt < T_) ssum += vbuf[tt];
    }
    float learned = clip01(ssum * 0.2f * mreg[r]);
    orow[t] = clip01(0.5f * rv + 0.5f * learned) * mreg[r];
  }
}

}  // namespace

extern "C" void kernel_launch(void* const* d_in, const int* in_sizes, int n_in,
                              void* d_out, int out_size, void* d_ws, size_t ws_size,
                              hipStream_t stream) {
  const float* traj      = (const float*)d_in[0];
  const float* intervals = (const float*)d_in[1];
  const float* amask     = (const float*)d_in[2];
  const float* omask     = (const float*)d_in[3];
  const float* w1        = (const float*)d_in[4];
  const float* b1        = (const float*)d_in[5];
  const float* w2        = (const float*)d_in[6];
  const float* b2        = (const float*)d_in[7];
  const float* w3        = (const float*)d_in[8];
  const float* b3        = (const float*)d_in[9];
  float* out = (float*)d_out;
  float* ws = (float*)d_ws;

  _Float16* feats16 = (_Float16*)(ws + OFF_F16);
  float* hc = ws + OFF_HC;
  float* an = ws + OFF_AN;
  float* sc = ws + OFF_SC;
  float* ot = ws + OFF_OT;
  float* lp = ws + OFF_LP;
  half8* w1f = (half8*)(ws + OFF_W1F);
  half8* w2f = (half8*)(ws + OFF_W2F);

  featurize_k<<<BT / 256, 256, 0, stream>>>(traj, intervals, amask, omask, w1, w2,
                                            feats16, hc, an, sc, ot, w1f, w2f);
  conv_k<<<dim3(T_ / CT, B_), 256, 0, stream>>>(feats16, w1f, b1, w2f, b2, w3, b3,
                                                amask, lp);
  ruleselect_k<<<B_, 1024, 0, stream>>>(hc, an, sc, ot, amask, lp, out);
}

// Round 13
// 147.601 us; speedup vs baseline: 1.8928x; 1.0206x over previous
//
#include <hip/hip_runtime.h>

namespace {

constexpr int B_ = 128;
constexpr int T_ = 4096;
constexpr int BT = B_ * T_;
constexpr int CT = 64;  // conv t-tile (4-wave blocks, 7 blocks/CU)
constexpr unsigned NOINS = 0xFFFFFFFFu;  // "do not insert" sentinel (invalid/masked lane)

// workspace layout (float offsets)
constexpr size_t OFF_W1F = 0;                     // 8 frags * 64 * 8 f16
constexpr size_t OFF_W2F = 2048;                  // 40 frags * 64 * 8 f16
constexpr size_t OFF_F16 = 16384;                 // feats16: B*T*10 halfs = B*T*5 dwords
constexpr size_t OFF_MET = OFF_F16 + (size_t)BT * 5;   // met: float4 per (b,t) = 4*BT floats
constexpr size_t OFF_LP  = OFF_MET + (size_t)BT * 4;

typedef _Float16 half8 __attribute__((ext_vector_type(8)));
typedef _Float16 half4 __attribute__((ext_vector_type(4)));
typedef _Float16 half2_t __attribute__((ext_vector_type(2)));
typedef float f32x4 __attribute__((ext_vector_type(4)));

__device__ __forceinline__ float clip01(float x) { return fminf(fmaxf(x, 0.f), 1.f); }

// tanh-GELU as sigmoid: x*sigmoid(1.5957691*(x+0.044715x^3)), 7 VALU ops.
__device__ __forceinline__ float gelu_tanh(float x) {
  float x2 = x * x;
  float q = x * __builtin_fmaf(-0.10294444f, x2, -2.3022077f);
  float e = __builtin_amdgcn_exp2f(q);
  return x * __builtin_amdgcn_rcpf(1.0f + e);
}

// rcp + one Newton step: <=1 ulp vs exact divide for normal inputs (dt >= 1e-3)
__device__ __forceinline__ float rcp_nr(float d) {
  float r = __builtin_amdgcn_rcpf(d);
  return r * __builtin_fmaf(-d, r, 2.0f);
}

// |atan2(y,x)| in [0,pi]; poly err <= ~1e-5 rad; exact corner semantics:
// (0,0)->0, (0,x<0)->pi, (y,0)->pi/2 — matches fabsf(atan2f(y,x)).
__device__ __forceinline__ float fabs_atan2_fast(float y, float x) {
  float ay = fabsf(y), ax = fabsf(x);
  float mn = fminf(ax, ay), mx = fmaxf(ax, ay);
  float rc = rcp_nr(mx);
  float r = (mx > 0.f) ? mn * rc : 0.f;
  float s = r * r;
  float p = __builtin_fmaf(s, -0.01172120f, 0.05265332f);
  p = __builtin_fmaf(s, p, -0.11643287f);
  p = __builtin_fmaf(s, p, 0.19354346f);
  p = __builtin_fmaf(s, p, -0.33262347f);
  p = __builtin_fmaf(s, p, 0.99997726f);
  float t = r * p;
  if (ay > ax) t = 1.5707963267948966f - t;
  if (x < 0.f) t = 3.141592653589793f - t;
  return t;
}

// feature math for (b,t) — same values as round-4 featurize_k (divides via rcp-NR,
// atan2 via poly; both well within threshold).
__device__ __forceinline__ void compute_feats(
    const float* __restrict__ tr, const float* __restrict__ iv,
    const float* __restrict__ mk, const float* __restrict__ om, int t,
    float* __restrict__ f /*10*/, float* anv_out, float* scv_out, float* otv_out) {
  float m  = mk[t];
  float m1 = (t >= 1) ? mk[t - 1] : 0.f;
  float m2 = (t >= 2) ? mk[t - 2] : 0.f;
  float pm01 = (m > 0.5f && m1 > 0.5f) ? 1.f : 0.f;
  float pm12 = (m1 > 0.5f && m2 > 0.5f) ? 1.f : 0.f;
  float x0x = tr[2 * t] * m, x0y = tr[2 * t + 1] * m;
  float x1x = 0.f, x1y = 0.f, x2x = 0.f, x2y = 0.f;
  if (t >= 1) { x1x = tr[2 * (t - 1)] * m1; x1y = tr[2 * (t - 1) + 1] * m1; }
  if (t >= 2) { x2x = tr[2 * (t - 2)] * m2; x2y = tr[2 * (t - 2) + 1] * m2; }
  float dt0 = fmaxf(iv[t], 1e-3f);
  float dt1 = (t >= 1) ? fmaxf(iv[t - 1], 1e-3f) : 1e-3f;
  float inv0 = rcp_nr(dt0);
  float inv1 = rcp_nr(dt1);
  float vx = 0.f, vy = 0.f, v1x = 0.f, v1y = 0.f;
  if (t >= 1) { vx = (x0x - x1x) * pm01 * inv0 * m; vy = (x0y - x1y) * pm01 * inv0 * m; }
  if (t >= 2) { v1x = (x1x - x2x) * pm12 * inv1 * m1; v1y = (x1y - x2y) * pm12 * inv1 * m1; }
  float ax = 0.f, ay = 0.f;
  if (t >= 1) { ax = (vx - v1x) * pm01 * inv0 * m; ay = (vy - v1y) * pm01 * inv0 * m; }
  float s2 = vx * vx + vy * vy;
  float speed = (s2 > 0.f ? sqrtf(s2) : 0.f) * m;
  float s21 = v1x * v1x + v1y * v1y;
  float speed1 = (s21 > 0.f ? sqrtf(s21) : 0.f) * m1;
  float scv = (t >= 1) ? fabsf((speed - speed1) * pm01) * m : 0.f;
  float a2 = ax * ax + ay * ay;
  float anv = (a2 > 0.f ? sqrtf(a2) : 0.f) * m;
  float hcv = 0.f;
  if (t >= 1) {
    bool z0 = (vx == 0.f && vy == 0.f);
    bool z1 = (v1x == 0.f && v1y == 0.f);
    float yy, xx;
    if (z1)      { yy = vy;  xx = vx; }
    else if (z0) { yy = v1y; xx = v1x; }
    else { yy = vy * v1x - vx * v1y; xx = vx * v1x + vy * v1y; }
    hcv = fabs_atan2_fast(yy, xx) * pm01 * m;
  }
  float obs = om[t] * m;
  float otv = (t >= 1) ? fminf(fabsf(om[t] - om[t - 1]) * pm01 * m, 1.f) : 0.f;
  float itf = iv[t] * m;
  f[0] = x0x; f[1] = x0y; f[2] = vx; f[3] = vy; f[4] = ax; f[5] = ay;
  f[6] = speed; f[7] = hcv; f[8] = itf; f[9] = obs;
  *anv_out = anv; *scv_out = scv; *otv_out = otv;
}

// ---------------- Kernel A: featurize -> f16 feats + packed float4 metrics + repack ----------------
__global__ __launch_bounds__(256)
void featurize_k(const float* __restrict__ traj, const float* __restrict__ intervals,
                 const float* __restrict__ amask, const float* __restrict__ omask,
                 const float* __restrict__ w1g, const float* __restrict__ w2g,
                 _Float16* __restrict__ feats16, float4* __restrict__ met,
                 half8* __restrict__ w1f, half8* __restrict__ w2f) {
  int idx = blockIdx.x * 256 + threadIdx.x;
  int b = idx >> 12;
  int t = idx & (T_ - 1);
  float f[10], anv, scv, otv;
  compute_feats(traj + (size_t)b * T_ * 2, intervals + (size_t)b * T_,
                amask + (size_t)b * T_, omask + (size_t)b * T_, t, f, &anv, &scv, &otv);
  // interleaved [t][c] layout, pre-scaled 2^-6 (RNE)
  half2_t* fd = reinterpret_cast<half2_t*>(feats16) + (size_t)idx * 5;
#pragma unroll
  for (int q = 0; q < 5; ++q) {
    half2_t pk;
    pk[0] = (_Float16)(f[2 * q] * 0.015625f);
    pk[1] = (_Float16)(f[2 * q + 1] * 0.015625f);
    fd[q] = pk;
  }
  met[idx] = make_float4(f[7], anv, scv, otv);

  // fused repack: first 12 blocks also build MFMA weight fragments
  if (blockIdx.x < 12) {
    int gid = blockIdx.x * 256 + threadIdx.x;
    if (gid < 48 * 64) {
      int fid = gid >> 6, lane = gid & 63;
      int qd = lane >> 4, ln = lane & 15;
      half8 v;
      if (fid < 8) {
        int m = fid >> 1, kk = fid & 1;
        int o = m * 16 + ln;
#pragma unroll
        for (int j = 0; j < 8; ++j) {
          int ck = kk * 32 + qd * 8 + j;
          float val = 0.f;
          if (ck < 50) { int k_ = ck / 10, c = ck - 10 * k_; val = w1g[o * 50 + c * 5 + k_]; }
          v[j] = (_Float16)val;
        }
        w1f[fid * 64 + lane] = v;
      } else {
        int f2 = fid - 8;
        int k = f2 >> 3, kk = (f2 >> 2) & 1, m = f2 & 3;
        int o = m * 16 + ln;
#pragma unroll
        for (int j = 0; j < 8; ++j) {
          int ic = kk * 32 + qd * 8 + j;
          v[j] = (_Float16)w2g[o * 320 + ic * 5 + k];
        }
        w2f[f2 * 64 + lane] = v;
      }
    }
  }
}

// ---------------- Kernel B: MFMA conv stack, CT=64 / 4-wave blocks ----------------
// __launch_bounds__(256,7): 7 waves/EU = the LDS-limited occupancy (7 x 21.8 KB
// blocks/CU) -> allocator may use ~73 VGPRs for load pipelining (was squeezed to 36).
__global__ __launch_bounds__(256, 7)
void conv_k(const _Float16* __restrict__ feats16, const half8* __restrict__ w1f,
            const float* __restrict__ b1g, const half8* __restrict__ w2f,
            const float* __restrict__ b2g, const float* __restrict__ w3g,
            const float* __restrict__ b3g, const float* __restrict__ amask,
            float* __restrict__ lp) {
  __shared__ _Float16 sIm[80 * 72];    // 11520 B
  __shared__ _Float16 sH1[68 * 72];    // 9792 B
  __shared__ float sPart[2][64];
  _Float16* sF16 = sH1;  // staging tile aliases sH1 until im2col barrier
  int tid = threadIdx.x;
  int lane = tid & 63, w = tid >> 6;
  int qd = lane >> 4, ln = lane & 15;
  int tile = blockIdx.x, b = blockIdx.y;
  int t0 = tile * CT;

  const unsigned* gfd = reinterpret_cast<const unsigned*>(feats16 + (size_t)b * T_ * 10);
  unsigned* sFd = reinterpret_cast<unsigned*>(sF16);
  int dbase = (t0 - 4) * 5;
  for (int s = tid; s < 360; s += 256) {
    int gi = dbase + s;
    sFd[s] = (gi >= 0 && gi < T_ * 5) ? gfd[gi] : 0u;
  }
  for (int s = tid; s < 560; s += 256) {
    int jt = s / 7, d = s - jt * 7;
    *reinterpret_cast<unsigned*>(&sIm[jt * 72 + 50 + 2 * d]) = 0u;
  }
  __syncthreads();
  unsigned* sId = reinterpret_cast<unsigned*>(sIm);
  for (int s = tid; s < 340; s += 256) {
    int jt = s / 5, k = s - jt * 5;
    const unsigned* src = sFd + (jt + k) * 5;
    unsigned* dst = sId + jt * 36 + k * 5;
#pragma unroll
    for (int q = 0; q < 5; ++q) dst[q] = src[q];
  }
  __syncthreads();  // sF16 dead; sH1 writes may begin

  // ---- phase 1: conv1; wave w owns output-channel group m = w ----
  {
    int m = w;
    half8 a1k0 = w1f[(m * 2 + 0) * 64 + lane];
    half8 a1k1 = w1f[(m * 2 + 1) * 64 + lane];
    f32x4 bv = *reinterpret_cast<const f32x4*>(&b1g[m * 16 + qd * 4]);
    f32x4 b1s;
#pragma unroll
    for (int r = 0; r < 4; ++r) b1s[r] = bv[r] * 0.015625f;
#pragma unroll
    for (int tl = 0; tl < 5; ++tl) {
      int jt = tl * 16 + ln;
      half8 bf0 = *reinterpret_cast<const half8*>(&sIm[jt * 72 + qd * 8]);
      half8 bf1 = *reinterpret_cast<const half8*>(&sIm[jt * 72 + 32 + qd * 8]);
      f32x4 acc = b1s;
      acc = __builtin_amdgcn_mfma_f32_16x16x32_f16(a1k0, bf0, acc, 0, 0, 0);
      acc = __builtin_amdgcn_mfma_f32_16x16x32_f16(a1k1, bf1, acc, 0, 0, 0);
      if (jt < 68) {
        int t = t0 - 2 + jt;
        bool inr = (t >= 0 && t < T_);
        half4 hv;
#pragma unroll
        for (int r = 0; r < 4; ++r) {
          float h = inr ? gelu_tanh(acc[r] * 64.f) * 0.0625f : 0.f;
          hv[r] = (_Float16)h;
        }
        *reinterpret_cast<half4*>(&sH1[jt * 72 + m * 16 + qd * 4]) = hv;
      }
    }
  }
  __syncthreads();

  // ---- phase 2: conv2 as 5 shifted GEMMs; wave = (p, nq) ----
  int p = w & 1, nq = w >> 1;
  f32x4 acc2[2][2];
#pragma unroll
  for (int dm = 0; dm < 2; ++dm) {
    f32x4 bv = *reinterpret_cast<const f32x4*>(&b2g[(2 * p + dm) * 16 + qd * 4]);
#pragma unroll
    for (int dn = 0; dn < 2; ++dn)
#pragma unroll
      for (int r = 0; r < 4; ++r) acc2[dm][dn][r] = bv[r] * 0.0625f;
  }
#pragma unroll
  for (int k = 0; k < 5; ++k) {
#pragma unroll
    for (int kk = 0; kk < 2; ++kk) {
      half8 A0 = w2f[((k * 2 + kk) * 4 + 2 * p + 0) * 64 + lane];
      half8 A1 = w2f[((k * 2 + kk) * 4 + 2 * p + 1) * 64 + lane];
      half8 B0 = *reinterpret_cast<const half8*>(
          &sH1[((2 * nq + 0) * 16 + ln + k) * 72 + kk * 32 + qd * 8]);
      half8 B1 = *reinterpret_cast<const half8*>(
          &sH1[((2 * nq + 1) * 16 + ln + k) * 72 + kk * 32 + qd * 8]);
      acc2[0][0] = __builtin_amdgcn_mfma_f32_16x16x32_f16(A0, B0, acc2[0][0], 0, 0, 0);
      acc2[0][1] = __builtin_amdgcn_mfma_f32_16x16x32_f16(A0, B1, acc2[0][1], 0, 0, 0);
      acc2[1][0] = __builtin_amdgcn_mfma_f32_16x16x32_f16(A1, B0, acc2[1][0], 0, 0, 0);
      acc2[1][1] = __builtin_amdgcn_mfma_f32_16x16x32_f16(A1, B1, acc2[1][1], 0, 0, 0);
    }
  }
  f32x4 w3a = *reinterpret_cast<const f32x4*>(&w3g[(2 * p + 0) * 16 + qd * 4]);
  f32x4 w3b = *reinterpret_cast<const f32x4*>(&w3g[(2 * p + 1) * 16 + qd * 4]);
#pragma unroll
  for (int dn = 0; dn < 2; ++dn) {
    float s = 0.f;
#pragma unroll
    for (int r = 0; r < 4; ++r) s += w3a[r] * gelu_tanh(acc2[0][dn][r] * 16.f);
#pragma unroll
    for (int r = 0; r < 4; ++r) s += w3b[r] * gelu_tanh(acc2[1][dn][r] * 16.f);
    s += __shfl_xor(s, 16);
    s += __shfl_xor(s, 32);
    if (lane < 16) sPart[p][(2 * nq + dn) * 16 + lane] = s;
  }
  __syncthreads();
  if (tid < 64) {
    int t = t0 + tid;
    float logit = sPart[0][tid] + sPart[1][tid] + b3g[0];
    float m = amask[(size_t)b * T_ + t];
    float e = __builtin_amdgcn_exp2f(logit * -1.4426950408889634f);
    lp[(size_t)b * T_ + t] = m * __builtin_amdgcn_rcpf(1.f + e);
  }
}

// ---------------- low-barrier radix-select machinery ----------------
__device__ __forceinline__ void scan4096(unsigned (*hist)[4096], int j, int tid, int lane,
                                         int wv, unsigned (*sW)[16], uint4& v,
                                         unsigned& ps, unsigned& incl) {
  v = *reinterpret_cast<uint4*>(&hist[j][tid * 4]);
  uint4 zz = {0u, 0u, 0u, 0u};
  *reinterpret_cast<uint4*>(&hist[j][tid * 4]) = zz;
  ps = v.x + v.y + v.z + v.w;
  incl = ps;
#pragma unroll
  for (int off = 1; off < 64; off <<= 1) {
    unsigned tv = __shfl_up(incl, off, 64);
    if (lane >= off) incl += tv;
  }
  if (lane == 63) sW[j][wv] = incl;
}
__device__ __forceinline__ void resolve4096(const unsigned (*sW)[16], int j, int tid, int wv,
                                            uint4 v, unsigned ps, unsigned incl, unsigned k,
                                            unsigned* selb, unsigned* selk) {
  unsigned woff = 0;
  for (int i = 0; i < wv; ++i) woff += sW[j][i];
  incl += woff;
  unsigned excl = incl - ps;
  if (excl <= k && k < incl) {
    unsigned vv[4] = {v.x, v.y, v.z, v.w};
    unsigned run = excl;
    int c = 0;
#pragma unroll
    for (; c < 3; ++c) {
      if (run + vv[c] > k) break;
      run += vv[c];
    }
    *selb = (unsigned)(tid * 4 + c);
    *selk = k - run;
  }
}
__device__ __forceinline__ void scan256(unsigned (*hist)[4096], int j, int tid, int lane,
                                        int wv, unsigned (*sW)[16], unsigned& v,
                                        unsigned& incl) {
  v = (tid < 256) ? hist[j][tid] : 0u;
  if (tid < 256) hist[j][tid] = 0u;
  incl = v;
#pragma unroll
  for (int off = 1; off < 64; off <<= 1) {
    unsigned tv = __shfl_up(incl, off, 64);
    if (lane >= off) incl += tv;
  }
  if (lane == 63) sW[j][wv] = incl;
}
__device__ __forceinline__ void resolve256(const unsigned (*sW)[16], int j, int tid, int wv,
                                           unsigned v, unsigned incl, unsigned k,
                                           unsigned* selb) {
  unsigned woff = 0;
  for (int i = 0; i < wv; ++i) woff += sW[j][i];
  incl += woff;
  unsigned excl = incl - v;
  if (excl <= k && k < incl) *selb = (unsigned)tid;
}

// ---------------- Kernel C: selects + smooth + normalize + FINAL BLEND (per row) ----------------
__global__ __launch_bounds__(1024)
void ruleselect_k(const float4* __restrict__ met, const float* __restrict__ amask,
                  const float* __restrict__ lp, float* __restrict__ out) {
  __shared__ unsigned hist3[3][4096];
  __shared__ float vbuf[4096];
  __shared__ unsigned selB[2][4];
  __shared__ unsigned selK[2][4];
  __shared__ unsigned sW3[3][16];
  __shared__ float sM3[3][16];
  __shared__ int iCnt[16];
  int b = blockIdx.x, tid = threadIdx.x;
  int lane = tid & 63, wv = tid >> 6;
  const float* mk = amask + (size_t)b * T_;
  const float4* mrow = met + (size_t)b * T_;

  float mv0[4], mv1[4], mv2[4], otv[4], mreg[4];
  int cnt = 0;
#pragma unroll
  for (int r = 0; r < 4; ++r) {
    int t = tid + 1024 * r;
    float4 v = mrow[t];
    mv0[r] = v.x; mv1[r] = v.y; mv2[r] = v.z; otv[r] = v.w;
    mreg[r] = mk[t];
    cnt += (mreg[r] > 0.5f);
  }
#pragma unroll
  for (int off = 32; off; off >>= 1) cnt += __shfl_xor(cnt, off);
  if (lane == 0) iCnt[wv] = cnt;
  {
    unsigned* hflat = &hist3[0][0];
    for (int i = tid; i < 3 * 4096; i += 1024) hflat[i] = 0u;
  }
  unsigned u0[4], u1[4], u2[4];
  float mxa = 0.f, mxb = 0.f, mxc = 0.f;
#pragma unroll
  for (int r = 0; r < 4; ++r) {
    bool valid = mreg[r] > 0.5f;
    unsigned b0 = __float_as_uint(mv0[r]); if ((int)b0 < 0) b0 = 0u;
    unsigned b1 = __float_as_uint(mv1[r]); if ((int)b1 < 0) b1 = 0u;
    unsigned b2 = __float_as_uint(mv2[r]); if ((int)b2 < 0) b2 = 0u;
    u0[r] = valid ? b0 : NOINS;
    u1[r] = valid ? b1 : NOINS;
    u2[r] = valid ? b2 : NOINS;
    if (valid) {
      mxa = fmaxf(mxa, fabsf(mv0[r]));
      mxb = fmaxf(mxb, fabsf(mv1[r]));
      mxc = fmaxf(mxc, fabsf(mv2[r]));
    }
  }
#pragma unroll
  for (int off = 32; off; off >>= 1) {
    mxa = fmaxf(mxa, __shfl_xor(mxa, off));
    mxb = fmaxf(mxb, __shfl_xor(mxb, off));
    mxc = fmaxf(mxc, __shfl_xor(mxc, off));
  }
  if (lane == 0) { sM3[0][wv] = mxa; sM3[1][wv] = mxb; sM3[2][wv] = mxc; }
  __syncthreads();  // B1
  int n = 0;
#pragma unroll
  for (int i = 0; i < 16; ++i) n += iCnt[i];
  int cidx = (int)ceilf((float)n * 0.95f);
  if (cidx < 1) cidx = 1;
  unsigned kidx = (unsigned)(cidx - 1);
  if (kidx > (unsigned)(T_ - 1)) kidx = T_ - 1;
  float mx3a = sM3[0][0], mx3b = sM3[1][0], mx3c = sM3[2][0];
#pragma unroll
  for (int i = 1; i < 16; ++i) {
    mx3a = fmaxf(mx3a, sM3[0][i]);
    mx3b = fmaxf(mx3b, sM3[1][i]);
    mx3c = fmaxf(mx3c, sM3[2][i]);
  }

#pragma unroll
  for (int r = 0; r < 4; ++r) {
    if (u0[r] != NOINS) atomicAdd(&hist3[0][u0[r] >> 20], 1u);
    if (u1[r] != NOINS) atomicAdd(&hist3[1][u1[r] >> 20], 1u);
    if (u2[r] != NOINS) atomicAdd(&hist3[2][u2[r] >> 20], 1u);
  }
  __syncthreads();  // B2
  uint4 v40, v41, v42; unsigned ps0, ps1, ps2, in0, in1, in2;
  scan4096(hist3, 0, tid, lane, wv, sW3, v40, ps0, in0);
  scan4096(hist3, 1, tid, lane, wv, sW3, v41, ps1, in1);
  scan4096(hist3, 2, tid, lane, wv, sW3, v42, ps2, in2);
  __syncthreads();  // B3
  resolve4096(sW3, 0, tid, wv, v40, ps0, in0, kidx, &selB[1][0], &selK[1][0]);
  resolve4096(sW3, 1, tid, wv, v41, ps1, in1, kidx, &selB[1][1], &selK[1][1]);
  resolve4096(sW3, 2, tid, wv, v42, ps2, in2, kidx, &selB[1][2], &selK[1][2]);
  __syncthreads();  // B4
  unsigned p1_0 = selB[1][0], p1_1 = selB[1][1], p1_2 = selB[1][2];
  unsigned k2_0 = selK[1][0], k2_1 = selK[1][1], k2_2 = selK[1][2];
#pragma unroll
  for (int r = 0; r < 4; ++r) {
    if (u0[r] != NOINS && (u0[r] >> 20) == p1_0) atomicAdd(&hist3[0][(u0[r] >> 8) & 0xFFFu], 1u);
    if (u1[r] != NOINS && (u1[r] >> 20) == p1_1) atomicAdd(&hist3[1][(u1[r] >> 8) & 0xFFFu], 1u);
    if (u2[r] != NOINS && (u2[r] >> 20) == p1_2) atomicAdd(&hist3[2][(u2[r] >> 8) & 0xFFFu], 1u);
  }
  __syncthreads();  // B5
  scan4096(hist3, 0, tid, lane, wv, sW3, v40, ps0, in0);
  scan4096(hist3, 1, tid, lane, wv, sW3, v41, ps1, in1);
  scan4096(hist3, 2, tid, lane, wv, sW3, v42, ps2, in2);
  __syncthreads();  // B6
  resolve4096(sW3, 0, tid, wv, v40, ps0, in0, k2_0, &selB[0][0], &selK[0][0]);
  resolve4096(sW3, 1, tid, wv, v41, ps1, in1, k2_1, &selB[0][1], &selK[0][1]);
  resolve4096(sW3, 2, tid, wv, v42, ps2, in2, k2_2, &selB[0][2], &selK[0][2]);
  __syncthreads();  // B7
  unsigned p2_0 = selB[0][0], p2_1 = selB[0][1], p2_2 = selB[0][2];
  unsigned k3_0 = selK[0][0], k3_1 = selK[0][1], k3_2 = selK[0][2];
  unsigned pf0 = (p1_0 << 12) | p2_0, pf1 = (p1_1 << 12) | p2_1, pf2 = (p1_2 << 12) | p2_2;
#pragma unroll
  for (int r = 0; r < 4; ++r) {
    if (u0[r] != NOINS && (u0[r] >> 8) == pf0) atomicAdd(&hist3[0][u0[r] & 0xFFu], 1u);
    if (u1[r] != NOINS && (u1[r] >> 8) == pf1) atomicAdd(&hist3[1][u1[r] & 0xFFu], 1u);
    if (u2[r] != NOINS && (u2[r] >> 8) == pf2) atomicAdd(&hist3[2][u2[r] & 0xFFu], 1u);
  }
  __syncthreads();  // B8
  unsigned s80, s81, s82;
  scan256(hist3, 0, tid, lane, wv, sW3, s80, in0);
  scan256(hist3, 1, tid, lane, wv, sW3, s81, in1);
  scan256(hist3, 2, tid, lane, wv, sW3, s82, in2);
  __syncthreads();  // B9
  resolve256(sW3, 0, tid, wv, s80, in0, k3_0, &selB[1][0]);
  resolve256(sW3, 1, tid, wv, s81, in1, k3_1, &selB[1][1]);
  resolve256(sW3, 2, tid, wv, s82, in2, k3_2, &selB[1][2]);
  __syncthreads();  // B10
  float kth0 = fabsf(__uint_as_float((p1_0 << 20) | (p2_0 << 8) | selB[1][0]));
  float kth1 = fabsf(__uint_as_float((p1_1 << 20) | (p2_1 << 8) | selB[1][1]));
  float kth2 = fabsf(__uint_as_float((p1_2 << 20) | (p2_2 << 8) | selB[1][2]));
  float sc0 = fmaxf((kth0 < 1e-6f) ? mx3a : kth0, 1e-6f);
  float sc1 = fmaxf((kth1 < 1e-6f) ? mx3b : kth1, 1e-6f);
  float sc2 = fmaxf((kth2 < 1e-6f) ? mx3c : kth2, 1e-6f);

#pragma unroll
  for (int r = 0; r < 4; ++r) {
    int t = tid + 1024 * r;
    float v = 0.f;
    if (n > 0) {
      v = 0.35f * (mv0[r] / sc0) + 0.30f * (mv1[r] / sc1)
        + 0.25f * (mv2[r] / sc2) + 0.10f * otv[r];
    }
    vbuf[t] = v;
  }
  __syncthreads();  // B11
  float sm[4];
#pragma unroll
  for (int r = 0; r < 4; ++r) {
    int t = tid + 1024 * r;
    float s = 0.f;
#pragma unroll
    for (int d = -2; d <= 2; ++d) {
      int tt = t + d;
      if (tt >= 0 && tt < T_) s += vbuf[tt];
    }
    sm[r] = s * 0.2f * mreg[r];
  }
  // ---- 4th select (hist3[0], slot 3) ----
  unsigned uu[4];
  float mxs = 0.f;
#pragma unroll
  for (int r = 0; r < 4; ++r) {
    bool valid = mreg[r] > 0.5f;
    unsigned ub = __float_as_uint(sm[r]); if ((int)ub < 0) ub = 0u;
    uu[r] = valid ? ub : NOINS;
    if (valid) mxs = fmaxf(mxs, fabsf(sm[r]));
  }
#pragma unroll
  for (int off = 32; off; off >>= 1) mxs = fmaxf(mxs, __shfl_xor(mxs, off));
  if (lane == 0) sM3[0][wv] = mxs;
#pragma unroll
  for (int r = 0; r < 4; ++r)
    if (uu[r] != NOINS) atomicAdd(&hist3[0][uu[r] >> 20], 1u);
  __syncthreads();  // B12 — smooth reads of vbuf done; repurpose vbuf for lp
  const float* lprow = lp + (size_t)b * T_;
#pragma unroll
  for (int r = 0; r < 4; ++r) {
    int t = tid + 1024 * r;
    vbuf[t] = lprow[t];
  }
  float mx4 = sM3[0][0];
#pragma unroll
  for (int i = 1; i < 16; ++i) mx4 = fmaxf(mx4, sM3[0][i]);
  scan4096(hist3, 0, tid, lane, wv, sW3, v40, ps0, in0);
  __syncthreads();  // B13
  resolve4096(sW3, 0, tid, wv, v40, ps0, in0, kidx, &selB[1][3], &selK[1][3]);
  __syncthreads();  // B14
  unsigned q1 = selB[1][3], kq2 = selK[1][3];
#pragma unroll
  for (int r = 0; r < 4; ++r)
    if (uu[r] != NOINS && (uu[r] >> 20) == q1) atomicAdd(&hist3[0][(uu[r] >> 8) & 0xFFFu], 1u);
  __syncthreads();  // B15
  scan4096(hist3, 0, tid, lane, wv, sW3, v40, ps0, in0);
  __syncthreads();  // B16
  resolve4096(sW3, 0, tid, wv, v40, ps0, in0, kq2, &selB[0][3], &selK[0][3]);
  __syncthreads();  // B17
  unsigned q2 = selB[0][3], kq3 = selK[0][3];
  unsigned qf = (q1 << 12) | q2;
#pragma unroll
  for (int r = 0; r < 4; ++r)
    if (uu[r] != NOINS && (uu[r] >> 8) == qf) atomicAdd(&hist3[0][uu[r] & 0xFFu], 1u);
  __syncthreads();  // B18
  scan256(hist3, 0, tid, lane, wv, sW3, s80, in0);
  __syncthreads();  // B19
  resolve256(sW3, 0, tid, wv, s80, in0, kq3, &selB[1][3]);
  __syncthreads();  // B20
  float kth4 = fabsf(__uint_as_float((q1 << 20) | (q2 << 8) | selB[1][3]));
  float scale4 = fmaxf((kth4 < 1e-6f) ? mx4 : kth4, 1e-6f);
  // ---- final blend: rule + smoothed learned -> out ----
  float* orow = out + (size_t)b * T_;
#pragma unroll
  for (int r = 0; r < 4; ++r) {
    int t = tid + 1024 * r;
    float rv = (n > 0) ? sm[r] / scale4 : 0.f;
    rv = clip01(rv) * mreg[r];
    float ssum = 0.f;
#pragma unroll
    for (int d = -2; d <= 2; ++d) {
      int tt = t + d;
      if (tt >= 0 && tt < T_) ssum += vbuf[tt];
    }
    float learned = clip01(ssum * 0.2f * mreg[r]);
    orow[t] = clip01(0.5f * rv + 0.5f * learned) * mreg[r];
  }
}

}  // namespace

extern "C" void kernel_launch(void* const* d_in, const int* in_sizes, int n_in,
                              void* d_out, int out_size, void* d_ws, size_t ws_size,
                              hipStream_t stream) {
  const float* traj      = (const float*)d_in[0];
  const float* intervals = (const float*)d_in[1];
  const float* amask     = (const float*)d_in[2];
  const float* omask     = (const float*)d_in[3];
  const float* w1        = (const float*)d_in[4];
  const float* b1        = (const float*)d_in[5];
  const float* w2        = (const float*)d_in[6];
  const float* b2        = (const float*)d_in[7];
  const float* w3        = (const float*)d_in[8];
  const float* b3        = (const float*)d_in[9];
  float* out = (float*)d_out;
  float* ws = (float*)d_ws;

  _Float16* feats16 = (_Float16*)(ws + OFF_F16);
  float4* met = (float4*)(ws + OFF_MET);
  float* lp = ws + OFF_LP;
  half8* w1f = (half8*)(ws + OFF_W1F);
  half8* w2f = (half8*)(ws + OFF_W2F);

  featurize_k<<<BT / 256, 256, 0, stream>>>(traj, intervals, amask, omask, w1, w2,
                                            feats16, met, w1f, w2f);
  conv_k<<<dim3(T_ / CT, B_), 256, 0, stream>>>(feats16, w1f, b1, w2f, b2, w3, b3,
                                                amask, lp);
  ruleselect_k<<<B_, 1024, 0, stream>>>(met, amask, lp, out);
}